// Round 7
// baseline (1495.848 us; speedup 1.0000x reference)
//
#include <hip/hip_runtime.h>

// Problem constants
#define T_TOK 2048   // B*S
#define DIM   2048
#define NQ    16
#define NKV   4
#define HDIM  128
#define NE    32
#define TOPK  4
#define FF    1024
#define FSH   2048
#define SEQ   1024
#define MAXROWS 16384
#define MAXTILES 96

typedef __attribute__((ext_vector_type(4))) float f32x4;
typedef __attribute__((ext_vector_type(8))) short bf16x8;

__device__ __forceinline__ short f2bf(float f) {
    union { float f; unsigned u; } c; c.f = f;
    unsigned r = (c.u + 0x7fffu + ((c.u >> 16) & 1u)) >> 16;
    return (short)r;
}
__device__ __forceinline__ float bf2f(short h) {
    union { unsigned u; float f; } c; c.u = ((unsigned)(unsigned short)h) << 16;
    return c.f;
}
__device__ __forceinline__ void splitf(float v, short& hi, short& lo) {
    hi = f2bf(v);
    lo = f2bf(v - bf2f(hi));
}
// bijective XCD-chunk swizzle (m204)
__device__ __forceinline__ int xcd_swz(int lin, int total) {
    int q8 = total >> 3, r8 = total & 7;
    int xcd = lin & 7, idx = lin >> 3;
    return (xcd < r8 ? xcd * (q8 + 1) : r8 * (q8 + 1) + (xcd - r8) * q8) + idx;
}

// ---------------- RMSNorm. MODE 0: hi/lo bf16 planes. MODE 1: bf16 + fp32 ----------------
template<int MODE>
__global__ __launch_bounds__(256)
void rmsnorm_k(const float* __restrict__ x, const float* __restrict__ sc,
               short* __restrict__ ybh, short* __restrict__ ybl, float* __restrict__ yf)
{
    long base = (long)blockIdx.x * DIM;
    int tid = threadIdx.x;
    const float* xp = x + base + tid * 8;
    float4 a = *(const float4*)xp;
    float4 b = *(const float4*)(xp + 4);
    float ss = a.x*a.x + a.y*a.y + a.z*a.z + a.w*a.w
             + b.x*b.x + b.y*b.y + b.z*b.z + b.w*b.w;
#pragma unroll
    for (int off = 32; off > 0; off >>= 1) ss += __shfl_xor(ss, off);
    __shared__ float red[4];
    if ((tid & 63) == 0) red[tid >> 6] = ss;
    __syncthreads();
    float s = red[0] + red[1] + red[2] + red[3];
    float inv = rsqrtf(s * (1.f / DIM) + 1e-6f);
    const float* sp = sc + tid * 8;
    float4 s0 = *(const float4*)sp;
    float4 s1 = *(const float4*)(sp + 4);
    float o[8];
    o[0]=a.x*inv*s0.x; o[1]=a.y*inv*s0.y; o[2]=a.z*inv*s0.z; o[3]=a.w*inv*s0.w;
    o[4]=b.x*inv*s1.x; o[5]=b.y*inv*s1.y; o[6]=b.z*inv*s1.z; o[7]=b.w*inv*s1.w;
    if (MODE == 0) {
        union { short s[8]; int4 v; } ph, pl;
#pragma unroll
        for (int i = 0; i < 8; ++i) splitf(o[i], ph.s[i], pl.s[i]);
        *(int4*)(ybh + base + tid * 8) = ph.v;
        *(int4*)(ybl + base + tid * 8) = pl.v;
    } else {
        union { short s[8]; int4 v; } ph;
#pragma unroll
        for (int i = 0; i < 8; ++i) ph.s[i] = f2bf(o[i]);
        *(int4*)(ybh + base + tid * 8) = ph.v;
        float4 w0; w0.x=o[0]; w0.y=o[1]; w0.z=o[2]; w0.w=o[3];
        float4 w1; w1.x=o[4]; w1.y=o[5]; w1.z=o[6]; w1.w=o[7];
        *(float4*)(yf + base + tid * 8) = w0;
        *(float4*)(yf + base + tid * 8 + 4) = w1;
    }
}

// -------- split+transpose weights: W[K][N] fp32 -> Thi/Tlo[N][K] bf16 --------
__global__ __launch_bounds__(256)
void splitw_k(const float* __restrict__ W, short* __restrict__ Thi, short* __restrict__ Tlo,
              int K, int N)
{
    __shared__ float t[64][65];
    int k0 = blockIdx.x * 64, n0 = blockIdx.y * 64;
    int tid = threadIdx.x;
    int rr = tid >> 4, cc = (tid & 15) * 4;
#pragma unroll
    for (int i = 0; i < 4; ++i) {
        int row = rr + i * 16;
        float4 v = *(const float4*)(W + (long)(k0 + row) * N + n0 + cc);
        t[row][cc] = v.x; t[row][cc+1] = v.y; t[row][cc+2] = v.z; t[row][cc+3] = v.w;
    }
    __syncthreads();
    int n = tid >> 2, kc = (tid & 3) * 16;
    union { short s[16]; int4 v[2]; } uh, ul;
#pragma unroll
    for (int j = 0; j < 16; ++j) splitf(t[kc + j][n], uh.s[j], ul.s[j]);
    long ob = (long)(n0 + n) * K + k0 + kc;
    *(int4*)(Thi + ob) = uh.v[0];
    *(int4*)(Thi + ob + 8) = uh.v[1];
    *(int4*)(Tlo + ob) = ul.v[0];
    *(int4*)(Tlo + ob + 8) = ul.v[1];
}

// ------- Split GEMM, LDS-free: C[M,N] = (Ahi+Alo)[M][K] @ (BThi+BTlo)[N][K]^T -------
// EPI 0: Cf=acc ; 1: Cf=acc+addb ; 2: split acc -> Ohi/Olo bf16 planes
template<int EPI>
__global__ __launch_bounds__(256)
void gemmsp2_k(const short* __restrict__ Ahi, const short* __restrict__ Alo,
               const short* __restrict__ BThi, const short* __restrict__ BTlo,
               float* __restrict__ Cf, const float* __restrict__ addb,
               short* __restrict__ Ohi, short* __restrict__ Olo,
               int N, int K)
{
    int nby = gridDim.y;
    int total = gridDim.x * nby;
    int lin = blockIdx.x + gridDim.x * blockIdx.y;
    int vt = xcd_swz(lin, total);
    int row0 = (vt / nby) * 128, col0 = (vt % nby) * 128;
    int tid = threadIdx.x, w = tid >> 6, l = tid & 63, g = l >> 4, lr = l & 15;
    int wr = w >> 1, wc = w & 1;
    const short* pah = Ahi + (long)(row0 + wr * 64 + lr) * K + 8 * g;
    const short* pal = Alo + (long)(row0 + wr * 64 + lr) * K + 8 * g;
    const short* pbh = BThi + (long)(col0 + wc * 64 + lr) * K + 8 * g;
    const short* pbl = BTlo + (long)(col0 + wc * 64 + lr) * K + 8 * g;
    long mstr = (long)16 * K;
    f32x4 acc[4][4];
#pragma unroll
    for (int m = 0; m < 4; ++m)
#pragma unroll
        for (int n = 0; n < 4; ++n) acc[m][n] = (f32x4){0,0,0,0};
#pragma unroll 2
    for (int kk = 0; kk < K; kk += 32) {
        bf16x8 ah[4], al[4], bh[4], bl[4];
#pragma unroll
        for (int m = 0; m < 4; ++m) {
            ah[m] = *(const bf16x8*)(pah + m * mstr + kk);
            al[m] = *(const bf16x8*)(pal + m * mstr + kk);
        }
#pragma unroll
        for (int n = 0; n < 4; ++n) {
            bh[n] = *(const bf16x8*)(pbh + n * mstr + kk);
            bl[n] = *(const bf16x8*)(pbl + n * mstr + kk);
        }
#pragma unroll
        for (int m = 0; m < 4; ++m)
#pragma unroll
            for (int n = 0; n < 4; ++n) {
                acc[m][n] = __builtin_amdgcn_mfma_f32_16x16x32_bf16(al[m], bh[n], acc[m][n], 0, 0, 0);
                acc[m][n] = __builtin_amdgcn_mfma_f32_16x16x32_bf16(ah[m], bl[n], acc[m][n], 0, 0, 0);
                acc[m][n] = __builtin_amdgcn_mfma_f32_16x16x32_bf16(ah[m], bh[n], acc[m][n], 0, 0, 0);
            }
    }
#pragma unroll
    for (int m = 0; m < 4; ++m)
#pragma unroll
        for (int n = 0; n < 4; ++n)
#pragma unroll
            for (int j = 0; j < 4; ++j) {
                int row = row0 + wr * 64 + m * 16 + 4 * g + j;
                int col = col0 + wc * 64 + n * 16 + lr;
                float v = acc[m][n][j];
                if (EPI == 0) Cf[(long)row * N + col] = v;
                else if (EPI == 1) Cf[(long)row * N + col] = v + addb[(long)row * N + col];
                else {
                    short hh, ll;
                    splitf(v, hh, ll);
                    Ohi[(long)row * N + col] = hh;
                    Olo[(long)row * N + col] = ll;
                }
            }
}

// ---------------- bf16 GEMM, 128x128 tile, acc=64 regs/wave, 2-deep prefetch ----------------
// EPI 1: Cf=acc+addb ; 3: Cbf=bf16(acc) ; 5: Cbf=bf16(silu(gsrc)*acc) ;
// EPI 4: atomicAdd(Cf[tok*DIM+col], wslot[row]*acc)
template<int EPI, bool GATHER, bool EXPERT>
__global__ __launch_bounds__(256)
void gemm_k(const short* __restrict__ A, const float* __restrict__ Bg,
            float* __restrict__ Cf, short* __restrict__ Cbf,
            const float* __restrict__ addb, const short* __restrict__ gsrc,
            int N, int K,
            const int* __restrict__ rowmap, const int* __restrict__ tile_e,
            const int* __restrict__ tile_base, const int* __restrict__ ntiles,
            long strideB, const float* __restrict__ wslot)
{
    int nby = gridDim.y;
    int total = gridDim.x * nby;
    int lin = blockIdx.x + gridDim.x * blockIdx.y;
    int vt = xcd_swz(lin, total);
    int bx = vt / nby, by = vt % nby;
    int row0;
    const float* B;
    if (EXPERT) {
        if (bx >= *ntiles) return;
        int e = tile_e[bx];
        row0 = tile_base[bx];
        B = Bg + (long)e * strideB;
    } else {
        row0 = bx * 128; B = Bg;
    }
    int col0 = by * 128;
    __shared__ short As[5120], Bs[5120];
    int tid = threadIdx.x;
    int w = tid >> 6, l = tid & 63, g = l >> 4, lr = l & 15;
    int wr = w >> 1, wc = w & 1;
    f32x4 acc[4][4];
#pragma unroll
    for (int m = 0; m < 4; ++m)
#pragma unroll
        for (int n = 0; n < 4; ++n) acc[m][n] = (f32x4){0,0,0,0};
    int ar = tid >> 2, ak = (tid & 3) * 8;
    int bk0 = (tid >> 5) * 4, bc0 = (tid & 31) * 4;
    bool rok[2]; const short* abase[2];
#pragma unroll
    for (int it = 0; it < 2; ++it) {
        int r = row0 + ar + it * 64;
        int sr = GATHER ? rowmap[r] : r;
        rok[it] = (!GATHER) || (sr >= 0);
        abase[it] = A + (long)(rok[it] ? sr : 0) * K + ak;
    }
    const float* bb = B + (long)bk0 * N + col0 + bc0;
    int4 aE[2], aO[2];
    float4 bE[4], bO[4];
#pragma unroll
    for (int it = 0; it < 2; ++it) {
        aE[it] = rok[it] ? *(const int4*)(abase[it]) : (int4){0,0,0,0};
        aO[it] = rok[it] ? *(const int4*)(abase[it] + 32) : (int4){0,0,0,0};
    }
#pragma unroll
    for (int q = 0; q < 4; ++q) {
        bE[q] = *(const float4*)(bb + (long)q * N);
        bO[q] = *(const float4*)(bb + (long)(32 + q) * N);
    }

#define GEMM_STEP(BANKA, BANKB, KNEXT)                                        \
    {                                                                         \
        __syncthreads();                                                      \
        _Pragma("unroll")                                                     \
        for (int it = 0; it < 2; ++it)                                        \
            *(int4*)(As + (ar + it * 64) * 40 + ak) = BANKA[it];              \
        _Pragma("unroll")                                                     \
        for (int j = 0; j < 4; ++j) {                                         \
            short4 pk;                                                        \
            pk.x = f2bf(((const float*)&BANKB[0])[j]);                        \
            pk.y = f2bf(((const float*)&BANKB[1])[j]);                        \
            pk.z = f2bf(((const float*)&BANKB[2])[j]);                        \
            pk.w = f2bf(((const float*)&BANKB[3])[j]);                        \
            int c = bc0 + j;                                                  \
            int blk = (bk0 >> 3) ^ ((c >> 2) & 3);                            \
            *(short4*)(Bs + c * 40 + blk * 8 + (bk0 & 4)) = pk;               \
        }                                                                     \
        if ((KNEXT) < K) {                                                    \
            _Pragma("unroll")                                                 \
            for (int it = 0; it < 2; ++it)                                    \
                BANKA[it] = rok[it] ? *(const int4*)(abase[it] + (KNEXT))     \
                                    : (int4){0,0,0,0};                        \
            _Pragma("unroll")                                                 \
            for (int q = 0; q < 4; ++q)                                       \
                BANKB[q] = *(const float4*)(bb + (long)((KNEXT) + q) * N);    \
        }                                                                     \
        __syncthreads();                                                      \
        bf16x8 af[4], bf[4];                                                  \
        _Pragma("unroll")                                                     \
        for (int m = 0; m < 4; ++m)                                           \
            af[m] = *(const bf16x8*)(As + (wr * 64 + m * 16 + lr) * 40 + g * 8); \
        _Pragma("unroll")                                                     \
        for (int n = 0; n < 4; ++n) {                                         \
            int c = wc * 64 + n * 16 + lr;                                    \
            int blk = g ^ ((c >> 2) & 3);                                     \
            bf[n] = *(const bf16x8*)(Bs + c * 40 + blk * 8);                  \
        }                                                                     \
        _Pragma("unroll")                                                     \
        for (int m = 0; m < 4; ++m)                                           \
            _Pragma("unroll")                                                 \
            for (int n = 0; n < 4; ++n)                                       \
                acc[m][n] = __builtin_amdgcn_mfma_f32_16x16x32_bf16(af[m], bf[n], acc[m][n], 0, 0, 0); \
    }

    for (int kk = 0; kk < K; kk += 64) {
        GEMM_STEP(aE, bE, kk + 64)
        GEMM_STEP(aO, bO, kk + 96)
    }
#undef GEMM_STEP

#pragma unroll
    for (int m = 0; m < 4; ++m)
#pragma unroll
        for (int n = 0; n < 4; ++n)
#pragma unroll
            for (int j = 0; j < 4; ++j) {
                int row = row0 + wr * 64 + m * 16 + 4 * g + j;
                int col = col0 + wc * 64 + n * 16 + lr;
                float v = acc[m][n][j];
                if (EPI == 1) Cf[(long)row * N + col] = v + addb[(long)row * N + col];
                else if (EPI == 3) Cbf[(long)row * N + col] = f2bf(v);
                else if (EPI == 5) {
                    float gv_ = bf2f(gsrc[(long)row * N + col]);
                    float sg = gv_ / (1.f + __expf(-gv_));
                    Cbf[(long)row * N + col] = f2bf(sg * v);
                } else if (EPI == 4) {
                    int tok = rowmap[row];
                    if (tok >= 0) atomicAdd(&Cf[(long)tok * DIM + col], wslot[row] * v);
                }
            }
}

// ---------------- qk-norm + neox RoPE + scale -> split bf16 planes ----------------
__global__ __launch_bounds__(256)
void rope2_k(const float* __restrict__ qf, const float* __restrict__ kf,
             const float* __restrict__ qn, const float* __restrict__ kn,
             const int* __restrict__ posp,
             short* __restrict__ qhi, short* __restrict__ qlo,
             short* __restrict__ khi, short* __restrict__ klo)
{
    int t = blockIdx.x;
    int w = threadIdx.x >> 6, l = threadIdx.x & 63;
    int hi = blockIdx.y * 4 + w;   // 0..19
    const float* src; const float* nrm; float esc;
    short* dh; short* dl;
    if (hi < NQ) {
        long off = (long)t * DIM + hi * HDIM;
        src = qf + off; nrm = qn; dh = qhi + off; dl = qlo + off;
        esc = 0.08838834764831843f;  // HD^-0.5 folded into q
    } else {
        int kh = hi - NQ;
        long off = (long)t * (NKV * HDIM) + kh * HDIM;
        src = kf + off; nrm = kn; dh = khi + off; dl = klo + off;
        esc = 1.f;
    }
    float x1 = src[l], x2 = src[l + 64];
    float ss = x1 * x1 + x2 * x2;
#pragma unroll
    for (int off = 32; off > 0; off >>= 1) ss += __shfl_xor(ss, off);
    float inv = rsqrtf(ss * (1.f / HDIM) + 1e-6f);
    float a1 = x1 * inv * nrm[l], a2 = x2 * inv * nrm[l + 64];
    float p = (float)posp[t];
    float fr = expf((float)l * -0.21586735246819178f); // -ln(1e6)/64
    float ang = p * fr;
    float cv = cosf(ang), sv = sinf(ang);
    float v1 = (a1 * cv - a2 * sv) * esc;
    float v2 = (a1 * sv + a2 * cv) * esc;
    short hh, ll;
    splitf(v1, hh, ll); dh[l] = hh; dl[l] = ll;
    splitf(v2, hh, ll); dh[l + 64] = hh; dl[l + 64] = ll;
}

// ---------------- flash attention (causal, GQA) — pre-split bf16 inputs ----------------
__global__ __launch_bounds__(256)
void attn_k(const short* __restrict__ qhi, const short* __restrict__ qlo,
            const short* __restrict__ khi, const short* __restrict__ klo,
            const short* __restrict__ vhi, const short* __restrict__ vlo,
            short* __restrict__ ohi, short* __restrict__ olo)
{
    int blk = blockIdx.x;
    int qt = blk & 15, bh = blk >> 4;
    int h = bh & (NQ - 1), b = bh >> 4;
    int kvh = h >> 2;
    int tid = threadIdx.x;
    int w = tid >> 6, l = tid & 63, g = l >> 4, lr = l & 15;
    int q0 = qt * 64, qbase = q0 + w * 16;
    long qoff = (long)(b * SEQ + qbase + lr) * DIM + h * HDIM + 8 * g;
    bf16x8 qh[4], ql[4];
#pragma unroll
    for (int kc = 0; kc < 4; ++kc) {
        qh[kc] = *(const bf16x8*)(qhi + qoff + kc * 32);
        ql[kc] = *(const bf16x8*)(qlo + qoff + kc * 32);
    }
    f32x4 o[8];
#pragma unroll
    for (int i = 0; i < 8; ++i) o[i] = (f32x4){0,0,0,0};
    float mr[4] = {-1e30f, -1e30f, -1e30f, -1e30f};
    float ls[4] = {0, 0, 0, 0};
    __shared__ short Vth[5120], Vtl[5120];      // [hd][40 keys]
    __shared__ short Plh[2560], Pll[2560];      // per-wave [16 q][40 keys]
    int nsteps = 2 * (qt + 1);
    for (int st = 0; st < nsteps; ++st) {
        int kb = st * 32;
        __syncthreads();
        {   // stage V transposed (already split): Vt[hd][key]
            int key = tid >> 3, hx = (tid & 7) * 16;
            long voff = (long)(b * SEQ + kb + key) * (NKV * HDIM) + kvh * HDIM + hx;
            union { int4 v; short s[8]; } h0, h1, l0, l1;
            h0.v = *(const int4*)(vhi + voff);
            h1.v = *(const int4*)(vhi + voff + 8);
            l0.v = *(const int4*)(vlo + voff);
            l1.v = *(const int4*)(vlo + voff + 8);
#pragma unroll
            for (int i = 0; i < 8; ++i) {
                Vth[(hx + i) * 40 + key] = h0.s[i];
                Vth[(hx + 8 + i) * 40 + key] = h1.s[i];
                Vtl[(hx + i) * 40 + key] = l0.s[i];
                Vtl[(hx + 8 + i) * 40 + key] = l1.s[i];
            }
        }
        __syncthreads();
        f32x4 sa[2]; sa[0] = (f32x4){0,0,0,0}; sa[1] = (f32x4){0,0,0,0};
#pragma unroll
        for (int kc = 0; kc < 4; ++kc)
#pragma unroll
            for (int n = 0; n < 2; ++n) {
                long koff = (long)(b * SEQ + kb + n * 16 + lr) * (NKV * HDIM) + kvh * HDIM + kc * 32 + 8 * g;
                bf16x8 kh = *(const bf16x8*)(khi + koff);
                bf16x8 kl = *(const bf16x8*)(klo + koff);
                sa[n] = __builtin_amdgcn_mfma_f32_16x16x32_bf16(ql[kc], kh, sa[n], 0, 0, 0);
                sa[n] = __builtin_amdgcn_mfma_f32_16x16x32_bf16(qh[kc], kl, sa[n], 0, 0, 0);
                sa[n] = __builtin_amdgcn_mfma_f32_16x16x32_bf16(qh[kc], kh, sa[n], 0, 0, 0);
            }
        // causal mask
#pragma unroll
        for (int n = 0; n < 2; ++n)
#pragma unroll
            for (int j = 0; j < 4; ++j) {
                int key = kb + n * 16 + lr;
                int qr = qbase + 4 * g + j;
                if (key > qr) sa[n][j] = -1e30f;
            }
        // online softmax (fp32), P stored as hi/lo bf16 planes
#pragma unroll
        for (int j = 0; j < 4; ++j) {
            float v = fmaxf(sa[0][j], sa[1][j]);
#pragma unroll
            for (int off = 1; off < 16; off <<= 1) v = fmaxf(v, __shfl_xor(v, off));
            float mn = fmaxf(mr[j], v);
            float sc = __expf(mr[j] - mn);
            mr[j] = mn;
            float p0 = __expf(sa[0][j] - mn);
            float p1 = __expf(sa[1][j] - mn);
            float rs = p0 + p1;
#pragma unroll
            for (int off = 1; off < 16; off <<= 1) rs += __shfl_xor(rs, off);
            ls[j] = ls[j] * sc + rs;
            short hh, ll;
            splitf(p0, hh, ll);
            Plh[w * 640 + (4 * g + j) * 40 + lr] = hh;
            Pll[w * 640 + (4 * g + j) * 40 + lr] = ll;
            splitf(p1, hh, ll);
            Plh[w * 640 + (4 * g + j) * 40 + 16 + lr] = hh;
            Pll[w * 640 + (4 * g + j) * 40 + 16 + lr] = ll;
#pragma unroll
            for (int nf = 0; nf < 8; ++nf) o[nf][j] *= sc;
        }
        asm volatile("s_waitcnt lgkmcnt(0)" ::: "memory");
        bf16x8 pah = *(const bf16x8*)(Plh + w * 640 + lr * 40 + 8 * g);
        bf16x8 pal = *(const bf16x8*)(Pll + w * 640 + lr * 40 + 8 * g);
#pragma unroll
        for (int nf = 0; nf < 8; ++nf) {
            bf16x8 vh = *(const bf16x8*)(Vth + (nf * 16 + lr) * 40 + 8 * g);
            bf16x8 vl = *(const bf16x8*)(Vtl + (nf * 16 + lr) * 40 + 8 * g);
            o[nf] = __builtin_amdgcn_mfma_f32_16x16x32_bf16(pal, vh, o[nf], 0, 0, 0);
            o[nf] = __builtin_amdgcn_mfma_f32_16x16x32_bf16(pah, vl, o[nf], 0, 0, 0);
            o[nf] = __builtin_amdgcn_mfma_f32_16x16x32_bf16(pah, vh, o[nf], 0, 0, 0);
        }
    }
    float invl[4];
#pragma unroll
    for (int j = 0; j < 4; ++j) invl[j] = 1.f / ls[j];
#pragma unroll
    for (int nf = 0; nf < 8; ++nf)
#pragma unroll
        for (int j = 0; j < 4; ++j) {
            long idx = (long)(b * SEQ + qbase + 4 * g + j) * DIM + h * HDIM + nf * 16 + lr;
            short hh, ll;
            splitf(o[nf][j] * invl[j], hh, ll);
            ohi[idx] = hh;
            olo[idx] = ll;
        }
}

// ---------------- router: sigmoid gate + top-4 + renorm ----------------
__global__ __launch_bounds__(256)
void router_k(const float* __restrict__ x, const float* __restrict__ gw,
              float* __restrict__ topw, int* __restrict__ topi,
              int* __restrict__ posb, int* __restrict__ counts)
{
    int t = blockIdx.x, tid = threadIdx.x;
    int e = tid & 31, ch = tid >> 5;
    const float* xp = x + (long)t * DIM + ch * 256;
    float p = 0.f;
    for (int d = 0; d < 256; ++d) p += xp[d] * gw[(ch * 256 + d) * NE + e];
    __shared__ float red[8][32];
    __shared__ float gv[32];
    red[ch][e] = p;
    __syncthreads();
    if (tid < 32) {
        float s = 0.f;
        for (int c = 0; c < 8; ++c) s += red[c][tid];
        gv[tid] = 1.f / (1.f + expf(-s));
    }
    __syncthreads();
    if (tid == 0) {
        float lg[32];
        for (int i = 0; i < 32; ++i) lg[i] = gv[i];
        float tv[TOPK]; int ti[TOPK]; float wsum = 0.f;
        for (int j = 0; j < TOPK; ++j) {
            float bv = -1e30f; int bi = 0;
            for (int i = 0; i < 32; ++i) if (lg[i] > bv) { bv = lg[i]; bi = i; }
            tv[j] = bv; ti[j] = bi; lg[bi] = -1e30f; wsum += bv;
        }
        float r = 1.f / wsum;
        for (int j = 0; j < TOPK; ++j) {
            topw[t * TOPK + j] = tv[j] * r;
            topi[t * TOPK + j] = ti[j];
            posb[t * TOPK + j] = atomicAdd(&counts[ti[j]], 1);
        }
    }
}

__global__ void initmoe_k(int* __restrict__ rowmap, float* __restrict__ wslot, int* __restrict__ counts)
{
    int i = blockIdx.x * 256 + threadIdx.x;
    if (i < MAXROWS) { rowmap[i] = -1; wslot[i] = 0.f; }
    if (i < NE) counts[i] = 0;
}

__global__ void prep_k(const int* __restrict__ counts, int* __restrict__ padoff,
                       int* __restrict__ tile_e, int* __restrict__ tile_base, int* __restrict__ ntl)
{
    if (threadIdx.x == 0 && blockIdx.x == 0) {
        int nt = 0, rb = 0;
        for (int e = 0; e < NE; ++e) {
            padoff[e] = rb;
            int c = counts[e];
            int te = (c + 127) >> 7;
            for (int i = 0; i < te; ++i) { tile_e[nt] = e; tile_base[nt] = rb + i * 128; ++nt; }
            rb += te * 128;
        }
        *ntl = nt;
    }
}

__global__ void scatter_k(const int* __restrict__ topi, const float* __restrict__ topw,
                          const int* __restrict__ posb, const int* __restrict__ padoff,
                          int* __restrict__ rowmap, float* __restrict__ wslot)
{
    int i = blockIdx.x * 256 + threadIdx.x;
    if (i < T_TOK * TOPK) {
        int e = topi[i];
        int s = padoff[e] + posb[i];
        rowmap[s] = i >> 2;
        wslot[s] = topw[i];
    }
}

// ---------------- launch ----------------
extern "C" void kernel_launch(void* const* d_in, const int* in_sizes, int n_in,
                              void* d_out, int out_size, void* d_ws, size_t ws_size,
                              hipStream_t stream)
{
    (void)in_sizes; (void)n_in; (void)out_size; (void)ws_size;
    const int*   positions = (const int*)  d_in[0];
    const float* hidden    = (const float*)d_in[1];
    const float* in_ln     = (const float*)d_in[2];
    const float* post_ln   = (const float*)d_in[3];
    const float* q_norm    = (const float*)d_in[4];
    const float* k_norm    = (const float*)d_in[5];
    const float* wq        = (const float*)d_in[6];
    const float* wk        = (const float*)d_in[7];
    const float* wv        = (const float*)d_in[8];
    const float* wo        = (const float*)d_in[9];
    const float* gate_w    = (const float*)d_in[10];
    const float* sh_wg     = (const float*)d_in[11];
    const float* sh_wu     = (const float*)d_in[12];
    const float* sh_wd     = (const float*)d_in[13];
    const float* e_wg      = (const float*)d_in[14];
    const float* e_wu      = (const float*)d_in[15];
    const float* e_wd      = (const float*)d_in[16];
    float* out = (float*)d_out;
    char* ws = (char*)d_ws;

    // lifetime-overlapped workspace map (1M = 1048576 bytes):
    short* hfhi    = (short*)(ws + 0);          // [0,8M)   -> gatesh later
    short* hflo    = (short*)(ws + 8388608);    // [8,16M)  -> shint later
    short* gatesh  = (short*)(ws + 0);
    short* shint   = (short*)(ws + 8388608);
    short* wqThi   = (short*)(ws + 16777216);   // [16,24M) -> h2 later
    short* wqTlo   = (short*)(ws + 25165824);   // [24,32M)
    float* h2      = (float*)(ws + 16777216);   // [16,32M)
    short* wkThi   = (short*)(ws + 33554432);   // [32,34M) -> h2lnbf later
    short* wkTlo   = (short*)(ws + 35651584);   // [34,36M)
    short* wvThi   = (short*)(ws + 37748736);   // [36,38M)
    short* wvTlo   = (short*)(ws + 39845888);   // [38,40M)
    short* h2lnbf  = (short*)(ws + 33554432);   // [32,40M)
    short* woThi   = (short*)(ws + 41943040);   // [40,48M) -> h2lnf later
    short* woTlo   = (short*)(ws + 50331648);   // [48,56M)
    float* h2lnf   = (float*)(ws + 41943040);   // [40,56M)
    short* qhi     = (short*)(ws + 58720256);   // [56,64M) -> gate_e region
    short* qlo     = (short*)(ws + 67108864);   // [64,72M)
    short* khi     = (short*)(ws + 75497472);   // [72,74M)
    short* klo     = (short*)(ws + 77594624);   // [74,76M)
    short* vhi     = (short*)(ws + 79691776);   // [76,78M)
    short* vlo     = (short*)(ws + 81788928);   // [78,80M)
    short* attnhi  = (short*)(ws + 83886080);   // [80,88M)
    short* attnlo  = (short*)(ws + 92274688);   // [88,96M) -> interbf region
    short* gate_e  = (short*)(ws + 58720256);   // [56,88M)
    short* interbf = (short*)(ws + 92274688);   // [88,120M)
    float* qf      = (float*)(ws + 100663296);  // [96,112M) dead before interbf use
    float* kf      = (float*)(ws + 117440512);  // [112,116M)
    float* topw    = (float*)(ws + 125829120);
    int*   topi    = (int*)  (ws + 125861888);
    int*   posb    = (int*)  (ws + 125894656);
    int*   counts  = (int*)  (ws + 125927424);
    int*   padoff  = (int*)  (ws + 125927680);
    int*   ntl     = (int*)  (ws + 125927936);
    int*   tile_e  = (int*)  (ws + 125928192);
    int*   tile_b  = (int*)  (ws + 125928704);
    int*   rowmap  = (int*)  (ws + 125929216);
    float* wslot   = (float*)(ws + 125994752);

    dim3 blk(256);

    // 1) input RMSNorm -> hi/lo bf16 planes
    rmsnorm_k<0><<<T_TOK, blk, 0, stream>>>(hidden, in_ln, hfhi, hflo, nullptr);
    // 1b) pre-split + transpose weights
    splitw_k<<<dim3(32,32), blk, 0, stream>>>(wq, wqThi, wqTlo, 2048, 2048);
    splitw_k<<<dim3(32,8),  blk, 0, stream>>>(wk, wkThi, wkTlo, 2048, 512);
    splitw_k<<<dim3(32,8),  blk, 0, stream>>>(wv, wvThi, wvTlo, 2048, 512);
    splitw_k<<<dim3(32,32), blk, 0, stream>>>(wo, woThi, woTlo, 2048, 2048);
    // 2) QKV projections (split, LDS-free)
    gemmsp2_k<0><<<dim3(16,16), blk, 0, stream>>>(hfhi, hflo, wqThi, wqTlo, qf, nullptr, nullptr, nullptr, 2048, 2048);
    gemmsp2_k<0><<<dim3(16,4),  blk, 0, stream>>>(hfhi, hflo, wkThi, wkTlo, kf, nullptr, nullptr, nullptr,  512, 2048);
    gemmsp2_k<2><<<dim3(16,4),  blk, 0, stream>>>(hfhi, hflo, wvThi, wvTlo, nullptr, nullptr, vhi, vlo,     512, 2048);
    // 3) qk-norm + rope -> split planes (q scaled by HD^-0.5)
    rope2_k<<<dim3(T_TOK,5), blk, 0, stream>>>(qf, kf, q_norm, k_norm, positions, qhi, qlo, khi, klo);
    // 4) causal flash attention -> split output
    attn_k<<<512, blk, 0, stream>>>(qhi, qlo, khi, klo, vhi, vlo, attnhi, attnlo);
    // 5) output projection + residual
    gemmsp2_k<1><<<dim3(16,16), blk, 0, stream>>>(attnhi, attnlo, woThi, woTlo, h2, hidden, nullptr, nullptr, 2048, 2048);
    // 6) post-attn RMSNorm (bf16 for experts + fp32 for router)
    rmsnorm_k<1><<<T_TOK, blk, 0, stream>>>(h2, post_ln, h2lnbf, nullptr, h2lnf);
    // 7) router + MoE bookkeeping
    initmoe_k<<<64, blk, 0, stream>>>(rowmap, wslot, counts);
    router_k<<<T_TOK, blk, 0, stream>>>(h2lnf, gate_w, topw, topi, posb, counts);
    prep_k<<<1, 64, 0, stream>>>(counts, padoff, tile_e, tile_b, ntl);
    scatter_k<<<32, blk, 0, stream>>>(topi, topw, posb, padoff, rowmap, wslot);
    // 8) shared expert: gate -> bf16 tmp, up (silu-fused), down (+resid into out)
    gemm_k<3,false,false><<<dim3(16,16), blk, 0, stream>>>(h2lnbf, sh_wg, nullptr, gatesh, nullptr, nullptr, 2048, 2048, nullptr, nullptr, nullptr, nullptr, 0, nullptr);
    gemm_k<5,false,false><<<dim3(16,16), blk, 0, stream>>>(h2lnbf, sh_wu, nullptr, shint, nullptr, gatesh, 2048, 2048, nullptr, nullptr, nullptr, nullptr, 0, nullptr);
    gemm_k<1,false,false><<<dim3(16,16), blk, 0, stream>>>(shint, sh_wd, out, nullptr, h2, nullptr, 2048, 2048, nullptr, nullptr, nullptr, nullptr, 0, nullptr);
    // 9) routed experts: gate -> bf16 tmp, up (silu-fused), down (weighted atomic add)
    gemm_k<3,true,true><<<dim3(MAXTILES,8), blk, 0, stream>>>(h2lnbf, e_wg, nullptr, gate_e, nullptr, nullptr, 1024, 2048, rowmap, tile_e, tile_b, ntl, (long)2048*1024, nullptr);
    gemm_k<5,true,true><<<dim3(MAXTILES,8), blk, 0, stream>>>(h2lnbf, e_wu, nullptr, interbf, nullptr, gate_e, 1024, 2048, rowmap, tile_e, tile_b, ntl, (long)2048*1024, nullptr);
    gemm_k<4,false,true><<<dim3(MAXTILES,16), blk, 0, stream>>>(interbf, e_wd, out, nullptr, nullptr, nullptr, 2048, 1024, rowmap, tile_e, tile_b, ntl, (long)1024*2048, wslot);
}

// Round 9
// 1405.359 us; speedup vs baseline: 1.0644x; 1.0644x over previous
//
#include <hip/hip_runtime.h>

// Problem constants
#define T_TOK 2048   // B*S
#define DIM   2048
#define NQ    16
#define NKV   4
#define HDIM  128
#define NE    32
#define TOPK  4
#define FF    1024
#define FSH   2048
#define SEQ   1024
#define MAXROWS 16384
#define MAXTILES 96

typedef __attribute__((ext_vector_type(4))) float f32x4;
typedef __attribute__((ext_vector_type(8))) short bf16x8;

__device__ __forceinline__ short f2bf(float f) {
    union { float f; unsigned u; } c; c.f = f;
    unsigned r = (c.u + 0x7fffu + ((c.u >> 16) & 1u)) >> 16;
    return (short)r;
}
__device__ __forceinline__ float bf2f(short h) {
    union { unsigned u; float f; } c; c.u = ((unsigned)(unsigned short)h) << 16;
    return c.f;
}
__device__ __forceinline__ void splitf(float v, short& hi, short& lo) {
    hi = f2bf(v);
    lo = f2bf(v - bf2f(hi));
}
// bijective XCD-chunk swizzle (m204)
__device__ __forceinline__ int xcd_swz(int lin, int total) {
    int q8 = total >> 3, r8 = total & 7;
    int xcd = lin & 7, idx = lin >> 3;
    return (xcd < r8 ? xcd * (q8 + 1) : r8 * (q8 + 1) + (xcd - r8) * q8) + idx;
}
// async global->LDS, 16B per lane; lds dest = wave-uniform base + lane*16
__device__ __forceinline__ void gl16(const void* g, void* l) {
    __builtin_amdgcn_global_load_lds(
        (const __attribute__((address_space(1))) unsigned int*)g,
        (__attribute__((address_space(3))) unsigned int*)l, 16, 0, 0);
}

// ---------------- RMSNorm. MODE 0: hi/lo bf16 planes. MODE 1: bf16 + fp32 ----------------
template<int MODE>
__global__ __launch_bounds__(256)
void rmsnorm_k(const float* __restrict__ x, const float* __restrict__ sc,
               short* __restrict__ ybh, short* __restrict__ ybl, float* __restrict__ yf)
{
    long base = (long)blockIdx.x * DIM;
    int tid = threadIdx.x;
    const float* xp = x + base + tid * 8;
    float4 a = *(const float4*)xp;
    float4 b = *(const float4*)(xp + 4);
    float ss = a.x*a.x + a.y*a.y + a.z*a.z + a.w*a.w
             + b.x*b.x + b.y*b.y + b.z*b.z + b.w*b.w;
#pragma unroll
    for (int off = 32; off > 0; off >>= 1) ss += __shfl_xor(ss, off);
    __shared__ float red[4];
    if ((tid & 63) == 0) red[tid >> 6] = ss;
    __syncthreads();
    float s = red[0] + red[1] + red[2] + red[3];
    float inv = rsqrtf(s * (1.f / DIM) + 1e-6f);
    const float* sp = sc + tid * 8;
    float4 s0 = *(const float4*)sp;
    float4 s1 = *(const float4*)(sp + 4);
    float o[8];
    o[0]=a.x*inv*s0.x; o[1]=a.y*inv*s0.y; o[2]=a.z*inv*s0.z; o[3]=a.w*inv*s0.w;
    o[4]=b.x*inv*s1.x; o[5]=b.y*inv*s1.y; o[6]=b.z*inv*s1.z; o[7]=b.w*inv*s1.w;
    if (MODE == 0) {
        union { short s[8]; int4 v; } ph, pl;
#pragma unroll
        for (int i = 0; i < 8; ++i) splitf(o[i], ph.s[i], pl.s[i]);
        *(int4*)(ybh + base + tid * 8) = ph.v;
        *(int4*)(ybl + base + tid * 8) = pl.v;
    } else {
        union { short s[8]; int4 v; } ph;
#pragma unroll
        for (int i = 0; i < 8; ++i) ph.s[i] = f2bf(o[i]);
        *(int4*)(ybh + base + tid * 8) = ph.v;
        float4 w0; w0.x=o[0]; w0.y=o[1]; w0.z=o[2]; w0.w=o[3];
        float4 w1; w1.x=o[4]; w1.y=o[5]; w1.z=o[6]; w1.w=o[7];
        *(float4*)(yf + base + tid * 8) = w0;
        *(float4*)(yf + base + tid * 8 + 4) = w1;
    }
}

// -------- split+transpose weights: W[K][N] fp32 -> Thi/Tlo[N][K] bf16 --------
__global__ __launch_bounds__(256)
void splitw_k(const float* __restrict__ W, short* __restrict__ Thi, short* __restrict__ Tlo,
              int K, int N)
{
    __shared__ float t[64][65];
    int k0 = blockIdx.x * 64, n0 = blockIdx.y * 64;
    int tid = threadIdx.x;
    int rr = tid >> 4, cc = (tid & 15) * 4;
#pragma unroll
    for (int i = 0; i < 4; ++i) {
        int row = rr + i * 16;
        float4 v = *(const float4*)(W + (long)(k0 + row) * N + n0 + cc);
        t[row][cc] = v.x; t[row][cc+1] = v.y; t[row][cc+2] = v.z; t[row][cc+3] = v.w;
    }
    __syncthreads();
    int n = tid >> 2, kc = (tid & 3) * 16;
    union { short s[16]; int4 v[2]; } uh, ul;
#pragma unroll
    for (int j = 0; j < 16; ++j) splitf(t[kc + j][n], uh.s[j], ul.s[j]);
    long ob = (long)(n0 + n) * K + k0 + kc;
    *(int4*)(Thi + ob) = uh.v[0];
    *(int4*)(Thi + ob + 8) = uh.v[1];
    *(int4*)(Tlo + ob) = ul.v[0];
    *(int4*)(Tlo + ob + 8) = ul.v[1];
}

// -------- convert+transpose: W[K][N] fp32 -> T[N][K] bf16 (per blockIdx.z matrix) --------
__global__ __launch_bounds__(256)
void cvtT_k(const float* __restrict__ W, short* __restrict__ T, int K, int N)
{
    __shared__ float t[64][65];
    const float* Wp = W + (long)blockIdx.z * K * N;
    short* Tp = T + (long)blockIdx.z * K * N;
    int k0 = blockIdx.x * 64, n0 = blockIdx.y * 64;
    int tid = threadIdx.x;
    int rr = tid >> 4, cc = (tid & 15) * 4;
#pragma unroll
    for (int i = 0; i < 4; ++i) {
        int row = rr + i * 16;
        float4 v = *(const float4*)(Wp + (long)(k0 + row) * N + n0 + cc);
        t[row][cc] = v.x; t[row][cc+1] = v.y; t[row][cc+2] = v.z; t[row][cc+3] = v.w;
    }
    __syncthreads();
    int n = tid >> 2, kc = (tid & 3) * 16;
    union { short s[16]; int4 v[2]; } u;
#pragma unroll
    for (int j = 0; j < 16; ++j) u.s[j] = f2bf(t[kc + j][n]);
    long ob = (long)(n0 + n) * K + k0 + kc;
    *(int4*)(Tp + ob) = u.v[0];
    *(int4*)(Tp + ob + 8) = u.v[1];
}

// ------- Split GEMM (m97-style): C = (Ahi+Alo)[M][K] @ (BThi+BTlo)[N][K]^T -------
// EPI 0: Cf=acc ; 1: Cf=acc+addb ; 2: split acc -> Ohi/Olo
template<int EPI>
__global__ __launch_bounds__(256)
void gemmsp3_k(const short* __restrict__ Ahi, const short* __restrict__ Alo,
               const short* __restrict__ BThi, const short* __restrict__ BTlo,
               float* __restrict__ Cf, const float* __restrict__ addb,
               short* __restrict__ Ohi, short* __restrict__ Olo,
               int N, int K)
{
    int nby = gridDim.y;
    int total = gridDim.x * nby;
    int lin = blockIdx.x + gridDim.x * blockIdx.y;
    int vt = xcd_swz(lin, total);
    int row0 = (vt / nby) * 128, col0 = (vt % nby) * 128;
    __shared__ short Ah[4096], Al[4096], Bh[4096], Bl[4096];
    int tid = threadIdx.x, w = tid >> 6, l = tid & 63, g = l >> 4, lr = l & 15;
    int wr = w >> 1, wc = w & 1;
    int srt = tid >> 2, klane = (tid & 3) * 8;
    const short* pah0 = Ahi + (long)(row0 + srt) * K + klane;
    const short* pah1 = Ahi + (long)(row0 + srt + 64) * K + klane;
    const short* pal0 = Alo + (long)(row0 + srt) * K + klane;
    const short* pal1 = Alo + (long)(row0 + srt + 64) * K + klane;
    const short* pbh0 = BThi + (long)(col0 + srt) * K + klane;
    const short* pbh1 = BThi + (long)(col0 + srt + 64) * K + klane;
    const short* pbl0 = BTlo + (long)(col0 + srt) * K + klane;
    const short* pbl1 = BTlo + (long)(col0 + srt + 64) * K + klane;
    short* dA = Ah + w * 512;
    short* dAl = Al + w * 512;
    short* dB = Bh + w * 512;
    short* dBl = Bl + w * 512;
    f32x4 acc[4][4];
#pragma unroll
    for (int m = 0; m < 4; ++m)
#pragma unroll
        for (int n = 0; n < 4; ++n) acc[m][n] = (f32x4){0,0,0,0};
    for (int kk = 0; kk < K; kk += 32) {
        gl16(pah0 + kk, dA);        gl16(pah1 + kk, dA + 2048);
        gl16(pal0 + kk, dAl);       gl16(pal1 + kk, dAl + 2048);
        gl16(pbh0 + kk, dB);        gl16(pbh1 + kk, dB + 2048);
        gl16(pbl0 + kk, dBl);       gl16(pbl1 + kk, dBl + 2048);
        asm volatile("s_waitcnt vmcnt(0)" ::: "memory");
        __syncthreads();
        bf16x8 ah[4], al[4], bh[4], bl[4];
#pragma unroll
        for (int m = 0; m < 4; ++m) {
            int off = (wr * 64 + m * 16 + lr) * 32 + g * 8;
            ah[m] = *(const bf16x8*)(Ah + off);
            al[m] = *(const bf16x8*)(Al + off);
        }
#pragma unroll
        for (int n = 0; n < 4; ++n) {
            int off = (wc * 64 + n * 16 + lr) * 32 + g * 8;
            bh[n] = *(const bf16x8*)(Bh + off);
            bl[n] = *(const bf16x8*)(Bl + off);
        }
#pragma unroll
        for (int m = 0; m < 4; ++m)
#pragma unroll
            for (int n = 0; n < 4; ++n) {
                acc[m][n] = __builtin_amdgcn_mfma_f32_16x16x32_bf16(al[m], bh[n], acc[m][n], 0, 0, 0);
                acc[m][n] = __builtin_amdgcn_mfma_f32_16x16x32_bf16(ah[m], bl[n], acc[m][n], 0, 0, 0);
                acc[m][n] = __builtin_amdgcn_mfma_f32_16x16x32_bf16(ah[m], bh[n], acc[m][n], 0, 0, 0);
            }
        __syncthreads();
    }
#pragma unroll
    for (int m = 0; m < 4; ++m)
#pragma unroll
        for (int n = 0; n < 4; ++n)
#pragma unroll
            for (int j = 0; j < 4; ++j) {
                int row = row0 + wr * 64 + m * 16 + 4 * g + j;
                int col = col0 + wc * 64 + n * 16 + lr;
                float v = acc[m][n][j];
                if (EPI == 0) Cf[(long)row * N + col] = v;
                else if (EPI == 1) Cf[(long)row * N + col] = v + addb[(long)row * N + col];
                else {
                    short hh, ll;
                    splitf(v, hh, ll);
                    Ohi[(long)row * N + col] = hh;
                    Olo[(long)row * N + col] = ll;
                }
            }
}

// ------- bf16 GEMM (m97-style): C[M,N] = A[M][K] @ BT[N][K]^T, global_load_lds staging -------
// EPI 1: Cf=acc+addb ; 3: Cbf=bf16(acc) ; 5: Cbf=bf16(silu(gsrc)*acc) ;
// EPI 4: atomicAdd(Cf[tok*DIM+col], wslot[row]*acc)
template<int EPI, bool GATHER, bool EXPERT>
__global__ __launch_bounds__(256)
void gemm3_k(const short* __restrict__ A, const short* __restrict__ BTg,
             float* __restrict__ Cf, short* __restrict__ Cbf,
             const float* __restrict__ addb, const short* __restrict__ gsrc,
             int N, int K,
             const int* __restrict__ rowmap, const int* __restrict__ tile_e,
             const int* __restrict__ tile_base, const int* __restrict__ ntiles,
             long strideBT, const float* __restrict__ wslot,
             const short* __restrict__ zbuf)
{
    int nby = gridDim.y;
    int total = gridDim.x * nby;
    int lin = blockIdx.x + gridDim.x * blockIdx.y;
    int vt = xcd_swz(lin, total);
    int bx = vt / nby, by = vt % nby;
    int row0;
    const short* BT;
    if (EXPERT) {
        if (bx >= *ntiles) return;
        int e = tile_e[bx];
        row0 = tile_base[bx];
        BT = BTg + (long)e * strideBT;
    } else {
        row0 = bx * 128; BT = BTg;
    }
    int col0 = by * 128;
    __shared__ short As[4096], Bs[4096];
    int tid = threadIdx.x, w = tid >> 6, l = tid & 63, g = l >> 4, lr = l & 15;
    int wr = w >> 1, wc = w & 1;
    int srt = tid >> 2, klane = (tid & 3) * 8;
    const short *ap0, *ap1;
    if (GATHER) {
        int r0 = rowmap[row0 + srt], r1 = rowmap[row0 + srt + 64];
        ap0 = (r0 >= 0) ? (A + (long)r0 * K + klane) : (zbuf + klane);
        ap1 = (r1 >= 0) ? (A + (long)r1 * K + klane) : (zbuf + klane);
    } else {
        ap0 = A + (long)(row0 + srt) * K + klane;
        ap1 = A + (long)(row0 + srt + 64) * K + klane;
    }
    const short* bp0 = BT + (long)(col0 + srt) * K + klane;
    const short* bp1 = BT + (long)(col0 + srt + 64) * K + klane;
    short* dA = As + w * 512;
    short* dB = Bs + w * 512;
    f32x4 acc[4][4];
#pragma unroll
    for (int m = 0; m < 4; ++m)
#pragma unroll
        for (int n = 0; n < 4; ++n) acc[m][n] = (f32x4){0,0,0,0};
    for (int kk = 0; kk < K; kk += 32) {
        gl16(ap0 + kk, dA);  gl16(ap1 + kk, dA + 2048);
        gl16(bp0 + kk, dB);  gl16(bp1 + kk, dB + 2048);
        asm volatile("s_waitcnt vmcnt(0)" ::: "memory");
        __syncthreads();
        bf16x8 af[4], bf[4];
#pragma unroll
        for (int m = 0; m < 4; ++m)
            af[m] = *(const bf16x8*)(As + (wr * 64 + m * 16 + lr) * 32 + g * 8);
#pragma unroll
        for (int n = 0; n < 4; ++n)
            bf[n] = *(const bf16x8*)(Bs + (wc * 64 + n * 16 + lr) * 32 + g * 8);
#pragma unroll
        for (int m = 0; m < 4; ++m)
#pragma unroll
            for (int n = 0; n < 4; ++n)
                acc[m][n] = __builtin_amdgcn_mfma_f32_16x16x32_bf16(af[m], bf[n], acc[m][n], 0, 0, 0);
        __syncthreads();
    }
#pragma unroll
    for (int m = 0; m < 4; ++m)
#pragma unroll
        for (int n = 0; n < 4; ++n)
#pragma unroll
            for (int j = 0; j < 4; ++j) {
                int row = row0 + wr * 64 + m * 16 + 4 * g + j;
                int col = col0 + wc * 64 + n * 16 + lr;
                float v = acc[m][n][j];
                if (EPI == 1) Cf[(long)row * N + col] = v + addb[(long)row * N + col];
                else if (EPI == 3) Cbf[(long)row * N + col] = f2bf(v);
                else if (EPI == 5) {
                    float gv_ = bf2f(gsrc[(long)row * N + col]);
                    float sg = gv_ / (1.f + __expf(-gv_));
                    Cbf[(long)row * N + col] = f2bf(sg * v);
                } else if (EPI == 4) {
                    int tok = rowmap[row];
                    if (tok >= 0) atomicAdd(&Cf[(long)tok * DIM + col], wslot[row] * v);
                }
            }
}

// ---- fallback bf16 GEMM (round-6 proven): fp32 B reg-transpose staging, 2-deep prefetch ----
template<int EPI, bool GATHER, bool EXPERT>
__global__ __launch_bounds__(256)
void gemm_k(const short* __restrict__ A, const float* __restrict__ Bg,
            float* __restrict__ Cf, short* __restrict__ Cbf,
            const float* __restrict__ addb, const short* __restrict__ gsrc,
            int N, int K,
            const int* __restrict__ rowmap, const int* __restrict__ tile_e,
            const int* __restrict__ tile_base, const int* __restrict__ ntiles,
            long strideB, const float* __restrict__ wslot)
{
    int nby = gridDim.y;
    int total = gridDim.x * nby;
    int lin = blockIdx.x + gridDim.x * blockIdx.y;
    int vt = xcd_swz(lin, total);
    int bx = vt / nby, by = vt % nby;
    int row0;
    const float* B;
    if (EXPERT) {
        if (bx >= *ntiles) return;
        int e = tile_e[bx];
        row0 = tile_base[bx];
        B = Bg + (long)e * strideB;
    } else {
        row0 = bx * 128; B = Bg;
    }
    int col0 = by * 128;
    __shared__ short As[5120], Bs[5120];
    int tid = threadIdx.x;
    int w = tid >> 6, l = tid & 63, g = l >> 4, lr = l & 15;
    int wr = w >> 1, wc = w & 1;
    f32x4 acc[4][4];
#pragma unroll
    for (int m = 0; m < 4; ++m)
#pragma unroll
        for (int n = 0; n < 4; ++n) acc[m][n] = (f32x4){0,0,0,0};
    int ar = tid >> 2, ak = (tid & 3) * 8;
    int bk0 = (tid >> 5) * 4, bc0 = (tid & 31) * 4;
    bool rok[2]; const short* abase[2];
#pragma unroll
    for (int it = 0; it < 2; ++it) {
        int r = row0 + ar + it * 64;
        int sr = GATHER ? rowmap[r] : r;
        rok[it] = (!GATHER) || (sr >= 0);
        abase[it] = A + (long)(rok[it] ? sr : 0) * K + ak;
    }
    const float* bb = B + (long)bk0 * N + col0 + bc0;
    int4 aE[2], aO[2];
    float4 bE[4], bO[4];
#pragma unroll
    for (int it = 0; it < 2; ++it) {
        aE[it] = rok[it] ? *(const int4*)(abase[it]) : (int4){0,0,0,0};
        aO[it] = rok[it] ? *(const int4*)(abase[it] + 32) : (int4){0,0,0,0};
    }
#pragma unroll
    for (int q = 0; q < 4; ++q) {
        bE[q] = *(const float4*)(bb + (long)q * N);
        bO[q] = *(const float4*)(bb + (long)(32 + q) * N);
    }

#define GEMM_STEP(BANKA, BANKB, KNEXT)                                        \
    {                                                                         \
        __syncthreads();                                                      \
        _Pragma("unroll")                                                     \
        for (int it = 0; it < 2; ++it)                                        \
            *(int4*)(As + (ar + it * 64) * 40 + ak) = BANKA[it];              \
        _Pragma("unroll")                                                     \
        for (int j = 0; j < 4; ++j) {                                         \
            short4 pk;                                                        \
            pk.x = f2bf(((const float*)&BANKB[0])[j]);                        \
            pk.y = f2bf(((const float*)&BANKB[1])[j]);                        \
            pk.z = f2bf(((const float*)&BANKB[2])[j]);                        \
            pk.w = f2bf(((const float*)&BANKB[3])[j]);                        \
            int c = bc0 + j;                                                  \
            int blk = (bk0 >> 3) ^ ((c >> 2) & 3);                            \
            *(short4*)(Bs + c * 40 + blk * 8 + (bk0 & 4)) = pk;               \
        }                                                                     \
        if ((KNEXT) < K) {                                                    \
            _Pragma("unroll")                                                 \
            for (int it = 0; it < 2; ++it)                                    \
                BANKA[it] = rok[it] ? *(const int4*)(abase[it] + (KNEXT))     \
                                    : (int4){0,0,0,0};                        \
            _Pragma("unroll")                                                 \
            for (int q = 0; q < 4; ++q)                                       \
                BANKB[q] = *(const float4*)(bb + (long)((KNEXT) + q) * N);    \
        }                                                                     \
        __syncthreads();                                                      \
        bf16x8 af[4], bf[4];                                                  \
        _Pragma("unroll")                                                     \
        for (int m = 0; m < 4; ++m)                                           \
            af[m] = *(const bf16x8*)(As + (wr * 64 + m * 16 + lr) * 40 + g * 8); \
        _Pragma("unroll")                                                     \
        for (int n = 0; n < 4; ++n) {                                         \
            int c = wc * 64 + n * 16 + lr;                                    \
            int blk = g ^ ((c >> 2) & 3);                                     \
            bf[n] = *(const bf16x8*)(Bs + c * 40 + blk * 8);                  \
        }                                                                     \
        _Pragma("unroll")                                                     \
        for (int m = 0; m < 4; ++m)                                           \
            _Pragma("unroll")                                                 \
            for (int n = 0; n < 4; ++n)                                       \
                acc[m][n] = __builtin_amdgcn_mfma_f32_16x16x32_bf16(af[m], bf[n], acc[m][n], 0, 0, 0); \
    }

    for (int kk = 0; kk < K; kk += 64) {
        GEMM_STEP(aE, bE, kk + 64)
        GEMM_STEP(aO, bO, kk + 96)
    }
#undef GEMM_STEP

#pragma unroll
    for (int m = 0; m < 4; ++m)
#pragma unroll
        for (int n = 0; n < 4; ++n)
#pragma unroll
            for (int j = 0; j < 4; ++j) {
                int row = row0 + wr * 64 + m * 16 + 4 * g + j;
                int col = col0 + wc * 64 + n * 16 + lr;
                float v = acc[m][n][j];
                if (EPI == 1) Cf[(long)row * N + col] = v + addb[(long)row * N + col];
                else if (EPI == 3) Cbf[(long)row * N + col] = f2bf(v);
                else if (EPI == 5) {
                    float gv_ = bf2f(gsrc[(long)row * N + col]);
                    float sg = gv_ / (1.f + __expf(-gv_));
                    Cbf[(long)row * N + col] = f2bf(sg * v);
                } else if (EPI == 4) {
                    int tok = rowmap[row];
                    if (tok >= 0) atomicAdd(&Cf[(long)tok * DIM + col], wslot[row] * v);
                }
            }
}

// ---------------- qk-norm + neox RoPE + scale -> split bf16 planes ----------------
__global__ __launch_bounds__(256)
void rope2_k(const float* __restrict__ qf, const float* __restrict__ kf,
             const float* __restrict__ qn, const float* __restrict__ kn,
             const int* __restrict__ posp,
             short* __restrict__ qhi, short* __restrict__ qlo,
             short* __restrict__ khi, short* __restrict__ klo)
{
    int t = blockIdx.x;
    int w = threadIdx.x >> 6, l = threadIdx.x & 63;
    int hi = blockIdx.y * 4 + w;   // 0..19
    const float* src; const float* nrm; float esc;
    short* dh; short* dl;
    if (hi < NQ) {
        long off = (long)t * DIM + hi * HDIM;
        src = qf + off; nrm = qn; dh = qhi + off; dl = qlo + off;
        esc = 0.08838834764831843f;  // HD^-0.5 folded into q
    } else {
        int kh = hi - NQ;
        long off = (long)t * (NKV * HDIM) + kh * HDIM;
        src = kf + off; nrm = kn; dh = khi + off; dl = klo + off;
        esc = 1.f;
    }
    float x1 = src[l], x2 = src[l + 64];
    float ss = x1 * x1 + x2 * x2;
#pragma unroll
    for (int off = 32; off > 0; off >>= 1) ss += __shfl_xor(ss, off);
    float inv = rsqrtf(ss * (1.f / HDIM) + 1e-6f);
    float a1 = x1 * inv * nrm[l], a2 = x2 * inv * nrm[l + 64];
    float p = (float)posp[t];
    float fr = expf((float)l * -0.21586735246819178f); // -ln(1e6)/64
    float ang = p * fr;
    float cv = cosf(ang), sv = sinf(ang);
    float v1 = (a1 * cv - a2 * sv) * esc;
    float v2 = (a1 * sv + a2 * cv) * esc;
    short hh, ll;
    splitf(v1, hh, ll); dh[l] = hh; dl[l] = ll;
    splitf(v2, hh, ll); dh[l + 64] = hh; dl[l + 64] = ll;
}

// ---------------- flash attention (causal, GQA) — pre-split bf16 inputs ----------------
__global__ __launch_bounds__(256)
void attn_k(const short* __restrict__ qhi, const short* __restrict__ qlo,
            const short* __restrict__ khi, const short* __restrict__ klo,
            const short* __restrict__ vhi, const short* __restrict__ vlo,
            short* __restrict__ ohi, short* __restrict__ olo)
{
    int blk = blockIdx.x;
    int qt = blk & 15, bh = blk >> 4;
    int h = bh & (NQ - 1), b = bh >> 4;
    int kvh = h >> 2;
    int tid = threadIdx.x;
    int w = tid >> 6, l = tid & 63, g = l >> 4, lr = l & 15;
    int q0 = qt * 64, qbase = q0 + w * 16;
    long qoff = (long)(b * SEQ + qbase + lr) * DIM + h * HDIM + 8 * g;
    bf16x8 qh[4], ql[4];
#pragma unroll
    for (int kc = 0; kc < 4; ++kc) {
        qh[kc] = *(const bf16x8*)(qhi + qoff + kc * 32);
        ql[kc] = *(const bf16x8*)(qlo + qoff + kc * 32);
    }
    f32x4 o[8];
#pragma unroll
    for (int i = 0; i < 8; ++i) o[i] = (f32x4){0,0,0,0};
    float mr[4] = {-1e30f, -1e30f, -1e30f, -1e30f};
    float ls[4] = {0, 0, 0, 0};
    __shared__ short Vth[5120], Vtl[5120];      // [hd][40 keys]
    __shared__ short Plh[2560], Pll[2560];      // per-wave [16 q][40 keys]
    int nsteps = 2 * (qt + 1);
    for (int st = 0; st < nsteps; ++st) {
        int kb = st * 32;
        __syncthreads();
        {   // stage V transposed (already split): Vt[hd][key]
            int key = tid >> 3, hx = (tid & 7) * 16;
            long voff = (long)(b * SEQ + kb + key) * (NKV * HDIM) + kvh * HDIM + hx;
            union { int4 v; short s[8]; } h0, h1, l0, l1;
            h0.v = *(const int4*)(vhi + voff);
            h1.v = *(const int4*)(vhi + voff + 8);
            l0.v = *(const int4*)(vlo + voff);
            l1.v = *(const int4*)(vlo + voff + 8);
#pragma unroll
            for (int i = 0; i < 8; ++i) {
                Vth[(hx + i) * 40 + key] = h0.s[i];
                Vth[(hx + 8 + i) * 40 + key] = h1.s[i];
                Vtl[(hx + i) * 40 + key] = l0.s[i];
                Vtl[(hx + 8 + i) * 40 + key] = l1.s[i];
            }
        }
        __syncthreads();
        f32x4 sa[2]; sa[0] = (f32x4){0,0,0,0}; sa[1] = (f32x4){0,0,0,0};
#pragma unroll
        for (int kc = 0; kc < 4; ++kc)
#pragma unroll
            for (int n = 0; n < 2; ++n) {
                long koff = (long)(b * SEQ + kb + n * 16 + lr) * (NKV * HDIM) + kvh * HDIM + kc * 32 + 8 * g;
                bf16x8 kh = *(const bf16x8*)(khi + koff);
                bf16x8 kl = *(const bf16x8*)(klo + koff);
                sa[n] = __builtin_amdgcn_mfma_f32_16x16x32_bf16(ql[kc], kh, sa[n], 0, 0, 0);
                sa[n] = __builtin_amdgcn_mfma_f32_16x16x32_bf16(qh[kc], kl, sa[n], 0, 0, 0);
                sa[n] = __builtin_amdgcn_mfma_f32_16x16x32_bf16(qh[kc], kh, sa[n], 0, 0, 0);
            }
        // causal mask
#pragma unroll
        for (int n = 0; n < 2; ++n)
#pragma unroll
            for (int j = 0; j < 4; ++j) {
                int key = kb + n * 16 + lr;
                int qr = qbase + 4 * g + j;
                if (key > qr) sa[n][j] = -1e30f;
            }
        // online softmax (fp32), P stored as hi/lo bf16 planes
#pragma unroll
        for (int j = 0; j < 4; ++j) {
            float v = fmaxf(sa[0][j], sa[1][j]);
#pragma unroll
            for (int off = 1; off < 16; off <<= 1) v = fmaxf(v, __shfl_xor(v, off));
            float mn = fmaxf(mr[j], v);
            float sc = __expf(mr[j] - mn);
            mr[j] = mn;
            float p0 = __expf(sa[0][j] - mn);
            float p1 = __expf(sa[1][j] - mn);
            float rs = p0 + p1;
#pragma unroll
            for (int off = 1; off < 16; off <<= 1) rs += __shfl_xor(rs, off);
            ls[j] = ls[j] * sc + rs;
            short hh, ll;
            splitf(p0, hh, ll);
            Plh[w * 640 + (4 * g + j) * 40 + lr] = hh;
            Pll[w * 640 + (4 * g + j) * 40 + lr] = ll;
            splitf(p1, hh, ll);
            Plh[w * 640 + (4 * g + j) * 40 + 16 + lr] = hh;
            Pll[w * 640 + (4 * g + j) * 40 + 16 + lr] = ll;
#pragma unroll
            for (int nf = 0; nf < 8; ++nf) o[nf][j] *= sc;
        }
        asm volatile("s_waitcnt lgkmcnt(0)" ::: "memory");
        bf16x8 pah = *(const bf16x8*)(Plh + w * 640 + lr * 40 + 8 * g);
        bf16x8 pal = *(const bf16x8*)(Pll + w * 640 + lr * 40 + 8 * g);
#pragma unroll
        for (int nf = 0; nf < 8; ++nf) {
            bf16x8 vh = *(const bf16x8*)(Vth + (nf * 16 + lr) * 40 + 8 * g);
            bf16x8 vl = *(const bf16x8*)(Vtl + (nf * 16 + lr) * 40 + 8 * g);
            o[nf] = __builtin_amdgcn_mfma_f32_16x16x32_bf16(pal, vh, o[nf], 0, 0, 0);
            o[nf] = __builtin_amdgcn_mfma_f32_16x16x32_bf16(pah, vl, o[nf], 0, 0, 0);
            o[nf] = __builtin_amdgcn_mfma_f32_16x16x32_bf16(pah, vh, o[nf], 0, 0, 0);
        }
    }
    float invl[4];
#pragma unroll
    for (int j = 0; j < 4; ++j) invl[j] = 1.f / ls[j];
#pragma unroll
    for (int nf = 0; nf < 8; ++nf)
#pragma unroll
        for (int j = 0; j < 4; ++j) {
            long idx = (long)(b * SEQ + qbase + 4 * g + j) * DIM + h * HDIM + nf * 16 + lr;
            short hh, ll;
            splitf(o[nf][j] * invl[j], hh, ll);
            ohi[idx] = hh;
            olo[idx] = ll;
        }
}

// ---------------- router: sigmoid gate + top-4 + renorm ----------------
__global__ __launch_bounds__(256)
void router_k(const float* __restrict__ x, const float* __restrict__ gw,
              float* __restrict__ topw, int* __restrict__ topi,
              int* __restrict__ posb, int* __restrict__ counts)
{
    int t = blockIdx.x, tid = threadIdx.x;
    int e = tid & 31, ch = tid >> 5;
    const float* xp = x + (long)t * DIM + ch * 256;
    float p = 0.f;
    for (int d = 0; d < 256; ++d) p += xp[d] * gw[(ch * 256 + d) * NE + e];
    __shared__ float red[8][32];
    __shared__ float gv[32];
    red[ch][e] = p;
    __syncthreads();
    if (tid < 32) {
        float s = 0.f;
        for (int c = 0; c < 8; ++c) s += red[c][tid];
        gv[tid] = 1.f / (1.f + expf(-s));
    }
    __syncthreads();
    if (tid == 0) {
        float lg[32];
        for (int i = 0; i < 32; ++i) lg[i] = gv[i];
        float tv[TOPK]; int ti[TOPK]; float wsum = 0.f;
        for (int j = 0; j < TOPK; ++j) {
            float bv = -1e30f; int bi = 0;
            for (int i = 0; i < 32; ++i) if (lg[i] > bv) { bv = lg[i]; bi = i; }
            tv[j] = bv; ti[j] = bi; lg[bi] = -1e30f; wsum += bv;
        }
        float r = 1.f / wsum;
        for (int j = 0; j < TOPK; ++j) {
            topw[t * TOPK + j] = tv[j] * r;
            topi[t * TOPK + j] = ti[j];
            posb[t * TOPK + j] = atomicAdd(&counts[ti[j]], 1);
        }
    }
}

__global__ void initmoe_k(int* __restrict__ rowmap, float* __restrict__ wslot,
                          int* __restrict__ counts, int* __restrict__ zb)
{
    int i = blockIdx.x * 256 + threadIdx.x;
    if (i < MAXROWS) { rowmap[i] = -1; wslot[i] = 0.f; }
    if (i < NE) counts[i] = 0;
    if (i < 4096) zb[i] = 0;
}

__global__ void prep_k(const int* __restrict__ counts, int* __restrict__ padoff,
                       int* __restrict__ tile_e, int* __restrict__ tile_base, int* __restrict__ ntl)
{
    if (threadIdx.x == 0 && blockIdx.x == 0) {
        int nt = 0, rb = 0;
        for (int e = 0; e < NE; ++e) {
            padoff[e] = rb;
            int c = counts[e];
            int te = (c + 127) >> 7;
            for (int i = 0; i < te; ++i) { tile_e[nt] = e; tile_base[nt] = rb + i * 128; ++nt; }
            rb += te * 128;
        }
        *ntl = nt;
    }
}

__global__ void scatter_k(const int* __restrict__ topi, const float* __restrict__ topw,
                          const int* __restrict__ posb, const int* __restrict__ padoff,
                          int* __restrict__ rowmap, float* __restrict__ wslot)
{
    int i = blockIdx.x * 256 + threadIdx.x;
    if (i < T_TOK * TOPK) {
        int e = topi[i];
        int s = padoff[e] + posb[i];
        rowmap[s] = i >> 2;
        wslot[s] = topw[i];
    }
}

// ---------------- launch ----------------
extern "C" void kernel_launch(void* const* d_in, const int* in_sizes, int n_in,
                              void* d_out, int out_size, void* d_ws, size_t ws_size,
                              hipStream_t stream)
{
    (void)in_sizes; (void)n_in; (void)out_size;
    const int*   positions = (const int*)  d_in[0];
    const float* hidden    = (const float*)d_in[1];
    const float* in_ln     = (const float*)d_in[2];
    const float* post_ln   = (const float*)d_in[3];
    const float* q_norm    = (const float*)d_in[4];
    const float* k_norm    = (const float*)d_in[5];
    const float* wq        = (const float*)d_in[6];
    const float* wk        = (const float*)d_in[7];
    const float* wv        = (const float*)d_in[8];
    const float* wo        = (const float*)d_in[9];
    const float* gate_w    = (const float*)d_in[10];
    const float* sh_wg     = (const float*)d_in[11];
    const float* sh_wu     = (const float*)d_in[12];
    const float* sh_wd     = (const float*)d_in[13];
    const float* e_wg      = (const float*)d_in[14];
    const float* e_wu      = (const float*)d_in[15];
    const float* e_wd      = (const float*)d_in[16];
    float* out = (float*)d_out;
    char* ws = (char*)d_ws;

#define MB (1048576L)
    // proven-safe region is [0, ~126MB); ET (big path) needs ws_size >= 256MB
    short* hfhi    = (short*)(ws + 0*MB);      // dead after QKV
    short* hflo    = (short*)(ws + 8*MB);
    short* gatesh  = (short*)(ws + 0*MB);      // shared phase
    short* shint   = (short*)(ws + 8*MB);
    short* interbf = (short*)(ws + 0*MB);      // expert phase, 27MB (rows<=13k)
    short* wqThi   = (short*)(ws + 16*MB);     // dead after Q gemm
    short* wqTlo   = (short*)(ws + 24*MB);
    float* h2lnf   = (float*)(ws + 16*MB);     // born step 6
    short* wkThi   = (short*)(ws + 32*MB);
    short* wkTlo   = (short*)(ws + 34*MB);
    short* wvThi   = (short*)(ws + 36*MB);
    short* wvTlo   = (short*)(ws + 38*MB);
    short* h2lnbf  = (short*)(ws + 32*MB);     // born step 6
    short* woThi   = (short*)(ws + 40*MB);     // dead after Wo gemm
    short* woTlo   = (short*)(ws + 48*MB);
    short* shTwd   = (short*)(ws + 40*MB);     // born shared phase (8MB)
    short* qhi     = (short*)(ws + 56*MB);     // dead after attn
    short* qlo     = (short*)(ws + 64*MB);
    float* kf      = (float*)(ws + 72*MB);     // dead after rope
    short* khi     = (short*)(ws + 76*MB);
    short* klo     = (short*)(ws + 78*MB);
    short* vhi     = (short*)(ws + 80*MB);
    short* vlo     = (short*)(ws + 82*MB);
    float* h2      = (float*)(ws + 72*MB);     // born step 5 (16MB)
    float* qf      = (float*)(ws + 88*MB);     // dead after rope
    short* attnhi  = (short*)(ws + 88*MB);     // born attn
    short* attnlo  = (short*)(ws + 96*MB);
    short* gate_e  = (short*)(ws + 88*MB);     // expert phase, 27MB [88,115)
    short* shTwg   = (short*)(ws + 104*MB);    // shared phase (dead before gate_e write)
    short* shTwu   = (short*)(ws + 112*MB);
    char*  S       = ws + 120*MB;              // bookkeeping (proven region)
    float* topw    = (float*)(S);
    int*   topi    = (int*)  (S + 32768);
    int*   posb    = (int*)  (S + 65536);
    int*   counts  = (int*)  (S + 98304);
    int*   padoff  = (int*)  (S + 98560);
    int*   ntl     = (int*)  (S + 98816);
    int*   tile_e  = (int*)  (S + 99072);
    int*   tile_b  = (int*)  (S + 99584);
    int*   rowmap  = (int*)  (S + 100352);
    float* wslot   = (float*)(S + 165888);
    short* zbuf    = (short*)(S + 231424);     // 16KB zeros
    short* ET      = (short*)(ws + 128*MB);    // big path only: 128MB bf16T experts
    bool big = (ws_size >= (size_t)268435456);
#undef MB

    dim3 blk(256);

    // 1) input RMSNorm -> hi/lo planes; split+transpose attention weights
    rmsnorm_k<0><<<T_TOK, blk, 0, stream>>>(hidden, in_ln, hfhi, hflo, nullptr);
    splitw_k<<<dim3(32,32), blk, 0, stream>>>(wq, wqThi, wqTlo, 2048, 2048);
    splitw_k<<<dim3(32,8),  blk, 0, stream>>>(wk, wkThi, wkTlo, 2048, 512);
    splitw_k<<<dim3(32,8),  blk, 0, stream>>>(wv, wvThi, wvTlo, 2048, 512);
    splitw_k<<<dim3(32,32), blk, 0, stream>>>(wo, woThi, woTlo, 2048, 2048);
    // 2) QKV projections (split, m97 staging)
    gemmsp3_k<0><<<dim3(16,16), blk, 0, stream>>>(hfhi, hflo, wqThi, wqTlo, qf, nullptr, nullptr, nullptr, 2048, 2048);
    gemmsp3_k<0><<<dim3(16,4),  blk, 0, stream>>>(hfhi, hflo, wkThi, wkTlo, kf, nullptr, nullptr, nullptr,  512, 2048);
    gemmsp3_k<2><<<dim3(16,4),  blk, 0, stream>>>(hfhi, hflo, wvThi, wvTlo, nullptr, nullptr, vhi, vlo,     512, 2048);
    // 3) qk-norm + rope -> split planes
    rope2_k<<<dim3(T_TOK,5), blk, 0, stream>>>(qf, kf, q_norm, k_norm, positions, qhi, qlo, khi, klo);
    // 4) causal flash attention -> split output
    attn_k<<<512, blk, 0, stream>>>(qhi, qlo, khi, klo, vhi, vlo, attnhi, attnlo);
    // 5) output projection + residual
    gemmsp3_k<1><<<dim3(16,16), blk, 0, stream>>>(attnhi, attnlo, woThi, woTlo, h2, hidden, nullptr, nullptr, 2048, 2048);
    // 6) post-attn RMSNorm
    rmsnorm_k<1><<<T_TOK, blk, 0, stream>>>(h2, post_ln, h2lnbf, nullptr, h2lnf);
    // 7) router + MoE bookkeeping
    initmoe_k<<<64, blk, 0, stream>>>(rowmap, wslot, counts, (int*)zbuf);
    router_k<<<T_TOK, blk, 0, stream>>>(h2lnf, gate_w, topw, topi, posb, counts);
    prep_k<<<1, 64, 0, stream>>>(counts, padoff, tile_e, tile_b, ntl);
    scatter_k<<<32, blk, 0, stream>>>(topi, topw, posb, padoff, rowmap, wslot);
    // 8) shared expert: convert to bf16T (fits), then gate / up(silu) / down(+resid)
    cvtT_k<<<dim3(32,32,1), blk, 0, stream>>>(sh_wg, shTwg, 2048, 2048);
    cvtT_k<<<dim3(32,32,1), blk, 0, stream>>>(sh_wu, shTwu, 2048, 2048);
    cvtT_k<<<dim3(32,32,1), blk, 0, stream>>>(sh_wd, shTwd, 2048, 2048);
    gemm3_k<3,false,false><<<dim3(16,16), blk, 0, stream>>>(h2lnbf, shTwg, nullptr, gatesh, nullptr, nullptr, 2048, 2048, nullptr, nullptr, nullptr, nullptr, 0, nullptr, zbuf);
    gemm3_k<5,false,false><<<dim3(16,16), blk, 0, stream>>>(h2lnbf, shTwu, nullptr, shint, nullptr, gatesh, 2048, 2048, nullptr, nullptr, nullptr, nullptr, 0, nullptr, zbuf);
    gemm3_k<1,false,false><<<dim3(16,16), blk, 0, stream>>>(shint, shTwd, out, nullptr, h2, nullptr, 2048, 2048, nullptr, nullptr, nullptr, nullptr, 0, nullptr, zbuf);
    // 9) routed experts
    if (big) {
        cvtT_k<<<dim3(32,16,NE), blk, 0, stream>>>(e_wg, ET, 2048, 1024);
        gemm3_k<3,true,true><<<dim3(MAXTILES,8), blk, 0, stream>>>(h2lnbf, ET, nullptr, gate_e, nullptr, nullptr, 1024, 2048, rowmap, tile_e, tile_b, ntl, (long)1024*2048, nullptr, zbuf);
        cvtT_k<<<dim3(32,16,NE), blk, 0, stream>>>(e_wu, ET, 2048, 1024);
        gemm3_k<5,true,true><<<dim3(MAXTILES,8), blk, 0, stream>>>(h2lnbf, ET, nullptr, interbf, nullptr, gate_e, 1024, 2048, rowmap, tile_e, tile_b, ntl, (long)1024*2048, nullptr, zbuf);
        cvtT_k<<<dim3(16,32,NE), blk, 0, stream>>>(e_wd, ET, 1024, 2048);
        gemm3_k<4,false,true><<<dim3(MAXTILES,16), blk, 0, stream>>>(interbf, ET, out, nullptr, nullptr, nullptr, 2048, 1024, rowmap, tile_e, tile_b, ntl, (long)2048*1024, wslot, zbuf);
    } else {
        gemm_k<3,true,true><<<dim3(MAXTILES,8), blk, 0, stream>>>(h2lnbf, e_wg, nullptr, gate_e, nullptr, nullptr, 1024, 2048, rowmap, tile_e, tile_b, ntl, (long)2048*1024, nullptr);
        gemm_k<5,true,true><<<dim3(MAXTILES,8), blk, 0, stream>>>(h2lnbf, e_wu, nullptr, interbf, nullptr, gate_e, 1024, 2048, rowmap, tile_e, tile_b, ntl, (long)2048*1024, nullptr);
        gemm_k<4,false,true><<<dim3(MAXTILES,16), blk, 0, stream>>>(interbf, e_wd, out, nullptr, nullptr, nullptr, 2048, 1024, rowmap, tile_e, tile_b, ntl, (long)1024*2048, wslot);
    }
}

// Round 10
// 1403.990 us; speedup vs baseline: 1.0654x; 1.0010x over previous
//
#include <hip/hip_runtime.h>

// Problem constants
#define T_TOK 2048   // B*S
#define DIM   2048
#define NQ    16
#define NKV   4
#define HDIM  128
#define NE    32
#define TOPK  4
#define FF    1024
#define FSH   2048
#define SEQ   1024
#define MAXROWS 16384
#define MAXTILES 96

typedef __attribute__((ext_vector_type(4))) float f32x4;
typedef __attribute__((ext_vector_type(8))) short bf16x8;

__device__ __forceinline__ short f2bf(float f) {
    union { float f; unsigned u; } c; c.f = f;
    unsigned r = (c.u + 0x7fffu + ((c.u >> 16) & 1u)) >> 16;
    return (short)r;
}
__device__ __forceinline__ float bf2f(short h) {
    union { unsigned u; float f; } c; c.u = ((unsigned)(unsigned short)h) << 16;
    return c.f;
}
__device__ __forceinline__ void splitf(float v, short& hi, short& lo) {
    hi = f2bf(v);
    lo = f2bf(v - bf2f(hi));
}
// bijective XCD-chunk swizzle (m204)
__device__ __forceinline__ int xcd_swz(int lin, int total) {
    int q8 = total >> 3, r8 = total & 7;
    int xcd = lin & 7, idx = lin >> 3;
    return (xcd < r8 ? xcd * (q8 + 1) : r8 * (q8 + 1) + (xcd - r8) * q8) + idx;
}
// async global->LDS, 16B per lane; lds dest = wave-uniform base + lane*16
__device__ __forceinline__ void gl16(const void* g, void* l) {
    __builtin_amdgcn_global_load_lds(
        (const __attribute__((address_space(1))) unsigned int*)g,
        (__attribute__((address_space(3))) unsigned int*)l, 16, 0, 0);
}

// ---------------- RMSNorm. MODE 0: hi/lo bf16 planes. MODE 1: bf16 + fp32 ----------------
template<int MODE>
__global__ __launch_bounds__(256)
void rmsnorm_k(const float* __restrict__ x, const float* __restrict__ sc,
               short* __restrict__ ybh, short* __restrict__ ybl, float* __restrict__ yf)
{
    long base = (long)blockIdx.x * DIM;
    int tid = threadIdx.x;
    const float* xp = x + base + tid * 8;
    float4 a = *(const float4*)xp;
    float4 b = *(const float4*)(xp + 4);
    float ss = a.x*a.x + a.y*a.y + a.z*a.z + a.w*a.w
             + b.x*b.x + b.y*b.y + b.z*b.z + b.w*b.w;
#pragma unroll
    for (int off = 32; off > 0; off >>= 1) ss += __shfl_xor(ss, off);
    __shared__ float red[4];
    if ((tid & 63) == 0) red[tid >> 6] = ss;
    __syncthreads();
    float s = red[0] + red[1] + red[2] + red[3];
    float inv = rsqrtf(s * (1.f / DIM) + 1e-6f);
    const float* sp = sc + tid * 8;
    float4 s0 = *(const float4*)sp;
    float4 s1 = *(const float4*)(sp + 4);
    float o[8];
    o[0]=a.x*inv*s0.x; o[1]=a.y*inv*s0.y; o[2]=a.z*inv*s0.z; o[3]=a.w*inv*s0.w;
    o[4]=b.x*inv*s1.x; o[5]=b.y*inv*s1.y; o[6]=b.z*inv*s1.z; o[7]=b.w*inv*s1.w;
    if (MODE == 0) {
        union { short s[8]; int4 v; } ph, pl;
#pragma unroll
        for (int i = 0; i < 8; ++i) splitf(o[i], ph.s[i], pl.s[i]);
        *(int4*)(ybh + base + tid * 8) = ph.v;
        *(int4*)(ybl + base + tid * 8) = pl.v;
    } else {
        union { short s[8]; int4 v; } ph;
#pragma unroll
        for (int i = 0; i < 8; ++i) ph.s[i] = f2bf(o[i]);
        *(int4*)(ybh + base + tid * 8) = ph.v;
        float4 w0; w0.x=o[0]; w0.y=o[1]; w0.z=o[2]; w0.w=o[3];
        float4 w1; w1.x=o[4]; w1.y=o[5]; w1.z=o[6]; w1.w=o[7];
        *(float4*)(yf + base + tid * 8) = w0;
        *(float4*)(yf + base + tid * 8 + 4) = w1;
    }
}

// -------- split+transpose weights: W[K][N] fp32 -> Thi/Tlo[N][K] bf16 --------
__global__ __launch_bounds__(256)
void splitw_k(const float* __restrict__ W, short* __restrict__ Thi, short* __restrict__ Tlo,
              int K, int N)
{
    __shared__ float t[64][65];
    int k0 = blockIdx.x * 64, n0 = blockIdx.y * 64;
    int tid = threadIdx.x;
    int rr = tid >> 4, cc = (tid & 15) * 4;
#pragma unroll
    for (int i = 0; i < 4; ++i) {
        int row = rr + i * 16;
        float4 v = *(const float4*)(W + (long)(k0 + row) * N + n0 + cc);
        t[row][cc] = v.x; t[row][cc+1] = v.y; t[row][cc+2] = v.z; t[row][cc+3] = v.w;
    }
    __syncthreads();
    int n = tid >> 2, kc = (tid & 3) * 16;
    union { short s[16]; int4 v[2]; } uh, ul;
#pragma unroll
    for (int j = 0; j < 16; ++j) splitf(t[kc + j][n], uh.s[j], ul.s[j]);
    long ob = (long)(n0 + n) * K + k0 + kc;
    *(int4*)(Thi + ob) = uh.v[0];
    *(int4*)(Thi + ob + 8) = uh.v[1];
    *(int4*)(Tlo + ob) = ul.v[0];
    *(int4*)(Tlo + ob + 8) = ul.v[1];
}

// -------- convert+transpose: W[K][N] fp32 -> T[N][K] bf16 (per blockIdx.z matrix) --------
__global__ __launch_bounds__(256)
void cvtT_k(const float* __restrict__ W, short* __restrict__ T, int K, int N)
{
    __shared__ float t[64][65];
    const float* Wp = W + (long)blockIdx.z * K * N;
    short* Tp = T + (long)blockIdx.z * K * N;
    int k0 = blockIdx.x * 64, n0 = blockIdx.y * 64;
    int tid = threadIdx.x;
    int rr = tid >> 4, cc = (tid & 15) * 4;
#pragma unroll
    for (int i = 0; i < 4; ++i) {
        int row = rr + i * 16;
        float4 v = *(const float4*)(Wp + (long)(k0 + row) * N + n0 + cc);
        t[row][cc] = v.x; t[row][cc+1] = v.y; t[row][cc+2] = v.z; t[row][cc+3] = v.w;
    }
    __syncthreads();
    int n = tid >> 2, kc = (tid & 3) * 16;
    union { short s[16]; int4 v[2]; } u;
#pragma unroll
    for (int j = 0; j < 16; ++j) u.s[j] = f2bf(t[kc + j][n]);
    long ob = (long)(n0 + n) * K + k0 + kc;
    *(int4*)(Tp + ob) = u.v[0];
    *(int4*)(Tp + ob + 8) = u.v[1];
}

// ------- Split GEMM (m97-style): C = (Ahi+Alo)[M][K] @ (BThi+BTlo)[N][K]^T -------
// EPI 0: Cf=acc ; 1: Cf=acc+addb ; 2: split acc -> Ohi/Olo (row-major)
// EPI 6: split acc -> Ohi/Olo TRANSPOSED [col][row] (for V: [hd-slot][token])
template<int EPI>
__global__ __launch_bounds__(256)
void gemmsp3_k(const short* __restrict__ Ahi, const short* __restrict__ Alo,
               const short* __restrict__ BThi, const short* __restrict__ BTlo,
               float* __restrict__ Cf, const float* __restrict__ addb,
               short* __restrict__ Ohi, short* __restrict__ Olo,
               int N, int K)
{
    int nby = gridDim.y;
    int total = gridDim.x * nby;
    int lin = blockIdx.x + gridDim.x * blockIdx.y;
    int vt = xcd_swz(lin, total);
    int row0 = (vt / nby) * 128, col0 = (vt % nby) * 128;
    __shared__ short Ah[4096], Al[4096], Bh[4096], Bl[4096];
    int tid = threadIdx.x, w = tid >> 6, l = tid & 63, g = l >> 4, lr = l & 15;
    int wr = w >> 1, wc = w & 1;
    int srt = tid >> 2, klane = (tid & 3) * 8;
    const short* pah0 = Ahi + (long)(row0 + srt) * K + klane;
    const short* pah1 = Ahi + (long)(row0 + srt + 64) * K + klane;
    const short* pal0 = Alo + (long)(row0 + srt) * K + klane;
    const short* pal1 = Alo + (long)(row0 + srt + 64) * K + klane;
    const short* pbh0 = BThi + (long)(col0 + srt) * K + klane;
    const short* pbh1 = BThi + (long)(col0 + srt + 64) * K + klane;
    const short* pbl0 = BTlo + (long)(col0 + srt) * K + klane;
    const short* pbl1 = BTlo + (long)(col0 + srt + 64) * K + klane;
    short* dA = Ah + w * 512;
    short* dAl = Al + w * 512;
    short* dB = Bh + w * 512;
    short* dBl = Bl + w * 512;
    f32x4 acc[4][4];
#pragma unroll
    for (int m = 0; m < 4; ++m)
#pragma unroll
        for (int n = 0; n < 4; ++n) acc[m][n] = (f32x4){0,0,0,0};
    for (int kk = 0; kk < K; kk += 32) {
        gl16(pah0 + kk, dA);        gl16(pah1 + kk, dA + 2048);
        gl16(pal0 + kk, dAl);       gl16(pal1 + kk, dAl + 2048);
        gl16(pbh0 + kk, dB);        gl16(pbh1 + kk, dB + 2048);
        gl16(pbl0 + kk, dBl);       gl16(pbl1 + kk, dBl + 2048);
        asm volatile("s_waitcnt vmcnt(0)" ::: "memory");
        __syncthreads();
        bf16x8 ah[4], al[4], bh[4], bl[4];
#pragma unroll
        for (int m = 0; m < 4; ++m) {
            int off = (wr * 64 + m * 16 + lr) * 32 + g * 8;
            ah[m] = *(const bf16x8*)(Ah + off);
            al[m] = *(const bf16x8*)(Al + off);
        }
#pragma unroll
        for (int n = 0; n < 4; ++n) {
            int off = (wc * 64 + n * 16 + lr) * 32 + g * 8;
            bh[n] = *(const bf16x8*)(Bh + off);
            bl[n] = *(const bf16x8*)(Bl + off);
        }
#pragma unroll
        for (int m = 0; m < 4; ++m)
#pragma unroll
            for (int n = 0; n < 4; ++n) {
                acc[m][n] = __builtin_amdgcn_mfma_f32_16x16x32_bf16(al[m], bh[n], acc[m][n], 0, 0, 0);
                acc[m][n] = __builtin_amdgcn_mfma_f32_16x16x32_bf16(ah[m], bl[n], acc[m][n], 0, 0, 0);
                acc[m][n] = __builtin_amdgcn_mfma_f32_16x16x32_bf16(ah[m], bh[n], acc[m][n], 0, 0, 0);
            }
        __syncthreads();
    }
#pragma unroll
    for (int m = 0; m < 4; ++m)
#pragma unroll
        for (int n = 0; n < 4; ++n) {
            if (EPI == 6) {
                short4 h4, l4;
#pragma unroll
                for (int j = 0; j < 4; ++j)
                    splitf(acc[m][n][j], ((short*)&h4)[j], ((short*)&l4)[j]);
                int rowb = row0 + wr * 64 + m * 16 + 4 * g;
                int col = col0 + wc * 64 + n * 16 + lr;
                *(short4*)(Ohi + (long)col * T_TOK + rowb) = h4;
                *(short4*)(Olo + (long)col * T_TOK + rowb) = l4;
            } else {
#pragma unroll
                for (int j = 0; j < 4; ++j) {
                    int row = row0 + wr * 64 + m * 16 + 4 * g + j;
                    int col = col0 + wc * 64 + n * 16 + lr;
                    float v = acc[m][n][j];
                    if (EPI == 0) Cf[(long)row * N + col] = v;
                    else if (EPI == 1) Cf[(long)row * N + col] = v + addb[(long)row * N + col];
                    else {
                        short hh, ll;
                        splitf(v, hh, ll);
                        Ohi[(long)row * N + col] = hh;
                        Olo[(long)row * N + col] = ll;
                    }
                }
            }
        }
}

// ------- bf16 GEMM (m97-style): C[M,N] = A[M][K] @ BT[N][K]^T, global_load_lds staging -------
// EPI 1: Cf=acc+addb ; 3: Cbf=bf16(acc) ; 5: Cbf=bf16(silu(gsrc)*acc) ;
// EPI 4: atomicAdd(Cf[tok*DIM+col], wslot[row]*acc)
template<int EPI, bool GATHER, bool EXPERT>
__global__ __launch_bounds__(256)
void gemm3_k(const short* __restrict__ A, const short* __restrict__ BTg,
             float* __restrict__ Cf, short* __restrict__ Cbf,
             const float* __restrict__ addb, const short* __restrict__ gsrc,
             int N, int K,
             const int* __restrict__ rowmap, const int* __restrict__ tile_e,
             const int* __restrict__ tile_base, const int* __restrict__ ntiles,
             long strideBT, const float* __restrict__ wslot,
             const short* __restrict__ zbuf)
{
    int nby = gridDim.y;
    int total = gridDim.x * nby;
    int lin = blockIdx.x + gridDim.x * blockIdx.y;
    int vt = xcd_swz(lin, total);
    int bx = vt / nby, by = vt % nby;
    int row0;
    const short* BT;
    if (EXPERT) {
        if (bx >= *ntiles) return;
        int e = tile_e[bx];
        row0 = tile_base[bx];
        BT = BTg + (long)e * strideBT;
    } else {
        row0 = bx * 128; BT = BTg;
    }
    int col0 = by * 128;
    __shared__ short As[4096], Bs[4096];
    int tid = threadIdx.x, w = tid >> 6, l = tid & 63, g = l >> 4, lr = l & 15;
    int wr = w >> 1, wc = w & 1;
    int srt = tid >> 2, klane = (tid & 3) * 8;
    const short *ap0, *ap1;
    if (GATHER) {
        int r0 = rowmap[row0 + srt], r1 = rowmap[row0 + srt + 64];
        ap0 = (r0 >= 0) ? (A + (long)r0 * K + klane) : (zbuf + klane);
        ap1 = (r1 >= 0) ? (A + (long)r1 * K + klane) : (zbuf + klane);
    } else {
        ap0 = A + (long)(row0 + srt) * K + klane;
        ap1 = A + (long)(row0 + srt + 64) * K + klane;
    }
    const short* bp0 = BT + (long)(col0 + srt) * K + klane;
    const short* bp1 = BT + (long)(col0 + srt + 64) * K + klane;
    short* dA = As + w * 512;
    short* dB = Bs + w * 512;
    f32x4 acc[4][4];
#pragma unroll
    for (int m = 0; m < 4; ++m)
#pragma unroll
        for (int n = 0; n < 4; ++n) acc[m][n] = (f32x4){0,0,0,0};
    for (int kk = 0; kk < K; kk += 32) {
        gl16(ap0 + kk, dA);  gl16(ap1 + kk, dA + 2048);
        gl16(bp0 + kk, dB);  gl16(bp1 + kk, dB + 2048);
        asm volatile("s_waitcnt vmcnt(0)" ::: "memory");
        __syncthreads();
        bf16x8 af[4], bf[4];
#pragma unroll
        for (int m = 0; m < 4; ++m)
            af[m] = *(const bf16x8*)(As + (wr * 64 + m * 16 + lr) * 32 + g * 8);
#pragma unroll
        for (int n = 0; n < 4; ++n)
            bf[n] = *(const bf16x8*)(Bs + (wc * 64 + n * 16 + lr) * 32 + g * 8);
#pragma unroll
        for (int m = 0; m < 4; ++m)
#pragma unroll
            for (int n = 0; n < 4; ++n)
                acc[m][n] = __builtin_amdgcn_mfma_f32_16x16x32_bf16(af[m], bf[n], acc[m][n], 0, 0, 0);
        __syncthreads();
    }
#pragma unroll
    for (int m = 0; m < 4; ++m)
#pragma unroll
        for (int n = 0; n < 4; ++n)
#pragma unroll
            for (int j = 0; j < 4; ++j) {
                int row = row0 + wr * 64 + m * 16 + 4 * g + j;
                int col = col0 + wc * 64 + n * 16 + lr;
                float v = acc[m][n][j];
                if (EPI == 1) Cf[(long)row * N + col] = v + addb[(long)row * N + col];
                else if (EPI == 3) Cbf[(long)row * N + col] = f2bf(v);
                else if (EPI == 5) {
                    float gv_ = bf2f(gsrc[(long)row * N + col]);
                    float sg = gv_ / (1.f + __expf(-gv_));
                    Cbf[(long)row * N + col] = f2bf(sg * v);
                } else if (EPI == 4) {
                    int tok = rowmap[row];
                    if (tok >= 0) atomicAdd(&Cf[(long)tok * DIM + col], wslot[row] * v);
                }
            }
}

// ---- fallback bf16 GEMM (round-6 proven): fp32 B reg-transpose staging, 2-deep prefetch ----
template<int EPI, bool GATHER, bool EXPERT>
__global__ __launch_bounds__(256)
void gemm_k(const short* __restrict__ A, const float* __restrict__ Bg,
            float* __restrict__ Cf, short* __restrict__ Cbf,
            const float* __restrict__ addb, const short* __restrict__ gsrc,
            int N, int K,
            const int* __restrict__ rowmap, const int* __restrict__ tile_e,
            const int* __restrict__ tile_base, const int* __restrict__ ntiles,
            long strideB, const float* __restrict__ wslot)
{
    int nby = gridDim.y;
    int total = gridDim.x * nby;
    int lin = blockIdx.x + gridDim.x * blockIdx.y;
    int vt = xcd_swz(lin, total);
    int bx = vt / nby, by = vt % nby;
    int row0;
    const float* B;
    if (EXPERT) {
        if (bx >= *ntiles) return;
        int e = tile_e[bx];
        row0 = tile_base[bx];
        B = Bg + (long)e * strideB;
    } else {
        row0 = bx * 128; B = Bg;
    }
    int col0 = by * 128;
    __shared__ short As[5120], Bs[5120];
    int tid = threadIdx.x;
    int w = tid >> 6, l = tid & 63, g = l >> 4, lr = l & 15;
    int wr = w >> 1, wc = w & 1;
    f32x4 acc[4][4];
#pragma unroll
    for (int m = 0; m < 4; ++m)
#pragma unroll
        for (int n = 0; n < 4; ++n) acc[m][n] = (f32x4){0,0,0,0};
    int ar = tid >> 2, ak = (tid & 3) * 8;
    int bk0 = (tid >> 5) * 4, bc0 = (tid & 31) * 4;
    bool rok[2]; const short* abase[2];
#pragma unroll
    for (int it = 0; it < 2; ++it) {
        int r = row0 + ar + it * 64;
        int sr = GATHER ? rowmap[r] : r;
        rok[it] = (!GATHER) || (sr >= 0);
        abase[it] = A + (long)(rok[it] ? sr : 0) * K + ak;
    }
    const float* bb = B + (long)bk0 * N + col0 + bc0;
    int4 aE[2], aO[2];
    float4 bE[4], bO[4];
#pragma unroll
    for (int it = 0; it < 2; ++it) {
        aE[it] = rok[it] ? *(const int4*)(abase[it]) : (int4){0,0,0,0};
        aO[it] = rok[it] ? *(const int4*)(abase[it] + 32) : (int4){0,0,0,0};
    }
#pragma unroll
    for (int q = 0; q < 4; ++q) {
        bE[q] = *(const float4*)(bb + (long)q * N);
        bO[q] = *(const float4*)(bb + (long)(32 + q) * N);
    }

#define GEMM_STEP(BANKA, BANKB, KNEXT)                                        \
    {                                                                         \
        __syncthreads();                                                      \
        _Pragma("unroll")                                                     \
        for (int it = 0; it < 2; ++it)                                        \
            *(int4*)(As + (ar + it * 64) * 40 + ak) = BANKA[it];              \
        _Pragma("unroll")                                                     \
        for (int j = 0; j < 4; ++j) {                                         \
            short4 pk;                                                        \
            pk.x = f2bf(((const float*)&BANKB[0])[j]);                        \
            pk.y = f2bf(((const float*)&BANKB[1])[j]);                        \
            pk.z = f2bf(((const float*)&BANKB[2])[j]);                        \
            pk.w = f2bf(((const float*)&BANKB[3])[j]);                        \
            int c = bc0 + j;                                                  \
            int blk = (bk0 >> 3) ^ ((c >> 2) & 3);                            \
            *(short4*)(Bs + c * 40 + blk * 8 + (bk0 & 4)) = pk;               \
        }                                                                     \
        if ((KNEXT) < K) {                                                    \
            _Pragma("unroll")                                                 \
            for (int it = 0; it < 2; ++it)                                    \
                BANKA[it] = rok[it] ? *(const int4*)(abase[it] + (KNEXT))     \
                                    : (int4){0,0,0,0};                        \
            _Pragma("unroll")                                                 \
            for (int q = 0; q < 4; ++q)                                       \
                BANKB[q] = *(const float4*)(bb + (long)((KNEXT) + q) * N);    \
        }                                                                     \
        __syncthreads();                                                      \
        bf16x8 af[4], bf[4];                                                  \
        _Pragma("unroll")                                                     \
        for (int m = 0; m < 4; ++m)                                           \
            af[m] = *(const bf16x8*)(As + (wr * 64 + m * 16 + lr) * 40 + g * 8); \
        _Pragma("unroll")                                                     \
        for (int n = 0; n < 4; ++n) {                                         \
            int c = wc * 64 + n * 16 + lr;                                    \
            int blk = g ^ ((c >> 2) & 3);                                     \
            bf[n] = *(const bf16x8*)(Bs + c * 40 + blk * 8);                  \
        }                                                                     \
        _Pragma("unroll")                                                     \
        for (int m = 0; m < 4; ++m)                                           \
            _Pragma("unroll")                                                 \
            for (int n = 0; n < 4; ++n)                                       \
                acc[m][n] = __builtin_amdgcn_mfma_f32_16x16x32_bf16(af[m], bf[n], acc[m][n], 0, 0, 0); \
    }

    for (int kk = 0; kk < K; kk += 64) {
        GEMM_STEP(aE, bE, kk + 64)
        GEMM_STEP(aO, bO, kk + 96)
    }
#undef GEMM_STEP

#pragma unroll
    for (int m = 0; m < 4; ++m)
#pragma unroll
        for (int n = 0; n < 4; ++n)
#pragma unroll
            for (int j = 0; j < 4; ++j) {
                int row = row0 + wr * 64 + m * 16 + 4 * g + j;
                int col = col0 + wc * 64 + n * 16 + lr;
                float v = acc[m][n][j];
                if (EPI == 1) Cf[(long)row * N + col] = v + addb[(long)row * N + col];
                else if (EPI == 3) Cbf[(long)row * N + col] = f2bf(v);
                else if (EPI == 5) {
                    float gv_ = bf2f(gsrc[(long)row * N + col]);
                    float sg = gv_ / (1.f + __expf(-gv_));
                    Cbf[(long)row * N + col] = f2bf(sg * v);
                } else if (EPI == 4) {
                    int tok = rowmap[row];
                    if (tok >= 0) atomicAdd(&Cf[(long)tok * DIM + col], wslot[row] * v);
                }
            }
}

// ---------------- qk-norm + neox RoPE + scale -> split bf16 planes ----------------
__global__ __launch_bounds__(256)
void rope2_k(const float* __restrict__ qf, const float* __restrict__ kf,
             const float* __restrict__ qn, const float* __restrict__ kn,
             const int* __restrict__ posp,
             short* __restrict__ qhi, short* __restrict__ qlo,
             short* __restrict__ khi, short* __restrict__ klo)
{
    int t = blockIdx.x;
    int w = threadIdx.x >> 6, l = threadIdx.x & 63;
    int hi = blockIdx.y * 4 + w;   // 0..19
    const float* src; const float* nrm; float esc;
    short* dh; short* dl;
    if (hi < NQ) {
        long off = (long)t * DIM + hi * HDIM;
        src = qf + off; nrm = qn; dh = qhi + off; dl = qlo + off;
        esc = 0.08838834764831843f;  // HD^-0.5 folded into q
    } else {
        int kh = hi - NQ;
        long off = (long)t * (NKV * HDIM) + kh * HDIM;
        src = kf + off; nrm = kn; dh = khi + off; dl = klo + off;
        esc = 1.f;
    }
    float x1 = src[l], x2 = src[l + 64];
    float ss = x1 * x1 + x2 * x2;
#pragma unroll
    for (int off = 32; off > 0; off >>= 1) ss += __shfl_xor(ss, off);
    float inv = rsqrtf(ss * (1.f / HDIM) + 1e-6f);
    float a1 = x1 * inv * nrm[l], a2 = x2 * inv * nrm[l + 64];
    float p = (float)posp[t];
    float fr = expf((float)l * -0.21586735246819178f); // -ln(1e6)/64
    float ang = p * fr;
    float cv = cosf(ang), sv = sinf(ang);
    float v1 = (a1 * cv - a2 * sv) * esc;
    float v2 = (a1 * sv + a2 * cv) * esc;
    short hh, ll;
    splitf(v1, hh, ll); dh[l] = hh; dl[l] = ll;
    splitf(v2, hh, ll); dh[l + 64] = hh; dl[l + 64] = ll;
}

// ---------------- flash attention (causal, GQA) — pre-split bf16, V pre-transposed ----------------
// No block-shared state: 4 independent waves, no __syncthreads in loop.
// vthi/vtlo layout: [kvh*128+hd][b*1024+t]
__global__ __launch_bounds__(256)
void attn_k(const short* __restrict__ qhi, const short* __restrict__ qlo,
            const short* __restrict__ khi, const short* __restrict__ klo,
            const short* __restrict__ vthi, const short* __restrict__ vtlo,
            short* __restrict__ ohi, short* __restrict__ olo)
{
    int blk = blockIdx.x;
    int qt = 15 - (blk >> 5);          // heavy q-tiles dispatch first
    int bh = blk & 31;
    int h = bh & (NQ - 1), b = bh >> 4;
    int kvh = h >> 2;
    int tid = threadIdx.x;
    int w = tid >> 6, l = tid & 63, g = l >> 4, lr = l & 15;
    int q0 = qt * 64, qbase = q0 + w * 16;
    long qoff = (long)(b * SEQ + qbase + lr) * DIM + h * HDIM + 8 * g;
    bf16x8 qh[4], ql[4];
#pragma unroll
    for (int kc = 0; kc < 4; ++kc) {
        qh[kc] = *(const bf16x8*)(qhi + qoff + kc * 32);
        ql[kc] = *(const bf16x8*)(qlo + qoff + kc * 32);
    }
    f32x4 o[8];
#pragma unroll
    for (int i = 0; i < 8; ++i) o[i] = (f32x4){0,0,0,0};
    float mr[4] = {-1e30f, -1e30f, -1e30f, -1e30f};
    float ls[4] = {0, 0, 0, 0};
    __shared__ short Plh[2560], Pll[2560];      // per-wave [16 q][40 keys]
    const short* vbh = vthi + (long)kvh * HDIM * T_TOK + b * SEQ;
    const short* vbl = vtlo + (long)kvh * HDIM * T_TOK + b * SEQ;
    int nsteps = 2 * (qt + 1);
    for (int st = 0; st < nsteps; ++st) {
        int kb = st * 32;
        f32x4 sa[2]; sa[0] = (f32x4){0,0,0,0}; sa[1] = (f32x4){0,0,0,0};
#pragma unroll
        for (int kc = 0; kc < 4; ++kc)
#pragma unroll
            for (int n = 0; n < 2; ++n) {
                long koff = (long)(b * SEQ + kb + n * 16 + lr) * (NKV * HDIM) + kvh * HDIM + kc * 32 + 8 * g;
                bf16x8 kh = *(const bf16x8*)(khi + koff);
                bf16x8 kl = *(const bf16x8*)(klo + koff);
                sa[n] = __builtin_amdgcn_mfma_f32_16x16x32_bf16(ql[kc], kh, sa[n], 0, 0, 0);
                sa[n] = __builtin_amdgcn_mfma_f32_16x16x32_bf16(qh[kc], kl, sa[n], 0, 0, 0);
                sa[n] = __builtin_amdgcn_mfma_f32_16x16x32_bf16(qh[kc], kh, sa[n], 0, 0, 0);
            }
        // causal mask
#pragma unroll
        for (int n = 0; n < 2; ++n)
#pragma unroll
            for (int j = 0; j < 4; ++j) {
                int key = kb + n * 16 + lr;
                int qr = qbase + 4 * g + j;
                if (key > qr) sa[n][j] = -1e30f;
            }
        // online softmax (fp32), P stored as hi/lo bf16 planes (per-wave LDS)
#pragma unroll
        for (int j = 0; j < 4; ++j) {
            float v = fmaxf(sa[0][j], sa[1][j]);
#pragma unroll
            for (int off = 1; off < 16; off <<= 1) v = fmaxf(v, __shfl_xor(v, off));
            float mn = fmaxf(mr[j], v);
            float sc = __expf(mr[j] - mn);
            mr[j] = mn;
            float p0 = __expf(sa[0][j] - mn);
            float p1 = __expf(sa[1][j] - mn);
            float rs = p0 + p1;
#pragma unroll
            for (int off = 1; off < 16; off <<= 1) rs += __shfl_xor(rs, off);
            ls[j] = ls[j] * sc + rs;
            short hh, ll;
            splitf(p0, hh, ll);
            Plh[w * 640 + (4 * g + j) * 40 + lr] = hh;
            Pll[w * 640 + (4 * g + j) * 40 + lr] = ll;
            splitf(p1, hh, ll);
            Plh[w * 640 + (4 * g + j) * 40 + 16 + lr] = hh;
            Pll[w * 640 + (4 * g + j) * 40 + 16 + lr] = ll;
#pragma unroll
            for (int nf = 0; nf < 8; ++nf) o[nf][j] *= sc;
        }
        asm volatile("s_waitcnt lgkmcnt(0)" ::: "memory");
        __builtin_amdgcn_sched_barrier(0);
        bf16x8 pah = *(const bf16x8*)(Plh + w * 640 + lr * 40 + 8 * g);
        bf16x8 pal = *(const bf16x8*)(Pll + w * 640 + lr * 40 + 8 * g);
#pragma unroll
        for (int nf = 0; nf < 8; ++nf) {
            long voff = (long)(nf * 16 + lr) * T_TOK + kb + 8 * g;
            bf16x8 vh = *(const bf16x8*)(vbh + voff);
            bf16x8 vl = *(const bf16x8*)(vbl + voff);
            o[nf] = __builtin_amdgcn_mfma_f32_16x16x32_bf16(pal, vh, o[nf], 0, 0, 0);
            o[nf] = __builtin_amdgcn_mfma_f32_16x16x32_bf16(pah, vl, o[nf], 0, 0, 0);
            o[nf] = __builtin_amdgcn_mfma_f32_16x16x32_bf16(pah, vh, o[nf], 0, 0, 0);
        }
    }
    float invl[4];
#pragma unroll
    for (int j = 0; j < 4; ++j) invl[j] = 1.f / ls[j];
#pragma unroll
    for (int nf = 0; nf < 8; ++nf)
#pragma unroll
        for (int j = 0; j < 4; ++j) {
            long idx = (long)(b * SEQ + qbase + 4 * g + j) * DIM + h * HDIM + nf * 16 + lr;
            short hh, ll;
            splitf(o[nf][j] * invl[j], hh, ll);
            ohi[idx] = hh;
            olo[idx] = ll;
        }
}

// ---------------- router: sigmoid gate + top-4 + renorm ----------------
__global__ __launch_bounds__(256)
void router_k(const float* __restrict__ x, const float* __restrict__ gw,
              float* __restrict__ topw, int* __restrict__ topi,
              int* __restrict__ posb, int* __restrict__ counts)
{
    int t = blockIdx.x, tid = threadIdx.x;
    int e = tid & 31, ch = tid >> 5;
    const float* xp = x + (long)t * DIM + ch * 256;
    float p = 0.f;
    for (int d = 0; d < 256; ++d) p += xp[d] * gw[(ch * 256 + d) * NE + e];
    __shared__ float red[8][32];
    __shared__ float gv[32];
    red[ch][e] = p;
    __syncthreads();
    if (tid < 32) {
        float s = 0.f;
        for (int c = 0; c < 8; ++c) s += red[c][tid];
        gv[tid] = 1.f / (1.f + expf(-s));
    }
    __syncthreads();
    if (tid == 0) {
        float lg[32];
        for (int i = 0; i < 32; ++i) lg[i] = gv[i];
        float tv[TOPK]; int ti[TOPK]; float wsum = 0.f;
        for (int j = 0; j < TOPK; ++j) {
            float bv = -1e30f; int bi = 0;
            for (int i = 0; i < 32; ++i) if (lg[i] > bv) { bv = lg[i]; bi = i; }
            tv[j] = bv; ti[j] = bi; lg[bi] = -1e30f; wsum += bv;
        }
        float r = 1.f / wsum;
        for (int j = 0; j < TOPK; ++j) {
            topw[t * TOPK + j] = tv[j] * r;
            topi[t * TOPK + j] = ti[j];
            posb[t * TOPK + j] = atomicAdd(&counts[ti[j]], 1);
        }
    }
}

__global__ void initmoe_k(int* __restrict__ rowmap, float* __restrict__ wslot,
                          int* __restrict__ counts, int* __restrict__ zb)
{
    int i = blockIdx.x * 256 + threadIdx.x;
    if (i < MAXROWS) { rowmap[i] = -1; wslot[i] = 0.f; }
    if (i < NE) counts[i] = 0;
    if (i < 4096) zb[i] = 0;
}

__global__ void prep_k(const int* __restrict__ counts, int* __restrict__ padoff,
                       int* __restrict__ tile_e, int* __restrict__ tile_base, int* __restrict__ ntl)
{
    if (threadIdx.x == 0 && blockIdx.x == 0) {
        int nt = 0, rb = 0;
        for (int e = 0; e < NE; ++e) {
            padoff[e] = rb;
            int c = counts[e];
            int te = (c + 127) >> 7;
            for (int i = 0; i < te; ++i) { tile_e[nt] = e; tile_base[nt] = rb + i * 128; ++nt; }
            rb += te * 128;
        }
        *ntl = nt;
    }
}

__global__ void scatter_k(const int* __restrict__ topi, const float* __restrict__ topw,
                          const int* __restrict__ posb, const int* __restrict__ padoff,
                          int* __restrict__ rowmap, float* __restrict__ wslot)
{
    int i = blockIdx.x * 256 + threadIdx.x;
    if (i < T_TOK * TOPK) {
        int e = topi[i];
        int s = padoff[e] + posb[i];
        rowmap[s] = i >> 2;
        wslot[s] = topw[i];
    }
}

// ---------------- launch ----------------
extern "C" void kernel_launch(void* const* d_in, const int* in_sizes, int n_in,
                              void* d_out, int out_size, void* d_ws, size_t ws_size,
                              hipStream_t stream)
{
    (void)in_sizes; (void)n_in; (void)out_size;
    const int*   positions = (const int*)  d_in[0];
    const float* hidden    = (const float*)d_in[1];
    const float* in_ln     = (const float*)d_in[2];
    const float* post_ln   = (const float*)d_in[3];
    const float* q_norm    = (const float*)d_in[4];
    const float* k_norm    = (const float*)d_in[5];
    const float* wq        = (const float*)d_in[6];
    const float* wk        = (const float*)d_in[7];
    const float* wv        = (const float*)d_in[8];
    const float* wo        = (const float*)d_in[9];
    const float* gate_w    = (const float*)d_in[10];
    const float* sh_wg     = (const float*)d_in[11];
    const float* sh_wu     = (const float*)d_in[12];
    const float* sh_wd     = (const float*)d_in[13];
    const float* e_wg      = (const float*)d_in[14];
    const float* e_wu      = (const float*)d_in[15];
    const float* e_wd      = (const float*)d_in[16];
    float* out = (float*)d_out;
    char* ws = (char*)d_ws;

#define MB (1048576L)
    // proven-safe region is [0, ~126MB); ET (big path) needs ws_size >= 256MB
    short* hfhi    = (short*)(ws + 0*MB);      // dead after QKV
    short* hflo    = (short*)(ws + 8*MB);
    short* gatesh  = (short*)(ws + 0*MB);      // shared phase
    short* shint   = (short*)(ws + 8*MB);
    short* interbf = (short*)(ws + 0*MB);      // expert phase, 27MB (rows<=13k)
    short* wqThi   = (short*)(ws + 16*MB);     // dead after Q gemm
    short* wqTlo   = (short*)(ws + 24*MB);
    float* h2lnf   = (float*)(ws + 16*MB);     // born step 6
    short* wkThi   = (short*)(ws + 32*MB);
    short* wkTlo   = (short*)(ws + 34*MB);
    short* wvThi   = (short*)(ws + 36*MB);
    short* wvTlo   = (short*)(ws + 38*MB);
    short* h2lnbf  = (short*)(ws + 32*MB);     // born step 6
    short* woThi   = (short*)(ws + 40*MB);     // dead after Wo gemm
    short* woTlo   = (short*)(ws + 48*MB);
    short* shTwd   = (short*)(ws + 40*MB);     // born shared phase (8MB)
    short* qhi     = (short*)(ws + 56*MB);     // dead after attn
    short* qlo     = (short*)(ws + 64*MB);
    float* kf      = (float*)(ws + 72*MB);     // dead after rope
    short* khi     = (short*)(ws + 76*MB);
    short* klo     = (short*)(ws + 78*MB);
    short* vhi     = (short*)(ws + 80*MB);     // V TRANSPOSED planes [512][2048]
    short* vlo     = (short*)(ws + 82*MB);
    float* h2      = (float*)(ws + 72*MB);     // born step 5 (16MB)
    float* qf      = (float*)(ws + 88*MB);     // dead after rope
    short* attnhi  = (short*)(ws + 88*MB);     // born attn
    short* attnlo  = (short*)(ws + 96*MB);
    short* gate_e  = (short*)(ws + 88*MB);     // expert phase, 27MB [88,115)
    short* shTwg   = (short*)(ws + 104*MB);    // shared phase (dead before gate_e write)
    short* shTwu   = (short*)(ws + 112*MB);
    char*  S       = ws + 120*MB;              // bookkeeping (proven region)
    float* topw    = (float*)(S);
    int*   topi    = (int*)  (S + 32768);
    int*   posb    = (int*)  (S + 65536);
    int*   counts  = (int*)  (S + 98304);
    int*   padoff  = (int*)  (S + 98560);
    int*   ntl     = (int*)  (S + 98816);
    int*   tile_e  = (int*)  (S + 99072);
    int*   tile_b  = (int*)  (S + 99584);
    int*   rowmap  = (int*)  (S + 100352);
    float* wslot   = (float*)(S + 165888);
    short* zbuf    = (short*)(S + 231424);     // 16KB zeros
    short* ET      = (short*)(ws + 128*MB);    // big path only: 128MB bf16T experts
    bool big = (ws_size >= (size_t)268435456);
#undef MB

    dim3 blk(256);

    // 1) input RMSNorm -> hi/lo planes; split+transpose attention weights
    rmsnorm_k<0><<<T_TOK, blk, 0, stream>>>(hidden, in_ln, hfhi, hflo, nullptr);
    splitw_k<<<dim3(32,32), blk, 0, stream>>>(wq, wqThi, wqTlo, 2048, 2048);
    splitw_k<<<dim3(32,8),  blk, 0, stream>>>(wk, wkThi, wkTlo, 2048, 512);
    splitw_k<<<dim3(32,8),  blk, 0, stream>>>(wv, wvThi, wvTlo, 2048, 512);
    splitw_k<<<dim3(32,32), blk, 0, stream>>>(wo, woThi, woTlo, 2048, 2048);
    // 2) QKV projections (split, m97 staging); V written pre-transposed
    gemmsp3_k<0><<<dim3(16,16), blk, 0, stream>>>(hfhi, hflo, wqThi, wqTlo, qf, nullptr, nullptr, nullptr, 2048, 2048);
    gemmsp3_k<0><<<dim3(16,4),  blk, 0, stream>>>(hfhi, hflo, wkThi, wkTlo, kf, nullptr, nullptr, nullptr,  512, 2048);
    gemmsp3_k<6><<<dim3(16,4),  blk, 0, stream>>>(hfhi, hflo, wvThi, wvTlo, nullptr, nullptr, vhi, vlo,     512, 2048);
    // 3) qk-norm + rope -> split planes
    rope2_k<<<dim3(T_TOK,5), blk, 0, stream>>>(qf, kf, q_norm, k_norm, positions, qhi, qlo, khi, klo);
    // 4) causal flash attention (barrier-free, V pre-transposed) -> split output
    attn_k<<<512, blk, 0, stream>>>(qhi, qlo, khi, klo, vhi, vlo, attnhi, attnlo);
    // 5) output projection + residual
    gemmsp3_k<1><<<dim3(16,16), blk, 0, stream>>>(attnhi, attnlo, woThi, woTlo, h2, hidden, nullptr, nullptr, 2048, 2048);
    // 6) post-attn RMSNorm
    rmsnorm_k<1><<<T_TOK, blk, 0, stream>>>(h2, post_ln, h2lnbf, nullptr, h2lnf);
    // 7) router + MoE bookkeeping
    initmoe_k<<<64, blk, 0, stream>>>(rowmap, wslot, counts, (int*)zbuf);
    router_k<<<T_TOK, blk, 0, stream>>>(h2lnf, gate_w, topw, topi, posb, counts);
    prep_k<<<1, 64, 0, stream>>>(counts, padoff, tile_e, tile_b, ntl);
    scatter_k<<<32, blk, 0, stream>>>(topi, topw, posb, padoff, rowmap, wslot);
    // 8) shared expert: convert to bf16T (fits), then gate / up(silu) / down(+resid)
    cvtT_k<<<dim3(32,32,1), blk, 0, stream>>>(sh_wg, shTwg, 2048, 2048);
    cvtT_k<<<dim3(32,32,1), blk, 0, stream>>>(sh_wu, shTwu, 2048, 2048);
    cvtT_k<<<dim3(32,32,1), blk, 0, stream>>>(sh_wd, shTwd, 2048, 2048);
    gemm3_k<3,false,false><<<dim3(16,16), blk, 0, stream>>>(h2lnbf, shTwg, nullptr, gatesh, nullptr, nullptr, 2048, 2048, nullptr, nullptr, nullptr, nullptr, 0, nullptr, zbuf);
    gemm3_k<5,false,false><<<dim3(16,16), blk, 0, stream>>>(h2lnbf, shTwu, nullptr, shint, nullptr, gatesh, 2048, 2048, nullptr, nullptr, nullptr, nullptr, 0, nullptr, zbuf);
    gemm3_k<1,false,false><<<dim3(16,16), blk, 0, stream>>>(shint, shTwd, out, nullptr, h2, nullptr, 2048, 2048, nullptr, nullptr, nullptr, nullptr, 0, nullptr, zbuf);
    // 9) routed experts
    if (big) {
        cvtT_k<<<dim3(32,16,NE), blk, 0, stream>>>(e_wg, ET, 2048, 1024);
        gemm3_k<3,true,true><<<dim3(MAXTILES,8), blk, 0, stream>>>(h2lnbf, ET, nullptr, gate_e, nullptr, nullptr, 1024, 2048, rowmap, tile_e, tile_b, ntl, (long)1024*2048, nullptr, zbuf);
        cvtT_k<<<dim3(32,16,NE), blk, 0, stream>>>(e_wu, ET, 2048, 1024);
        gemm3_k<5,true,true><<<dim3(MAXTILES,8), blk, 0, stream>>>(h2lnbf, ET, nullptr, interbf, nullptr, gate_e, 1024, 2048, rowmap, tile_e, tile_b, ntl, (long)1024*2048, nullptr, zbuf);
        cvtT_k<<<dim3(16,32,NE), blk, 0, stream>>>(e_wd, ET, 1024, 2048);
        gemm3_k<4,false,true><<<dim3(MAXTILES,16), blk, 0, stream>>>(interbf, ET, out, nullptr, nullptr, nullptr, 2048, 1024, rowmap, tile_e, tile_b, ntl, (long)2048*1024, wslot, zbuf);
    } else {
        gemm_k<3,true,true><<<dim3(MAXTILES,8), blk, 0, stream>>>(h2lnbf, e_wg, nullptr, gate_e, nullptr, nullptr, 1024, 2048, rowmap, tile_e, tile_b, ntl, (long)2048*1024, nullptr);
        gemm_k<5,true,true><<<dim3(MAXTILES,8), blk, 0, stream>>>(h2lnbf, e_wu, nullptr, interbf, nullptr, gate_e, 1024, 2048, rowmap, tile_e, tile_b, ntl, (long)2048*1024, nullptr);
        gemm_k<4,false,true><<<dim3(MAXTILES,16), blk, 0, stream>>>(interbf, e_wd, out, nullptr, nullptr, nullptr, 2048, 1024, rowmap, tile_e, tile_b, ntl, (long)1024*2048, wslot);
    }
}

// Round 11
// 1397.076 us; speedup vs baseline: 1.0707x; 1.0049x over previous
//
#include <hip/hip_runtime.h>

// Problem constants
#define T_TOK 2048   // B*S
#define DIM   2048
#define NQ    16
#define NKV   4
#define HDIM  128
#define NE    32
#define TOPK  4
#define FF    1024
#define FSH   2048
#define SEQ   1024
#define MAXROWS 16384
#define MAXTILES 96

typedef __attribute__((ext_vector_type(4))) float f32x4;
typedef __attribute__((ext_vector_type(8))) short bf16x8;

__device__ __forceinline__ short f2bf(float f) {
    union { float f; unsigned u; } c; c.f = f;
    unsigned r = (c.u + 0x7fffu + ((c.u >> 16) & 1u)) >> 16;
    return (short)r;
}
__device__ __forceinline__ float bf2f(short h) {
    union { unsigned u; float f; } c; c.u = ((unsigned)(unsigned short)h) << 16;
    return c.f;
}
__device__ __forceinline__ void splitf(float v, short& hi, short& lo) {
    hi = f2bf(v);
    lo = f2bf(v - bf2f(hi));
}
// bijective XCD-chunk swizzle (m204)
__device__ __forceinline__ int xcd_swz(int lin, int total) {
    int q8 = total >> 3, r8 = total & 7;
    int xcd = lin & 7, idx = lin >> 3;
    return (xcd < r8 ? xcd * (q8 + 1) : r8 * (q8 + 1) + (xcd - r8) * q8) + idx;
}
// async global->LDS, 16B per lane; lds dest = wave-uniform base + lane*16
__device__ __forceinline__ void gl16(const void* g, void* l) {
    __builtin_amdgcn_global_load_lds(
        (const __attribute__((address_space(1))) unsigned int*)g,
        (__attribute__((address_space(3))) unsigned int*)l, 16, 0, 0);
}

// ---------------- RMSNorm. MODE 0: hi/lo bf16 planes. MODE 1: bf16 + fp32 ----------------
template<int MODE>
__global__ __launch_bounds__(256)
void rmsnorm_k(const float* __restrict__ x, const float* __restrict__ sc,
               short* __restrict__ ybh, short* __restrict__ ybl, float* __restrict__ yf)
{
    long base = (long)blockIdx.x * DIM;
    int tid = threadIdx.x;
    const float* xp = x + base + tid * 8;
    float4 a = *(const float4*)xp;
    float4 b = *(const float4*)(xp + 4);
    float ss = a.x*a.x + a.y*a.y + a.z*a.z + a.w*a.w
             + b.x*b.x + b.y*b.y + b.z*b.z + b.w*b.w;
#pragma unroll
    for (int off = 32; off > 0; off >>= 1) ss += __shfl_xor(ss, off);
    __shared__ float red[4];
    if ((tid & 63) == 0) red[tid >> 6] = ss;
    __syncthreads();
    float s = red[0] + red[1] + red[2] + red[3];
    float inv = rsqrtf(s * (1.f / DIM) + 1e-6f);
    const float* sp = sc + tid * 8;
    float4 s0 = *(const float4*)sp;
    float4 s1 = *(const float4*)(sp + 4);
    float o[8];
    o[0]=a.x*inv*s0.x; o[1]=a.y*inv*s0.y; o[2]=a.z*inv*s0.z; o[3]=a.w*inv*s0.w;
    o[4]=b.x*inv*s1.x; o[5]=b.y*inv*s1.y; o[6]=b.z*inv*s1.z; o[7]=b.w*inv*s1.w;
    if (MODE == 0) {
        union { short s[8]; int4 v; } ph, pl;
#pragma unroll
        for (int i = 0; i < 8; ++i) splitf(o[i], ph.s[i], pl.s[i]);
        *(int4*)(ybh + base + tid * 8) = ph.v;
        *(int4*)(ybl + base + tid * 8) = pl.v;
    } else {
        union { short s[8]; int4 v; } ph;
#pragma unroll
        for (int i = 0; i < 8; ++i) ph.s[i] = f2bf(o[i]);
        *(int4*)(ybh + base + tid * 8) = ph.v;
        float4 w0; w0.x=o[0]; w0.y=o[1]; w0.z=o[2]; w0.w=o[3];
        float4 w1; w1.x=o[4]; w1.y=o[5]; w1.z=o[6]; w1.w=o[7];
        *(float4*)(yf + base + tid * 8) = w0;
        *(float4*)(yf + base + tid * 8 + 4) = w1;
    }
}

// -------- split+transpose weights: W[K][N] fp32 -> Thi/Tlo[N][K] bf16 --------
__global__ __launch_bounds__(256)
void splitw_k(const float* __restrict__ W, short* __restrict__ Thi, short* __restrict__ Tlo,
              int K, int N)
{
    __shared__ float t[64][65];
    int k0 = blockIdx.x * 64, n0 = blockIdx.y * 64;
    int tid = threadIdx.x;
    int rr = tid >> 4, cc = (tid & 15) * 4;
#pragma unroll
    for (int i = 0; i < 4; ++i) {
        int row = rr + i * 16;
        float4 v = *(const float4*)(W + (long)(k0 + row) * N + n0 + cc);
        t[row][cc] = v.x; t[row][cc+1] = v.y; t[row][cc+2] = v.z; t[row][cc+3] = v.w;
    }
    __syncthreads();
    int n = tid >> 2, kc = (tid & 3) * 16;
    union { short s[16]; int4 v[2]; } uh, ul;
#pragma unroll
    for (int j = 0; j < 16; ++j) splitf(t[kc + j][n], uh.s[j], ul.s[j]);
    long ob = (long)(n0 + n) * K + k0 + kc;
    *(int4*)(Thi + ob) = uh.v[0];
    *(int4*)(Thi + ob + 8) = uh.v[1];
    *(int4*)(Tlo + ob) = ul.v[0];
    *(int4*)(Tlo + ob + 8) = ul.v[1];
}

// -------- convert+transpose: W[K][N] fp32 -> T[N][K] bf16 (per blockIdx.z matrix) --------
__global__ __launch_bounds__(256)
void cvtT_k(const float* __restrict__ W, short* __restrict__ T, int K, int N)
{
    __shared__ float t[64][65];
    const float* Wp = W + (long)blockIdx.z * K * N;
    short* Tp = T + (long)blockIdx.z * K * N;
    int k0 = blockIdx.x * 64, n0 = blockIdx.y * 64;
    int tid = threadIdx.x;
    int rr = tid >> 4, cc = (tid & 15) * 4;
#pragma unroll
    for (int i = 0; i < 4; ++i) {
        int row = rr + i * 16;
        float4 v = *(const float4*)(Wp + (long)(k0 + row) * N + n0 + cc);
        t[row][cc] = v.x; t[row][cc+1] = v.y; t[row][cc+2] = v.z; t[row][cc+3] = v.w;
    }
    __syncthreads();
    int n = tid >> 2, kc = (tid & 3) * 16;
    union { short s[16]; int4 v[2]; } u;
#pragma unroll
    for (int j = 0; j < 16; ++j) u.s[j] = f2bf(t[kc + j][n]);
    long ob = (long)(n0 + n) * K + k0 + kc;
    *(int4*)(Tp + ob) = u.v[0];
    *(int4*)(Tp + ob + 8) = u.v[1];
}

// ------- Split GEMM (m97-style): C = (Ahi+Alo)[M][K] @ (BThi+BTlo)[N][K]^T -------
// EPI 0: Cf=acc ; 1: Cf=acc+addb ; 2: split acc -> Ohi/Olo (row-major)
// EPI 6: split acc -> Ohi/Olo TRANSPOSED [col][row] (for V: [hd-slot][token])
template<int EPI>
__global__ __launch_bounds__(256)
void gemmsp3_k(const short* __restrict__ Ahi, const short* __restrict__ Alo,
               const short* __restrict__ BThi, const short* __restrict__ BTlo,
               float* __restrict__ Cf, const float* __restrict__ addb,
               short* __restrict__ Ohi, short* __restrict__ Olo,
               int N, int K)
{
    int nby = gridDim.y;
    int total = gridDim.x * nby;
    int lin = blockIdx.x + gridDim.x * blockIdx.y;
    int vt = xcd_swz(lin, total);
    int row0 = (vt / nby) * 128, col0 = (vt % nby) * 128;
    __shared__ short Ah[4096], Al[4096], Bh[4096], Bl[4096];
    int tid = threadIdx.x, w = tid >> 6, l = tid & 63, g = l >> 4, lr = l & 15;
    int wr = w >> 1, wc = w & 1;
    int srt = tid >> 2, klane = (tid & 3) * 8;
    const short* pah0 = Ahi + (long)(row0 + srt) * K + klane;
    const short* pah1 = Ahi + (long)(row0 + srt + 64) * K + klane;
    const short* pal0 = Alo + (long)(row0 + srt) * K + klane;
    const short* pal1 = Alo + (long)(row0 + srt + 64) * K + klane;
    const short* pbh0 = BThi + (long)(col0 + srt) * K + klane;
    const short* pbh1 = BThi + (long)(col0 + srt + 64) * K + klane;
    const short* pbl0 = BTlo + (long)(col0 + srt) * K + klane;
    const short* pbl1 = BTlo + (long)(col0 + srt + 64) * K + klane;
    short* dA = Ah + w * 512;
    short* dAl = Al + w * 512;
    short* dB = Bh + w * 512;
    short* dBl = Bl + w * 512;
    f32x4 acc[4][4];
#pragma unroll
    for (int m = 0; m < 4; ++m)
#pragma unroll
        for (int n = 0; n < 4; ++n) acc[m][n] = (f32x4){0,0,0,0};
    for (int kk = 0; kk < K; kk += 32) {
        gl16(pah0 + kk, dA);        gl16(pah1 + kk, dA + 2048);
        gl16(pal0 + kk, dAl);       gl16(pal1 + kk, dAl + 2048);
        gl16(pbh0 + kk, dB);        gl16(pbh1 + kk, dB + 2048);
        gl16(pbl0 + kk, dBl);       gl16(pbl1 + kk, dBl + 2048);
        asm volatile("s_waitcnt vmcnt(0)" ::: "memory");
        __syncthreads();
        bf16x8 ah[4], al[4], bh[4], bl[4];
#pragma unroll
        for (int m = 0; m < 4; ++m) {
            int off = (wr * 64 + m * 16 + lr) * 32 + g * 8;
            ah[m] = *(const bf16x8*)(Ah + off);
            al[m] = *(const bf16x8*)(Al + off);
        }
#pragma unroll
        for (int n = 0; n < 4; ++n) {
            int off = (wc * 64 + n * 16 + lr) * 32 + g * 8;
            bh[n] = *(const bf16x8*)(Bh + off);
            bl[n] = *(const bf16x8*)(Bl + off);
        }
#pragma unroll
        for (int m = 0; m < 4; ++m)
#pragma unroll
            for (int n = 0; n < 4; ++n) {
                acc[m][n] = __builtin_amdgcn_mfma_f32_16x16x32_bf16(al[m], bh[n], acc[m][n], 0, 0, 0);
                acc[m][n] = __builtin_amdgcn_mfma_f32_16x16x32_bf16(ah[m], bl[n], acc[m][n], 0, 0, 0);
                acc[m][n] = __builtin_amdgcn_mfma_f32_16x16x32_bf16(ah[m], bh[n], acc[m][n], 0, 0, 0);
            }
        __syncthreads();
    }
#pragma unroll
    for (int m = 0; m < 4; ++m)
#pragma unroll
        for (int n = 0; n < 4; ++n) {
            if (EPI == 6) {
                short4 h4, l4;
#pragma unroll
                for (int j = 0; j < 4; ++j)
                    splitf(acc[m][n][j], ((short*)&h4)[j], ((short*)&l4)[j]);
                int rowb = row0 + wr * 64 + m * 16 + 4 * g;
                int col = col0 + wc * 64 + n * 16 + lr;
                *(short4*)(Ohi + (long)col * T_TOK + rowb) = h4;
                *(short4*)(Olo + (long)col * T_TOK + rowb) = l4;
            } else {
#pragma unroll
                for (int j = 0; j < 4; ++j) {
                    int row = row0 + wr * 64 + m * 16 + 4 * g + j;
                    int col = col0 + wc * 64 + n * 16 + lr;
                    float v = acc[m][n][j];
                    if (EPI == 0) Cf[(long)row * N + col] = v;
                    else if (EPI == 1) Cf[(long)row * N + col] = v + addb[(long)row * N + col];
                    else {
                        short hh, ll;
                        splitf(v, hh, ll);
                        Ohi[(long)row * N + col] = hh;
                        Olo[(long)row * N + col] = ll;
                    }
                }
            }
        }
}

// ------- bf16 GEMM (m97-style): C[M,N] = A[M][K] @ BT[N][K]^T, global_load_lds staging -------
// EPI 1: Cf=acc+addb ; 3: Cbf=bf16(acc) ; 5: Cbf=bf16(silu(gsrc)*acc) ;
// EPI 4: atomicAdd(Cf[tok*DIM+col], wslot[row]*acc)
template<int EPI, bool GATHER, bool EXPERT>
__global__ __launch_bounds__(256)
void gemm3_k(const short* __restrict__ A, const short* __restrict__ BTg,
             float* __restrict__ Cf, short* __restrict__ Cbf,
             const float* __restrict__ addb, const short* __restrict__ gsrc,
             int N, int K,
             const int* __restrict__ rowmap, const int* __restrict__ tile_e,
             const int* __restrict__ tile_base, const int* __restrict__ ntiles,
             long strideBT, const float* __restrict__ wslot,
             const short* __restrict__ zbuf)
{
    int nby = gridDim.y;
    int total = gridDim.x * nby;
    int lin = blockIdx.x + gridDim.x * blockIdx.y;
    int vt = xcd_swz(lin, total);
    int bx = vt / nby, by = vt % nby;
    int row0;
    const short* BT;
    if (EXPERT) {
        if (bx >= *ntiles) return;
        int e = tile_e[bx];
        row0 = tile_base[bx];
        BT = BTg + (long)e * strideBT;
    } else {
        row0 = bx * 128; BT = BTg;
    }
    int col0 = by * 128;
    __shared__ short As[4096], Bs[4096];
    int tid = threadIdx.x, w = tid >> 6, l = tid & 63, g = l >> 4, lr = l & 15;
    int wr = w >> 1, wc = w & 1;
    int srt = tid >> 2, klane = (tid & 3) * 8;
    const short *ap0, *ap1;
    if (GATHER) {
        int r0 = rowmap[row0 + srt], r1 = rowmap[row0 + srt + 64];
        ap0 = (r0 >= 0) ? (A + (long)r0 * K + klane) : (zbuf + klane);
        ap1 = (r1 >= 0) ? (A + (long)r1 * K + klane) : (zbuf + klane);
    } else {
        ap0 = A + (long)(row0 + srt) * K + klane;
        ap1 = A + (long)(row0 + srt + 64) * K + klane;
    }
    const short* bp0 = BT + (long)(col0 + srt) * K + klane;
    const short* bp1 = BT + (long)(col0 + srt + 64) * K + klane;
    short* dA = As + w * 512;
    short* dB = Bs + w * 512;
    f32x4 acc[4][4];
#pragma unroll
    for (int m = 0; m < 4; ++m)
#pragma unroll
        for (int n = 0; n < 4; ++n) acc[m][n] = (f32x4){0,0,0,0};
    for (int kk = 0; kk < K; kk += 32) {
        gl16(ap0 + kk, dA);  gl16(ap1 + kk, dA + 2048);
        gl16(bp0 + kk, dB);  gl16(bp1 + kk, dB + 2048);
        asm volatile("s_waitcnt vmcnt(0)" ::: "memory");
        __syncthreads();
        bf16x8 af[4], bf[4];
#pragma unroll
        for (int m = 0; m < 4; ++m)
            af[m] = *(const bf16x8*)(As + (wr * 64 + m * 16 + lr) * 32 + g * 8);
#pragma unroll
        for (int n = 0; n < 4; ++n)
            bf[n] = *(const bf16x8*)(Bs + (wc * 64 + n * 16 + lr) * 32 + g * 8);
#pragma unroll
        for (int m = 0; m < 4; ++m)
#pragma unroll
            for (int n = 0; n < 4; ++n)
                acc[m][n] = __builtin_amdgcn_mfma_f32_16x16x32_bf16(af[m], bf[n], acc[m][n], 0, 0, 0);
        __syncthreads();
    }
#pragma unroll
    for (int m = 0; m < 4; ++m)
#pragma unroll
        for (int n = 0; n < 4; ++n)
#pragma unroll
            for (int j = 0; j < 4; ++j) {
                int row = row0 + wr * 64 + m * 16 + 4 * g + j;
                int col = col0 + wc * 64 + n * 16 + lr;
                float v = acc[m][n][j];
                if (EPI == 1) Cf[(long)row * N + col] = v + addb[(long)row * N + col];
                else if (EPI == 3) Cbf[(long)row * N + col] = f2bf(v);
                else if (EPI == 5) {
                    float gv_ = bf2f(gsrc[(long)row * N + col]);
                    float sg = gv_ / (1.f + __expf(-gv_));
                    Cbf[(long)row * N + col] = f2bf(sg * v);
                } else if (EPI == 4) {
                    int tok = rowmap[row];
                    if (tok >= 0) atomicAdd(&Cf[(long)tok * DIM + col], wslot[row] * v);
                }
            }
}

// ---- fallback bf16 GEMM (round-6 proven): fp32 B reg-transpose staging, 2-deep prefetch ----
template<int EPI, bool GATHER, bool EXPERT>
__global__ __launch_bounds__(256)
void gemm_k(const short* __restrict__ A, const float* __restrict__ Bg,
            float* __restrict__ Cf, short* __restrict__ Cbf,
            const float* __restrict__ addb, const short* __restrict__ gsrc,
            int N, int K,
            const int* __restrict__ rowmap, const int* __restrict__ tile_e,
            const int* __restrict__ tile_base, const int* __restrict__ ntiles,
            long strideB, const float* __restrict__ wslot)
{
    int nby = gridDim.y;
    int total = gridDim.x * nby;
    int lin = blockIdx.x + gridDim.x * blockIdx.y;
    int vt = xcd_swz(lin, total);
    int bx = vt / nby, by = vt % nby;
    int row0;
    const float* B;
    if (EXPERT) {
        if (bx >= *ntiles) return;
        int e = tile_e[bx];
        row0 = tile_base[bx];
        B = Bg + (long)e * strideB;
    } else {
        row0 = bx * 128; B = Bg;
    }
    int col0 = by * 128;
    __shared__ short As[5120], Bs[5120];
    int tid = threadIdx.x;
    int w = tid >> 6, l = tid & 63, g = l >> 4, lr = l & 15;
    int wr = w >> 1, wc = w & 1;
    f32x4 acc[4][4];
#pragma unroll
    for (int m = 0; m < 4; ++m)
#pragma unroll
        for (int n = 0; n < 4; ++n) acc[m][n] = (f32x4){0,0,0,0};
    int ar = tid >> 2, ak = (tid & 3) * 8;
    int bk0 = (tid >> 5) * 4, bc0 = (tid & 31) * 4;
    bool rok[2]; const short* abase[2];
#pragma unroll
    for (int it = 0; it < 2; ++it) {
        int r = row0 + ar + it * 64;
        int sr = GATHER ? rowmap[r] : r;
        rok[it] = (!GATHER) || (sr >= 0);
        abase[it] = A + (long)(rok[it] ? sr : 0) * K + ak;
    }
    const float* bb = B + (long)bk0 * N + col0 + bc0;
    int4 aE[2], aO[2];
    float4 bE[4], bO[4];
#pragma unroll
    for (int it = 0; it < 2; ++it) {
        aE[it] = rok[it] ? *(const int4*)(abase[it]) : (int4){0,0,0,0};
        aO[it] = rok[it] ? *(const int4*)(abase[it] + 32) : (int4){0,0,0,0};
    }
#pragma unroll
    for (int q = 0; q < 4; ++q) {
        bE[q] = *(const float4*)(bb + (long)q * N);
        bO[q] = *(const float4*)(bb + (long)(32 + q) * N);
    }

#define GEMM_STEP(BANKA, BANKB, KNEXT)                                        \
    {                                                                         \
        __syncthreads();                                                      \
        _Pragma("unroll")                                                     \
        for (int it = 0; it < 2; ++it)                                        \
            *(int4*)(As + (ar + it * 64) * 40 + ak) = BANKA[it];              \
        _Pragma("unroll")                                                     \
        for (int j = 0; j < 4; ++j) {                                         \
            short4 pk;                                                        \
            pk.x = f2bf(((const float*)&BANKB[0])[j]);                        \
            pk.y = f2bf(((const float*)&BANKB[1])[j]);                        \
            pk.z = f2bf(((const float*)&BANKB[2])[j]);                        \
            pk.w = f2bf(((const float*)&BANKB[3])[j]);                        \
            int c = bc0 + j;                                                  \
            int blk = (bk0 >> 3) ^ ((c >> 2) & 3);                            \
            *(short4*)(Bs + c * 40 + blk * 8 + (bk0 & 4)) = pk;               \
        }                                                                     \
        if ((KNEXT) < K) {                                                    \
            _Pragma("unroll")                                                 \
            for (int it = 0; it < 2; ++it)                                    \
                BANKA[it] = rok[it] ? *(const int4*)(abase[it] + (KNEXT))     \
                                    : (int4){0,0,0,0};                        \
            _Pragma("unroll")                                                 \
            for (int q = 0; q < 4; ++q)                                       \
                BANKB[q] = *(const float4*)(bb + (long)((KNEXT) + q) * N);    \
        }                                                                     \
        __syncthreads();                                                      \
        bf16x8 af[4], bf[4];                                                  \
        _Pragma("unroll")                                                     \
        for (int m = 0; m < 4; ++m)                                           \
            af[m] = *(const bf16x8*)(As + (wr * 64 + m * 16 + lr) * 40 + g * 8); \
        _Pragma("unroll")                                                     \
        for (int n = 0; n < 4; ++n) {                                         \
            int c = wc * 64 + n * 16 + lr;                                    \
            int blk = g ^ ((c >> 2) & 3);                                     \
            bf[n] = *(const bf16x8*)(Bs + c * 40 + blk * 8);                  \
        }                                                                     \
        _Pragma("unroll")                                                     \
        for (int m = 0; m < 4; ++m)                                           \
            _Pragma("unroll")                                                 \
            for (int n = 0; n < 4; ++n)                                       \
                acc[m][n] = __builtin_amdgcn_mfma_f32_16x16x32_bf16(af[m], bf[n], acc[m][n], 0, 0, 0); \
    }

    for (int kk = 0; kk < K; kk += 64) {
        GEMM_STEP(aE, bE, kk + 64)
        GEMM_STEP(aO, bO, kk + 96)
    }
#undef GEMM_STEP

#pragma unroll
    for (int m = 0; m < 4; ++m)
#pragma unroll
        for (int n = 0; n < 4; ++n)
#pragma unroll
            for (int j = 0; j < 4; ++j) {
                int row = row0 + wr * 64 + m * 16 + 4 * g + j;
                int col = col0 + wc * 64 + n * 16 + lr;
                float v = acc[m][n][j];
                if (EPI == 1) Cf[(long)row * N + col] = v + addb[(long)row * N + col];
                else if (EPI == 3) Cbf[(long)row * N + col] = f2bf(v);
                else if (EPI == 5) {
                    float gv_ = bf2f(gsrc[(long)row * N + col]);
                    float sg = gv_ / (1.f + __expf(-gv_));
                    Cbf[(long)row * N + col] = f2bf(sg * v);
                } else if (EPI == 4) {
                    int tok = rowmap[row];
                    if (tok >= 0) atomicAdd(&Cf[(long)tok * DIM + col], wslot[row] * v);
                }
            }
}

// ---------------- qk-norm + neox RoPE + scale -> split bf16 planes ----------------
__global__ __launch_bounds__(256)
void rope2_k(const float* __restrict__ qf, const float* __restrict__ kf,
             const float* __restrict__ qn, const float* __restrict__ kn,
             const int* __restrict__ posp,
             short* __restrict__ qhi, short* __restrict__ qlo,
             short* __restrict__ khi, short* __restrict__ klo)
{
    int t = blockIdx.x;
    int w = threadIdx.x >> 6, l = threadIdx.x & 63;
    int hi = blockIdx.y * 4 + w;   // 0..19
    const float* src; const float* nrm; float esc;
    short* dh; short* dl;
    if (hi < NQ) {
        long off = (long)t * DIM + hi * HDIM;
        src = qf + off; nrm = qn; dh = qhi + off; dl = qlo + off;
        esc = 0.08838834764831843f;  // HD^-0.5 folded into q
    } else {
        int kh = hi - NQ;
        long off = (long)t * (NKV * HDIM) + kh * HDIM;
        src = kf + off; nrm = kn; dh = khi + off; dl = klo + off;
        esc = 1.f;
    }
    float x1 = src[l], x2 = src[l + 64];
    float ss = x1 * x1 + x2 * x2;
#pragma unroll
    for (int off = 32; off > 0; off >>= 1) ss += __shfl_xor(ss, off);
    float inv = rsqrtf(ss * (1.f / HDIM) + 1e-6f);
    float a1 = x1 * inv * nrm[l], a2 = x2 * inv * nrm[l + 64];
    float p = (float)posp[t];
    float fr = expf((float)l * -0.21586735246819178f); // -ln(1e6)/64
    float ang = p * fr;
    float cv = cosf(ang), sv = sinf(ang);
    float v1 = (a1 * cv - a2 * sv) * esc;
    float v2 = (a1 * sv + a2 * cv) * esc;
    short hh, ll;
    splitf(v1, hh, ll); dh[l] = hh; dl[l] = ll;
    splitf(v2, hh, ll); dh[l + 64] = hh; dl[l + 64] = ll;
}

// ---------------- flash attention (causal, GQA) — 1 wave per block, balanced ----------------
// unit = (qt desc, bh, w-band); no block-shared state; vthi/vtlo: [kvh*128+hd][b*1024+t]
__global__ __launch_bounds__(64)
void attn_k(const short* __restrict__ qhi, const short* __restrict__ qlo,
            const short* __restrict__ khi, const short* __restrict__ klo,
            const short* __restrict__ vthi, const short* __restrict__ vtlo,
            short* __restrict__ ohi, short* __restrict__ olo)
{
    int u = blockIdx.x;
    int qt = 15 - (u >> 7);            // heavy q-tiles dispatch first
    int r = u & 127;
    int w = r & 3;                     // 16-row band within q-tile
    int bh = r >> 2;
    int h = bh & (NQ - 1), b = bh >> 4;
    int kvh = h >> 2;
    int l = threadIdx.x, g = l >> 4, lr = l & 15;
    int qbase = qt * 64 + w * 16;
    long qoff = (long)(b * SEQ + qbase + lr) * DIM + h * HDIM + 8 * g;
    bf16x8 qh[4], ql[4];
#pragma unroll
    for (int kc = 0; kc < 4; ++kc) {
        qh[kc] = *(const bf16x8*)(qhi + qoff + kc * 32);
        ql[kc] = *(const bf16x8*)(qlo + qoff + kc * 32);
    }
    f32x4 o[8];
#pragma unroll
    for (int i = 0; i < 8; ++i) o[i] = (f32x4){0,0,0,0};
    float mr[4] = {-1e30f, -1e30f, -1e30f, -1e30f};
    float ls[4] = {0, 0, 0, 0};
    __shared__ short Plh[640], Pll[640];      // this wave's [16 q][40 keys]
    const short* vbh = vthi + (long)kvh * HDIM * T_TOK + b * SEQ;
    const short* vbl = vtlo + (long)kvh * HDIM * T_TOK + b * SEQ;
    int nsteps = 2 * (qt + 1);
    for (int st = 0; st < nsteps; ++st) {
        int kb = st * 32;
        f32x4 sa[2]; sa[0] = (f32x4){0,0,0,0}; sa[1] = (f32x4){0,0,0,0};
#pragma unroll
        for (int kc = 0; kc < 4; ++kc)
#pragma unroll
            for (int n = 0; n < 2; ++n) {
                long koff = (long)(b * SEQ + kb + n * 16 + lr) * (NKV * HDIM) + kvh * HDIM + kc * 32 + 8 * g;
                bf16x8 kh = *(const bf16x8*)(khi + koff);
                bf16x8 kl = *(const bf16x8*)(klo + koff);
                sa[n] = __builtin_amdgcn_mfma_f32_16x16x32_bf16(ql[kc], kh, sa[n], 0, 0, 0);
                sa[n] = __builtin_amdgcn_mfma_f32_16x16x32_bf16(qh[kc], kl, sa[n], 0, 0, 0);
                sa[n] = __builtin_amdgcn_mfma_f32_16x16x32_bf16(qh[kc], kh, sa[n], 0, 0, 0);
            }
        // causal mask
#pragma unroll
        for (int n = 0; n < 2; ++n)
#pragma unroll
            for (int j = 0; j < 4; ++j) {
                int key = kb + n * 16 + lr;
                int qr = qbase + 4 * g + j;
                if (key > qr) sa[n][j] = -1e30f;
            }
        // online softmax (fp32), P stored as hi/lo bf16 planes (wave-local LDS)
#pragma unroll
        for (int j = 0; j < 4; ++j) {
            float v = fmaxf(sa[0][j], sa[1][j]);
#pragma unroll
            for (int off = 1; off < 16; off <<= 1) v = fmaxf(v, __shfl_xor(v, off));
            float mn = fmaxf(mr[j], v);
            float sc = __expf(mr[j] - mn);
            mr[j] = mn;
            float p0 = __expf(sa[0][j] - mn);
            float p1 = __expf(sa[1][j] - mn);
            float rs = p0 + p1;
#pragma unroll
            for (int off = 1; off < 16; off <<= 1) rs += __shfl_xor(rs, off);
            ls[j] = ls[j] * sc + rs;
            short hh, ll;
            splitf(p0, hh, ll);
            Plh[(4 * g + j) * 40 + lr] = hh;
            Pll[(4 * g + j) * 40 + lr] = ll;
            splitf(p1, hh, ll);
            Plh[(4 * g + j) * 40 + 16 + lr] = hh;
            Pll[(4 * g + j) * 40 + 16 + lr] = ll;
#pragma unroll
            for (int nf = 0; nf < 8; ++nf) o[nf][j] *= sc;
        }
        asm volatile("s_waitcnt lgkmcnt(0)" ::: "memory");
        __builtin_amdgcn_sched_barrier(0);
        bf16x8 pah = *(const bf16x8*)(Plh + lr * 40 + 8 * g);
        bf16x8 pal = *(const bf16x8*)(Pll + lr * 40 + 8 * g);
        __builtin_amdgcn_s_setprio(1);
#pragma unroll
        for (int nf = 0; nf < 8; ++nf) {
            long voff = (long)(nf * 16 + lr) * T_TOK + kb + 8 * g;
            bf16x8 vh = *(const bf16x8*)(vbh + voff);
            bf16x8 vl = *(const bf16x8*)(vbl + voff);
            o[nf] = __builtin_amdgcn_mfma_f32_16x16x32_bf16(pal, vh, o[nf], 0, 0, 0);
            o[nf] = __builtin_amdgcn_mfma_f32_16x16x32_bf16(pah, vl, o[nf], 0, 0, 0);
            o[nf] = __builtin_amdgcn_mfma_f32_16x16x32_bf16(pah, vh, o[nf], 0, 0, 0);
        }
        __builtin_amdgcn_s_setprio(0);
    }
    float invl[4];
#pragma unroll
    for (int j = 0; j < 4; ++j) invl[j] = 1.f / ls[j];
#pragma unroll
    for (int nf = 0; nf < 8; ++nf)
#pragma unroll
        for (int j = 0; j < 4; ++j) {
            long idx = (long)(b * SEQ + qbase + 4 * g + j) * DIM + h * HDIM + nf * 16 + lr;
            short hh, ll;
            splitf(o[nf][j] * invl[j], hh, ll);
            ohi[idx] = hh;
            olo[idx] = ll;
        }
}

// ---------------- router: sigmoid gate + top-4 + renorm ----------------
__global__ __launch_bounds__(256)
void router_k(const float* __restrict__ x, const float* __restrict__ gw,
              float* __restrict__ topw, int* __restrict__ topi,
              int* __restrict__ posb, int* __restrict__ counts)
{
    int t = blockIdx.x, tid = threadIdx.x;
    int e = tid & 31, ch = tid >> 5;
    const float* xp = x + (long)t * DIM + ch * 256;
    float p = 0.f;
    for (int d = 0; d < 256; ++d) p += xp[d] * gw[(ch * 256 + d) * NE + e];
    __shared__ float red[8][32];
    __shared__ float gv[32];
    red[ch][e] = p;
    __syncthreads();
    if (tid < 32) {
        float s = 0.f;
        for (int c = 0; c < 8; ++c) s += red[c][tid];
        gv[tid] = 1.f / (1.f + expf(-s));
    }
    __syncthreads();
    if (tid == 0) {
        float lg[32];
        for (int i = 0; i < 32; ++i) lg[i] = gv[i];
        float tv[TOPK]; int ti[TOPK]; float wsum = 0.f;
        for (int j = 0; j < TOPK; ++j) {
            float bv = -1e30f; int bi = 0;
            for (int i = 0; i < 32; ++i) if (lg[i] > bv) { bv = lg[i]; bi = i; }
            tv[j] = bv; ti[j] = bi; lg[bi] = -1e30f; wsum += bv;
        }
        float r = 1.f / wsum;
        for (int j = 0; j < TOPK; ++j) {
            topw[t * TOPK + j] = tv[j] * r;
            topi[t * TOPK + j] = ti[j];
            posb[t * TOPK + j] = atomicAdd(&counts[ti[j]], 1);
        }
    }
}

__global__ void initmoe_k(int* __restrict__ rowmap, float* __restrict__ wslot,
                          int* __restrict__ counts, int* __restrict__ zb)
{
    int i = blockIdx.x * 256 + threadIdx.x;
    if (i < MAXROWS) { rowmap[i] = -1; wslot[i] = 0.f; }
    if (i < NE) counts[i] = 0;
    if (i < 4096) zb[i] = 0;
}

__global__ void prep_k(const int* __restrict__ counts, int* __restrict__ padoff,
                       int* __restrict__ tile_e, int* __restrict__ tile_base, int* __restrict__ ntl)
{
    if (threadIdx.x == 0 && blockIdx.x == 0) {
        int nt = 0, rb = 0;
        for (int e = 0; e < NE; ++e) {
            padoff[e] = rb;
            int c = counts[e];
            int te = (c + 127) >> 7;
            for (int i = 0; i < te; ++i) { tile_e[nt] = e; tile_base[nt] = rb + i * 128; ++nt; }
            rb += te * 128;
        }
        *ntl = nt;
    }
}

__global__ void scatter_k(const int* __restrict__ topi, const float* __restrict__ topw,
                          const int* __restrict__ posb, const int* __restrict__ padoff,
                          int* __restrict__ rowmap, float* __restrict__ wslot)
{
    int i = blockIdx.x * 256 + threadIdx.x;
    if (i < T_TOK * TOPK) {
        int e = topi[i];
        int s = padoff[e] + posb[i];
        rowmap[s] = i >> 2;
        wslot[s] = topw[i];
    }
}

// ---------------- launch ----------------
extern "C" void kernel_launch(void* const* d_in, const int* in_sizes, int n_in,
                              void* d_out, int out_size, void* d_ws, size_t ws_size,
                              hipStream_t stream)
{
    (void)in_sizes; (void)n_in; (void)out_size;
    const int*   positions = (const int*)  d_in[0];
    const float* hidden    = (const float*)d_in[1];
    const float* in_ln     = (const float*)d_in[2];
    const float* post_ln   = (const float*)d_in[3];
    const float* q_norm    = (const float*)d_in[4];
    const float* k_norm    = (const float*)d_in[5];
    const float* wq        = (const float*)d_in[6];
    const float* wk        = (const float*)d_in[7];
    const float* wv        = (const float*)d_in[8];
    const float* wo        = (const float*)d_in[9];
    const float* gate_w    = (const float*)d_in[10];
    const float* sh_wg     = (const float*)d_in[11];
    const float* sh_wu     = (const float*)d_in[12];
    const float* sh_wd     = (const float*)d_in[13];
    const float* e_wg      = (const float*)d_in[14];
    const float* e_wu      = (const float*)d_in[15];
    const float* e_wd      = (const float*)d_in[16];
    float* out = (float*)d_out;
    char* ws = (char*)d_ws;

#define MB (1048576L)
    // proven-safe region is [0, ~126MB); ET (big path) needs ws_size >= 256MB
    short* hfhi    = (short*)(ws + 0*MB);      // dead after QKV
    short* hflo    = (short*)(ws + 8*MB);
    short* gatesh  = (short*)(ws + 0*MB);      // shared phase
    short* shint   = (short*)(ws + 8*MB);
    short* interbf = (short*)(ws + 0*MB);      // expert phase, 27MB (rows<=13k)
    short* wqThi   = (short*)(ws + 16*MB);     // dead after Q gemm
    short* wqTlo   = (short*)(ws + 24*MB);
    float* h2lnf   = (float*)(ws + 16*MB);     // born step 6
    short* wkThi   = (short*)(ws + 32*MB);
    short* wkTlo   = (short*)(ws + 34*MB);
    short* wvThi   = (short*)(ws + 36*MB);
    short* wvTlo   = (short*)(ws + 38*MB);
    short* h2lnbf  = (short*)(ws + 32*MB);     // born step 6
    short* woThi   = (short*)(ws + 40*MB);     // dead after Wo gemm
    short* woTlo   = (short*)(ws + 48*MB);
    short* shTwd   = (short*)(ws + 40*MB);     // born shared phase (8MB)
    short* qhi     = (short*)(ws + 56*MB);     // dead after attn
    short* qlo     = (short*)(ws + 64*MB);
    float* kf      = (float*)(ws + 72*MB);     // dead after rope
    short* khi     = (short*)(ws + 76*MB);
    short* klo     = (short*)(ws + 78*MB);
    short* vhi     = (short*)(ws + 80*MB);     // V TRANSPOSED planes [512][2048]
    short* vlo     = (short*)(ws + 82*MB);
    float* h2      = (float*)(ws + 72*MB);     // born step 5 (16MB)
    float* qf      = (float*)(ws + 88*MB);     // dead after rope
    short* attnhi  = (short*)(ws + 88*MB);     // born attn
    short* attnlo  = (short*)(ws + 96*MB);
    short* gate_e  = (short*)(ws + 88*MB);     // expert phase, 27MB [88,115)
    short* shTwg   = (short*)(ws + 104*MB);    // shared phase (dead before gate_e write)
    short* shTwu   = (short*)(ws + 112*MB);
    char*  S       = ws + 120*MB;              // bookkeeping (proven region)
    float* topw    = (float*)(S);
    int*   topi    = (int*)  (S + 32768);
    int*   posb    = (int*)  (S + 65536);
    int*   counts  = (int*)  (S + 98304);
    int*   padoff  = (int*)  (S + 98560);
    int*   ntl     = (int*)  (S + 98816);
    int*   tile_e  = (int*)  (S + 99072);
    int*   tile_b  = (int*)  (S + 99584);
    int*   rowmap  = (int*)  (S + 100352);
    float* wslot   = (float*)(S + 165888);
    short* zbuf    = (short*)(S + 231424);     // 16KB zeros
    short* ET      = (short*)(ws + 128*MB);    // big path only: 128MB bf16T experts
    bool big = (ws_size >= (size_t)268435456);
#undef MB

    dim3 blk(256);

    // 1) input RMSNorm -> hi/lo planes; split+transpose attention weights
    rmsnorm_k<0><<<T_TOK, blk, 0, stream>>>(hidden, in_ln, hfhi, hflo, nullptr);
    splitw_k<<<dim3(32,32), blk, 0, stream>>>(wq, wqThi, wqTlo, 2048, 2048);
    splitw_k<<<dim3(32,8),  blk, 0, stream>>>(wk, wkThi, wkTlo, 2048, 512);
    splitw_k<<<dim3(32,8),  blk, 0, stream>>>(wv, wvThi, wvTlo, 2048, 512);
    splitw_k<<<dim3(32,32), blk, 0, stream>>>(wo, woThi, woTlo, 2048, 2048);
    // 2) QKV projections (split, m97 staging); V written pre-transposed
    gemmsp3_k<0><<<dim3(16,16), blk, 0, stream>>>(hfhi, hflo, wqThi, wqTlo, qf, nullptr, nullptr, nullptr, 2048, 2048);
    gemmsp3_k<0><<<dim3(16,4),  blk, 0, stream>>>(hfhi, hflo, wkThi, wkTlo, kf, nullptr, nullptr, nullptr,  512, 2048);
    gemmsp3_k<6><<<dim3(16,4),  blk, 0, stream>>>(hfhi, hflo, wvThi, wvTlo, nullptr, nullptr, vhi, vlo,     512, 2048);
    // 3) qk-norm + rope -> split planes
    rope2_k<<<dim3(T_TOK,5), blk, 0, stream>>>(qf, kf, q_norm, k_norm, positions, qhi, qlo, khi, klo);
    // 4) causal flash attention (1-wave units, balanced) -> split output
    attn_k<<<2048, 64, 0, stream>>>(qhi, qlo, khi, klo, vhi, vlo, attnhi, attnlo);
    // 5) output projection + residual
    gemmsp3_k<1><<<dim3(16,16), blk, 0, stream>>>(attnhi, attnlo, woThi, woTlo, h2, hidden, nullptr, nullptr, 2048, 2048);
    // 6) post-attn RMSNorm
    rmsnorm_k<1><<<T_TOK, blk, 0, stream>>>(h2, post_ln, h2lnbf, nullptr, h2lnf);
    // 7) router + MoE bookkeeping
    initmoe_k<<<64, blk, 0, stream>>>(rowmap, wslot, counts, (int*)zbuf);
    router_k<<<T_TOK, blk, 0, stream>>>(h2lnf, gate_w, topw, topi, posb, counts);
    prep_k<<<1, 64, 0, stream>>>(counts, padoff, tile_e, tile_b, ntl);
    scatter_k<<<32, blk, 0, stream>>>(topi, topw, posb, padoff, rowmap, wslot);
    // 8) shared expert: convert to bf16T (fits), then gate / up(silu) / down(+resid)
    cvtT_k<<<dim3(32,32,1), blk, 0, stream>>>(sh_wg, shTwg, 2048, 2048);
    cvtT_k<<<dim3(32,32,1), blk, 0, stream>>>(sh_wu, shTwu, 2048, 2048);
    cvtT_k<<<dim3(32,32,1), blk, 0, stream>>>(sh_wd, shTwd, 2048, 2048);
    gemm3_k<3,false,false><<<dim3(16,16), blk, 0, stream>>>(h2lnbf, shTwg, nullptr, gatesh, nullptr, nullptr, 2048, 2048, nullptr, nullptr, nullptr, nullptr, 0, nullptr, zbuf);
    gemm3_k<5,false,false><<<dim3(16,16), blk, 0, stream>>>(h2lnbf, shTwu, nullptr, shint, nullptr, gatesh, 2048, 2048, nullptr, nullptr, nullptr, nullptr, 0, nullptr, zbuf);
    gemm3_k<1,false,false><<<dim3(16,16), blk, 0, stream>>>(shint, shTwd, out, nullptr, h2, nullptr, 2048, 2048, nullptr, nullptr, nullptr, nullptr, 0, nullptr, zbuf);
    // 9) routed experts
    if (big) {
        cvtT_k<<<dim3(32,16,NE), blk, 0, stream>>>(e_wg, ET, 2048, 1024);
        gemm3_k<3,true,true><<<dim3(MAXTILES,8), blk, 0, stream>>>(h2lnbf, ET, nullptr, gate_e, nullptr, nullptr, 1024, 2048, rowmap, tile_e, tile_b, ntl, (long)1024*2048, nullptr, zbuf);
        cvtT_k<<<dim3(32,16,NE), blk, 0, stream>>>(e_wu, ET, 2048, 1024);
        gemm3_k<5,true,true><<<dim3(MAXTILES,8), blk, 0, stream>>>(h2lnbf, ET, nullptr, interbf, nullptr, gate_e, 1024, 2048, rowmap, tile_e, tile_b, ntl, (long)1024*2048, nullptr, zbuf);
        cvtT_k<<<dim3(16,32,NE), blk, 0, stream>>>(e_wd, ET, 1024, 2048);
        gemm3_k<4,false,true><<<dim3(MAXTILES,16), blk, 0, stream>>>(interbf, ET, out, nullptr, nullptr, nullptr, 2048, 1024, rowmap, tile_e, tile_b, ntl, (long)2048*1024, wslot, zbuf);
    } else {
        gemm_k<3,true,true><<<dim3(MAXTILES,8), blk, 0, stream>>>(h2lnbf, e_wg, nullptr, gate_e, nullptr, nullptr, 1024, 2048, rowmap, tile_e, tile_b, ntl, (long)2048*1024, nullptr);
        gemm_k<5,true,true><<<dim3(MAXTILES,8), blk, 0, stream>>>(h2lnbf, e_wu, nullptr, interbf, nullptr, gate_e, 1024, 2048, rowmap, tile_e, tile_b, ntl, (long)2048*1024, nullptr);
        gemm_k<4,false,true><<<dim3(MAXTILES,16), blk, 0, stream>>>(interbf, e_wd, out, nullptr, nullptr, nullptr, 2048, 1024, rowmap, tile_e, tile_b, ntl, (long)1024*2048, wslot);
    }
}

// Round 12
// 1377.335 us; speedup vs baseline: 1.0860x; 1.0143x over previous
//
#include <hip/hip_runtime.h>

// Problem constants
#define T_TOK 2048   // B*S
#define DIM   2048
#define NQ    16
#define NKV   4
#define HDIM  128
#define NE    32
#define TOPK  4
#define FF    1024
#define FSH   2048
#define SEQ   1024
#define MAXROWS 16384
#define MAXTILES 96

typedef __attribute__((ext_vector_type(4))) float f32x4;
typedef __attribute__((ext_vector_type(8))) short bf16x8;

__device__ __forceinline__ short f2bf(float f) {
    union { float f; unsigned u; } c; c.f = f;
    unsigned r = (c.u + 0x7fffu + ((c.u >> 16) & 1u)) >> 16;
    return (short)r;
}
__device__ __forceinline__ float bf2f(short h) {
    union { unsigned u; float f; } c; c.u = ((unsigned)(unsigned short)h) << 16;
    return c.f;
}
__device__ __forceinline__ void splitf(float v, short& hi, short& lo) {
    hi = f2bf(v);
    lo = f2bf(v - bf2f(hi));
}
// bijective XCD-chunk swizzle (m204)
__device__ __forceinline__ int xcd_swz(int lin, int total) {
    int q8 = total >> 3, r8 = total & 7;
    int xcd = lin & 7, idx = lin >> 3;
    return (xcd < r8 ? xcd * (q8 + 1) : r8 * (q8 + 1) + (xcd - r8) * q8) + idx;
}
// async global->LDS, 16B per lane; lds dest = wave-uniform base + lane*16
__device__ __forceinline__ void gl16(const void* g, void* l) {
    __builtin_amdgcn_global_load_lds(
        (const __attribute__((address_space(1))) unsigned int*)g,
        (__attribute__((address_space(3))) unsigned int*)l, 16, 0, 0);
}

// ---------------- RMSNorm. MODE 0: hi/lo bf16 planes. MODE 1: bf16 + fp32 ----------------
template<int MODE>
__global__ __launch_bounds__(256)
void rmsnorm_k(const float* __restrict__ x, const float* __restrict__ sc,
               short* __restrict__ ybh, short* __restrict__ ybl, float* __restrict__ yf)
{
    long base = (long)blockIdx.x * DIM;
    int tid = threadIdx.x;
    const float* xp = x + base + tid * 8;
    float4 a = *(const float4*)xp;
    float4 b = *(const float4*)(xp + 4);
    float ss = a.x*a.x + a.y*a.y + a.z*a.z + a.w*a.w
             + b.x*b.x + b.y*b.y + b.z*b.z + b.w*b.w;
#pragma unroll
    for (int off = 32; off > 0; off >>= 1) ss += __shfl_xor(ss, off);
    __shared__ float red[4];
    if ((tid & 63) == 0) red[tid >> 6] = ss;
    __syncthreads();
    float s = red[0] + red[1] + red[2] + red[3];
    float inv = rsqrtf(s * (1.f / DIM) + 1e-6f);
    const float* sp = sc + tid * 8;
    float4 s0 = *(const float4*)sp;
    float4 s1 = *(const float4*)(sp + 4);
    float o[8];
    o[0]=a.x*inv*s0.x; o[1]=a.y*inv*s0.y; o[2]=a.z*inv*s0.z; o[3]=a.w*inv*s0.w;
    o[4]=b.x*inv*s1.x; o[5]=b.y*inv*s1.y; o[6]=b.z*inv*s1.z; o[7]=b.w*inv*s1.w;
    if (MODE == 0) {
        union { short s[8]; int4 v; } ph, pl;
#pragma unroll
        for (int i = 0; i < 8; ++i) splitf(o[i], ph.s[i], pl.s[i]);
        *(int4*)(ybh + base + tid * 8) = ph.v;
        *(int4*)(ybl + base + tid * 8) = pl.v;
    } else {
        union { short s[8]; int4 v; } ph;
#pragma unroll
        for (int i = 0; i < 8; ++i) ph.s[i] = f2bf(o[i]);
        *(int4*)(ybh + base + tid * 8) = ph.v;
        float4 w0; w0.x=o[0]; w0.y=o[1]; w0.z=o[2]; w0.w=o[3];
        float4 w1; w1.x=o[4]; w1.y=o[5]; w1.z=o[6]; w1.w=o[7];
        *(float4*)(yf + base + tid * 8) = w0;
        *(float4*)(yf + base + tid * 8 + 4) = w1;
    }
}

// -------- split+transpose weights: W[K][N] fp32 -> Thi/Tlo[N][K] bf16 --------
__global__ __launch_bounds__(256)
void splitw_k(const float* __restrict__ W, short* __restrict__ Thi, short* __restrict__ Tlo,
              int K, int N)
{
    __shared__ float t[64][65];
    int k0 = blockIdx.x * 64, n0 = blockIdx.y * 64;
    int tid = threadIdx.x;
    int rr = tid >> 4, cc = (tid & 15) * 4;
#pragma unroll
    for (int i = 0; i < 4; ++i) {
        int row = rr + i * 16;
        float4 v = *(const float4*)(W + (long)(k0 + row) * N + n0 + cc);
        t[row][cc] = v.x; t[row][cc+1] = v.y; t[row][cc+2] = v.z; t[row][cc+3] = v.w;
    }
    __syncthreads();
    int n = tid >> 2, kc = (tid & 3) * 16;
    union { short s[16]; int4 v[2]; } uh, ul;
#pragma unroll
    for (int j = 0; j < 16; ++j) splitf(t[kc + j][n], uh.s[j], ul.s[j]);
    long ob = (long)(n0 + n) * K + k0 + kc;
    *(int4*)(Thi + ob) = uh.v[0];
    *(int4*)(Thi + ob + 8) = uh.v[1];
    *(int4*)(Tlo + ob) = ul.v[0];
    *(int4*)(Tlo + ob + 8) = ul.v[1];
}

// -------- convert+transpose: W[K][N] fp32 -> T[N][K] bf16 (per blockIdx.z matrix) --------
__global__ __launch_bounds__(256)
void cvtT_k(const float* __restrict__ W, short* __restrict__ T, int K, int N)
{
    __shared__ float t[64][65];
    const float* Wp = W + (long)blockIdx.z * K * N;
    short* Tp = T + (long)blockIdx.z * K * N;
    int k0 = blockIdx.x * 64, n0 = blockIdx.y * 64;
    int tid = threadIdx.x;
    int rr = tid >> 4, cc = (tid & 15) * 4;
#pragma unroll
    for (int i = 0; i < 4; ++i) {
        int row = rr + i * 16;
        float4 v = *(const float4*)(Wp + (long)(k0 + row) * N + n0 + cc);
        t[row][cc] = v.x; t[row][cc+1] = v.y; t[row][cc+2] = v.z; t[row][cc+3] = v.w;
    }
    __syncthreads();
    int n = tid >> 2, kc = (tid & 3) * 16;
    union { short s[16]; int4 v[2]; } u;
#pragma unroll
    for (int j = 0; j < 16; ++j) u.s[j] = f2bf(t[kc + j][n]);
    long ob = (long)(n0 + n) * K + k0 + kc;
    *(int4*)(Tp + ob) = u.v[0];
    *(int4*)(Tp + ob + 8) = u.v[1];
}

// ------- Split GEMM (m97-style): C = (Ahi+Alo)[M][K] @ (BThi+BTlo)[N][K]^T -------
// EPI 0: Cf=acc ; 1: Cf=acc+addb ; 2: split acc -> Ohi/Olo (row-major)
// EPI 6: split acc -> Ohi/Olo TRANSPOSED [col][row] (for V: [hd-slot][token])
template<int EPI>
__global__ __launch_bounds__(256)
void gemmsp3_k(const short* __restrict__ Ahi, const short* __restrict__ Alo,
               const short* __restrict__ BThi, const short* __restrict__ BTlo,
               float* __restrict__ Cf, const float* __restrict__ addb,
               short* __restrict__ Ohi, short* __restrict__ Olo,
               int N, int K)
{
    int nby = gridDim.y;
    int total = gridDim.x * nby;
    int lin = blockIdx.x + gridDim.x * blockIdx.y;
    int vt = xcd_swz(lin, total);
    int row0 = (vt / nby) * 128, col0 = (vt % nby) * 128;
    __shared__ short Ah[4096], Al[4096], Bh[4096], Bl[4096];
    int tid = threadIdx.x, w = tid >> 6, l = tid & 63, g = l >> 4, lr = l & 15;
    int wr = w >> 1, wc = w & 1;
    int srt = tid >> 2, klane = (tid & 3) * 8;
    const short* pah0 = Ahi + (long)(row0 + srt) * K + klane;
    const short* pah1 = Ahi + (long)(row0 + srt + 64) * K + klane;
    const short* pal0 = Alo + (long)(row0 + srt) * K + klane;
    const short* pal1 = Alo + (long)(row0 + srt + 64) * K + klane;
    const short* pbh0 = BThi + (long)(col0 + srt) * K + klane;
    const short* pbh1 = BThi + (long)(col0 + srt + 64) * K + klane;
    const short* pbl0 = BTlo + (long)(col0 + srt) * K + klane;
    const short* pbl1 = BTlo + (long)(col0 + srt + 64) * K + klane;
    short* dA = Ah + w * 512;
    short* dAl = Al + w * 512;
    short* dB = Bh + w * 512;
    short* dBl = Bl + w * 512;
    f32x4 acc[4][4];
#pragma unroll
    for (int m = 0; m < 4; ++m)
#pragma unroll
        for (int n = 0; n < 4; ++n) acc[m][n] = (f32x4){0,0,0,0};
    for (int kk = 0; kk < K; kk += 32) {
        gl16(pah0 + kk, dA);        gl16(pah1 + kk, dA + 2048);
        gl16(pal0 + kk, dAl);       gl16(pal1 + kk, dAl + 2048);
        gl16(pbh0 + kk, dB);        gl16(pbh1 + kk, dB + 2048);
        gl16(pbl0 + kk, dBl);       gl16(pbl1 + kk, dBl + 2048);
        asm volatile("s_waitcnt vmcnt(0)" ::: "memory");
        __syncthreads();
        bf16x8 ah[4], al[4], bh[4], bl[4];
#pragma unroll
        for (int m = 0; m < 4; ++m) {
            int off = (wr * 64 + m * 16 + lr) * 32 + g * 8;
            ah[m] = *(const bf16x8*)(Ah + off);
            al[m] = *(const bf16x8*)(Al + off);
        }
#pragma unroll
        for (int n = 0; n < 4; ++n) {
            int off = (wc * 64 + n * 16 + lr) * 32 + g * 8;
            bh[n] = *(const bf16x8*)(Bh + off);
            bl[n] = *(const bf16x8*)(Bl + off);
        }
#pragma unroll
        for (int m = 0; m < 4; ++m)
#pragma unroll
            for (int n = 0; n < 4; ++n) {
                acc[m][n] = __builtin_amdgcn_mfma_f32_16x16x32_bf16(al[m], bh[n], acc[m][n], 0, 0, 0);
                acc[m][n] = __builtin_amdgcn_mfma_f32_16x16x32_bf16(ah[m], bl[n], acc[m][n], 0, 0, 0);
                acc[m][n] = __builtin_amdgcn_mfma_f32_16x16x32_bf16(ah[m], bh[n], acc[m][n], 0, 0, 0);
            }
        __syncthreads();
    }
#pragma unroll
    for (int m = 0; m < 4; ++m)
#pragma unroll
        for (int n = 0; n < 4; ++n) {
            if (EPI == 6) {
                short4 h4, l4;
#pragma unroll
                for (int j = 0; j < 4; ++j)
                    splitf(acc[m][n][j], ((short*)&h4)[j], ((short*)&l4)[j]);
                int rowb = row0 + wr * 64 + m * 16 + 4 * g;
                int col = col0 + wc * 64 + n * 16 + lr;
                *(short4*)(Ohi + (long)col * T_TOK + rowb) = h4;
                *(short4*)(Olo + (long)col * T_TOK + rowb) = l4;
            } else {
#pragma unroll
                for (int j = 0; j < 4; ++j) {
                    int row = row0 + wr * 64 + m * 16 + 4 * g + j;
                    int col = col0 + wc * 64 + n * 16 + lr;
                    float v = acc[m][n][j];
                    if (EPI == 0) Cf[(long)row * N + col] = v;
                    else if (EPI == 1) Cf[(long)row * N + col] = v + addb[(long)row * N + col];
                    else {
                        short hh, ll;
                        splitf(v, hh, ll);
                        Ohi[(long)row * N + col] = hh;
                        Olo[(long)row * N + col] = ll;
                    }
                }
            }
        }
}

// ------- bf16 GEMM (m97-style): C[M,N] = A[M][K] @ BT[N][K]^T, global_load_lds staging -------
// EPI 1: Cf=acc+addb ; 3: Cbf=bf16(acc) ; 5: Cbf=bf16(silu(gsrc)*acc) ;
// EPI 4: atomicAdd(Cf[tok*DIM+col], wslot[row]*acc)
template<int EPI, bool GATHER, bool EXPERT>
__global__ __launch_bounds__(256)
void gemm3_k(const short* __restrict__ A, const short* __restrict__ BTg,
             float* __restrict__ Cf, short* __restrict__ Cbf,
             const float* __restrict__ addb, const short* __restrict__ gsrc,
             int N, int K,
             const int* __restrict__ rowmap, const int* __restrict__ tile_e,
             const int* __restrict__ tile_base, const int* __restrict__ ntiles,
             long strideBT, const float* __restrict__ wslot,
             const short* __restrict__ zbuf)
{
    int nby = gridDim.y;
    int total = gridDim.x * nby;
    int lin = blockIdx.x + gridDim.x * blockIdx.y;
    int vt = xcd_swz(lin, total);
    int bx = vt / nby, by = vt % nby;
    int row0;
    const short* BT;
    if (EXPERT) {
        if (bx >= *ntiles) return;
        int e = tile_e[bx];
        row0 = tile_base[bx];
        BT = BTg + (long)e * strideBT;
    } else {
        row0 = bx * 128; BT = BTg;
    }
    int col0 = by * 128;
    __shared__ short As[4096], Bs[4096];
    int tid = threadIdx.x, w = tid >> 6, l = tid & 63, g = l >> 4, lr = l & 15;
    int wr = w >> 1, wc = w & 1;
    int srt = tid >> 2, klane = (tid & 3) * 8;
    const short *ap0, *ap1;
    if (GATHER) {
        int r0 = rowmap[row0 + srt], r1 = rowmap[row0 + srt + 64];
        ap0 = (r0 >= 0) ? (A + (long)r0 * K + klane) : (zbuf + klane);
        ap1 = (r1 >= 0) ? (A + (long)r1 * K + klane) : (zbuf + klane);
    } else {
        ap0 = A + (long)(row0 + srt) * K + klane;
        ap1 = A + (long)(row0 + srt + 64) * K + klane;
    }
    const short* bp0 = BT + (long)(col0 + srt) * K + klane;
    const short* bp1 = BT + (long)(col0 + srt + 64) * K + klane;
    short* dA = As + w * 512;
    short* dB = Bs + w * 512;
    f32x4 acc[4][4];
#pragma unroll
    for (int m = 0; m < 4; ++m)
#pragma unroll
        for (int n = 0; n < 4; ++n) acc[m][n] = (f32x4){0,0,0,0};
    for (int kk = 0; kk < K; kk += 32) {
        gl16(ap0 + kk, dA);  gl16(ap1 + kk, dA + 2048);
        gl16(bp0 + kk, dB);  gl16(bp1 + kk, dB + 2048);
        asm volatile("s_waitcnt vmcnt(0)" ::: "memory");
        __syncthreads();
        bf16x8 af[4], bf[4];
#pragma unroll
        for (int m = 0; m < 4; ++m)
            af[m] = *(const bf16x8*)(As + (wr * 64 + m * 16 + lr) * 32 + g * 8);
#pragma unroll
        for (int n = 0; n < 4; ++n)
            bf[n] = *(const bf16x8*)(Bs + (wc * 64 + n * 16 + lr) * 32 + g * 8);
#pragma unroll
        for (int m = 0; m < 4; ++m)
#pragma unroll
            for (int n = 0; n < 4; ++n)
                acc[m][n] = __builtin_amdgcn_mfma_f32_16x16x32_bf16(af[m], bf[n], acc[m][n], 0, 0, 0);
        __syncthreads();
    }
#pragma unroll
    for (int m = 0; m < 4; ++m)
#pragma unroll
        for (int n = 0; n < 4; ++n)
#pragma unroll
            for (int j = 0; j < 4; ++j) {
                int row = row0 + wr * 64 + m * 16 + 4 * g + j;
                int col = col0 + wc * 64 + n * 16 + lr;
                float v = acc[m][n][j];
                if (EPI == 1) Cf[(long)row * N + col] = v + addb[(long)row * N + col];
                else if (EPI == 3) Cbf[(long)row * N + col] = f2bf(v);
                else if (EPI == 5) {
                    float gv_ = bf2f(gsrc[(long)row * N + col]);
                    float sg = gv_ / (1.f + __expf(-gv_));
                    Cbf[(long)row * N + col] = f2bf(sg * v);
                } else if (EPI == 4) {
                    int tok = rowmap[row];
                    if (tok >= 0) atomicAdd(&Cf[(long)tok * DIM + col], wslot[row] * v);
                }
            }
}

// ---- fallback bf16 GEMM (round-6 proven): fp32 B reg-transpose staging, 2-deep prefetch ----
template<int EPI, bool GATHER, bool EXPERT>
__global__ __launch_bounds__(256)
void gemm_k(const short* __restrict__ A, const float* __restrict__ Bg,
            float* __restrict__ Cf, short* __restrict__ Cbf,
            const float* __restrict__ addb, const short* __restrict__ gsrc,
            int N, int K,
            const int* __restrict__ rowmap, const int* __restrict__ tile_e,
            const int* __restrict__ tile_base, const int* __restrict__ ntiles,
            long strideB, const float* __restrict__ wslot)
{
    int nby = gridDim.y;
    int total = gridDim.x * nby;
    int lin = blockIdx.x + gridDim.x * blockIdx.y;
    int vt = xcd_swz(lin, total);
    int bx = vt / nby, by = vt % nby;
    int row0;
    const float* B;
    if (EXPERT) {
        if (bx >= *ntiles) return;
        int e = tile_e[bx];
        row0 = tile_base[bx];
        B = Bg + (long)e * strideB;
    } else {
        row0 = bx * 128; B = Bg;
    }
    int col0 = by * 128;
    __shared__ short As[5120], Bs[5120];
    int tid = threadIdx.x;
    int w = tid >> 6, l = tid & 63, g = l >> 4, lr = l & 15;
    int wr = w >> 1, wc = w & 1;
    f32x4 acc[4][4];
#pragma unroll
    for (int m = 0; m < 4; ++m)
#pragma unroll
        for (int n = 0; n < 4; ++n) acc[m][n] = (f32x4){0,0,0,0};
    int ar = tid >> 2, ak = (tid & 3) * 8;
    int bk0 = (tid >> 5) * 4, bc0 = (tid & 31) * 4;
    bool rok[2]; const short* abase[2];
#pragma unroll
    for (int it = 0; it < 2; ++it) {
        int r = row0 + ar + it * 64;
        int sr = GATHER ? rowmap[r] : r;
        rok[it] = (!GATHER) || (sr >= 0);
        abase[it] = A + (long)(rok[it] ? sr : 0) * K + ak;
    }
    const float* bb = B + (long)bk0 * N + col0 + bc0;
    int4 aE[2], aO[2];
    float4 bE[4], bO[4];
#pragma unroll
    for (int it = 0; it < 2; ++it) {
        aE[it] = rok[it] ? *(const int4*)(abase[it]) : (int4){0,0,0,0};
        aO[it] = rok[it] ? *(const int4*)(abase[it] + 32) : (int4){0,0,0,0};
    }
#pragma unroll
    for (int q = 0; q < 4; ++q) {
        bE[q] = *(const float4*)(bb + (long)q * N);
        bO[q] = *(const float4*)(bb + (long)(32 + q) * N);
    }

#define GEMM_STEP(BANKA, BANKB, KNEXT)                                        \
    {                                                                         \
        __syncthreads();                                                      \
        _Pragma("unroll")                                                     \
        for (int it = 0; it < 2; ++it)                                        \
            *(int4*)(As + (ar + it * 64) * 40 + ak) = BANKA[it];              \
        _Pragma("unroll")                                                     \
        for (int j = 0; j < 4; ++j) {                                         \
            short4 pk;                                                        \
            pk.x = f2bf(((const float*)&BANKB[0])[j]);                        \
            pk.y = f2bf(((const float*)&BANKB[1])[j]);                        \
            pk.z = f2bf(((const float*)&BANKB[2])[j]);                        \
            pk.w = f2bf(((const float*)&BANKB[3])[j]);                        \
            int c = bc0 + j;                                                  \
            int blk = (bk0 >> 3) ^ ((c >> 2) & 3);                            \
            *(short4*)(Bs + c * 40 + blk * 8 + (bk0 & 4)) = pk;               \
        }                                                                     \
        if ((KNEXT) < K) {                                                    \
            _Pragma("unroll")                                                 \
            for (int it = 0; it < 2; ++it)                                    \
                BANKA[it] = rok[it] ? *(const int4*)(abase[it] + (KNEXT))     \
                                    : (int4){0,0,0,0};                        \
            _Pragma("unroll")                                                 \
            for (int q = 0; q < 4; ++q)                                       \
                BANKB[q] = *(const float4*)(bb + (long)((KNEXT) + q) * N);    \
        }                                                                     \
        __syncthreads();                                                      \
        bf16x8 af[4], bf[4];                                                  \
        _Pragma("unroll")                                                     \
        for (int m = 0; m < 4; ++m)                                           \
            af[m] = *(const bf16x8*)(As + (wr * 64 + m * 16 + lr) * 40 + g * 8); \
        _Pragma("unroll")                                                     \
        for (int n = 0; n < 4; ++n) {                                         \
            int c = wc * 64 + n * 16 + lr;                                    \
            int blk = g ^ ((c >> 2) & 3);                                     \
            bf[n] = *(const bf16x8*)(Bs + c * 40 + blk * 8);                  \
        }                                                                     \
        _Pragma("unroll")                                                     \
        for (int m = 0; m < 4; ++m)                                           \
            _Pragma("unroll")                                                 \
            for (int n = 0; n < 4; ++n)                                       \
                acc[m][n] = __builtin_amdgcn_mfma_f32_16x16x32_bf16(af[m], bf[n], acc[m][n], 0, 0, 0); \
    }

    for (int kk = 0; kk < K; kk += 64) {
        GEMM_STEP(aE, bE, kk + 64)
        GEMM_STEP(aO, bO, kk + 96)
    }
#undef GEMM_STEP

#pragma unroll
    for (int m = 0; m < 4; ++m)
#pragma unroll
        for (int n = 0; n < 4; ++n)
#pragma unroll
            for (int j = 0; j < 4; ++j) {
                int row = row0 + wr * 64 + m * 16 + 4 * g + j;
                int col = col0 + wc * 64 + n * 16 + lr;
                float v = acc[m][n][j];
                if (EPI == 1) Cf[(long)row * N + col] = v + addb[(long)row * N + col];
                else if (EPI == 3) Cbf[(long)row * N + col] = f2bf(v);
                else if (EPI == 5) {
                    float gv_ = bf2f(gsrc[(long)row * N + col]);
                    float sg = gv_ / (1.f + __expf(-gv_));
                    Cbf[(long)row * N + col] = f2bf(sg * v);
                } else if (EPI == 4) {
                    int tok = rowmap[row];
                    if (tok >= 0) atomicAdd(&Cf[(long)tok * DIM + col], wslot[row] * v);
                }
            }
}

// ---------------- qk-norm + neox RoPE + scale -> split bf16 planes ----------------
__global__ __launch_bounds__(256)
void rope2_k(const float* __restrict__ qf, const float* __restrict__ kf,
             const float* __restrict__ qn, const float* __restrict__ kn,
             const int* __restrict__ posp,
             short* __restrict__ qhi, short* __restrict__ qlo,
             short* __restrict__ khi, short* __restrict__ klo)
{
    int t = blockIdx.x;
    int w = threadIdx.x >> 6, l = threadIdx.x & 63;
    int hi = blockIdx.y * 4 + w;   // 0..19
    const float* src; const float* nrm; float esc;
    short* dh; short* dl;
    if (hi < NQ) {
        long off = (long)t * DIM + hi * HDIM;
        src = qf + off; nrm = qn; dh = qhi + off; dl = qlo + off;
        esc = 0.08838834764831843f;  // HD^-0.5 folded into q
    } else {
        int kh = hi - NQ;
        long off = (long)t * (NKV * HDIM) + kh * HDIM;
        src = kf + off; nrm = kn; dh = khi + off; dl = klo + off;
        esc = 1.f;
    }
    float x1 = src[l], x2 = src[l + 64];
    float ss = x1 * x1 + x2 * x2;
#pragma unroll
    for (int off = 32; off > 0; off >>= 1) ss += __shfl_xor(ss, off);
    float inv = rsqrtf(ss * (1.f / HDIM) + 1e-6f);
    float a1 = x1 * inv * nrm[l], a2 = x2 * inv * nrm[l + 64];
    float p = (float)posp[t];
    float fr = expf((float)l * -0.21586735246819178f); // -ln(1e6)/64
    float ang = p * fr;
    float cv = cosf(ang), sv = sinf(ang);
    float v1 = (a1 * cv - a2 * sv) * esc;
    float v2 = (a1 * sv + a2 * cv) * esc;
    short hh, ll;
    splitf(v1, hh, ll); dh[l] = hh; dl[l] = ll;
    splitf(v2, hh, ll); dh[l + 64] = hh; dl[l + 64] = ll;
}

// ---------------- flash attention (causal, GQA) — 1 wave/block, 64-key steps, split-term ILP ----------------
// vthi/vtlo layout: [kvh*128+hd][b*1024+t]
__global__ __launch_bounds__(64)
void attn_k(const short* __restrict__ qhi, const short* __restrict__ qlo,
            const short* __restrict__ khi, const short* __restrict__ klo,
            const short* __restrict__ vthi, const short* __restrict__ vtlo,
            short* __restrict__ ohi, short* __restrict__ olo)
{
    int u = blockIdx.x;
    int qt = 15 - (u >> 7);            // heavy q-tiles dispatch first
    int r = u & 127;
    int w = r & 3;                     // 16-row band within q-tile
    int bh = r >> 2;
    int h = bh & (NQ - 1), b = bh >> 4;
    int kvh = h >> 2;
    int l = threadIdx.x, g = l >> 4, lr = l & 15;
    int qbase = qt * 64 + w * 16;
    long qoff = (long)(b * SEQ + qbase + lr) * DIM + h * HDIM + 8 * g;
    bf16x8 qh[4], ql[4];
#pragma unroll
    for (int kc = 0; kc < 4; ++kc) {
        qh[kc] = *(const bf16x8*)(qhi + qoff + kc * 32);
        ql[kc] = *(const bf16x8*)(qlo + qoff + kc * 32);
    }
    f32x4 o[8];
#pragma unroll
    for (int i = 0; i < 8; ++i) o[i] = (f32x4){0,0,0,0};
    float mr[4] = {-1e30f, -1e30f, -1e30f, -1e30f};
    float ls[4] = {0, 0, 0, 0};
    __shared__ short Plh[16 * 72], Pll[16 * 72];   // [16 q][72-pitch, 64 keys]
    const short* vbh = vthi + (long)kvh * HDIM * T_TOK + b * SEQ;
    const short* vbl = vtlo + (long)kvh * HDIM * T_TOK + b * SEQ;
    const short* kbase_h = khi + (long)(b * SEQ) * (NKV * HDIM) + kvh * HDIM + 8 * g;
    const short* kbase_l = klo + (long)(b * SEQ) * (NKV * HDIM) + kvh * HDIM + 8 * g;
    int nsteps = qt + 1;
    for (int st = 0; st < nsteps; ++st) {
        int kb = st * 64;
        // QK^T over 64 keys: 3 split-terms in SEPARATE accumulator chains (depth 4)
        f32x4 shh[4], shl[4], slh[4];
#pragma unroll
        for (int n = 0; n < 4; ++n) {
            shh[n] = (f32x4){0,0,0,0};
            shl[n] = (f32x4){0,0,0,0};
            slh[n] = (f32x4){0,0,0,0};
        }
#pragma unroll
        for (int kc = 0; kc < 4; ++kc)
#pragma unroll
            for (int n = 0; n < 4; ++n) {
                long koff = (long)(kb + n * 16 + lr) * (NKV * HDIM) + kc * 32;
                bf16x8 kh8 = *(const bf16x8*)(kbase_h + koff);
                bf16x8 kl8 = *(const bf16x8*)(kbase_l + koff);
                shh[n] = __builtin_amdgcn_mfma_f32_16x16x32_bf16(qh[kc], kh8, shh[n], 0, 0, 0);
                shl[n] = __builtin_amdgcn_mfma_f32_16x16x32_bf16(qh[kc], kl8, shl[n], 0, 0, 0);
                slh[n] = __builtin_amdgcn_mfma_f32_16x16x32_bf16(ql[kc], kh8, slh[n], 0, 0, 0);
            }
        f32x4 sa[4];
#pragma unroll
        for (int n = 0; n < 4; ++n) {
            sa[n] = shh[n] + shl[n] + slh[n];
            // causal mask
#pragma unroll
            for (int j = 0; j < 4; ++j) {
                int key = kb + n * 16 + lr;
                int qr = qbase + 4 * g + j;
                if (key > qr) sa[n][j] = -1e30f;
            }
        }
        // online softmax (fp32) over 64 keys
#pragma unroll
        for (int j = 0; j < 4; ++j) {
            float v = fmaxf(fmaxf(sa[0][j], sa[1][j]), fmaxf(sa[2][j], sa[3][j]));
#pragma unroll
            for (int off = 1; off < 16; off <<= 1) v = fmaxf(v, __shfl_xor(v, off));
            float mn = fmaxf(mr[j], v);
            float sc = __expf(mr[j] - mn);
            mr[j] = mn;
            float p0 = __expf(sa[0][j] - mn);
            float p1 = __expf(sa[1][j] - mn);
            float p2 = __expf(sa[2][j] - mn);
            float p3 = __expf(sa[3][j] - mn);
            float rs = (p0 + p1) + (p2 + p3);
#pragma unroll
            for (int off = 1; off < 16; off <<= 1) rs += __shfl_xor(rs, off);
            ls[j] = ls[j] * sc + rs;
            int rb = (4 * g + j) * 72 + lr;
            short hh, ll;
            splitf(p0, hh, ll); Plh[rb] = hh;      Pll[rb] = ll;
            splitf(p1, hh, ll); Plh[rb + 16] = hh; Pll[rb + 16] = ll;
            splitf(p2, hh, ll); Plh[rb + 32] = hh; Pll[rb + 32] = ll;
            splitf(p3, hh, ll); Plh[rb + 48] = hh; Pll[rb + 48] = ll;
#pragma unroll
            for (int nf = 0; nf < 8; ++nf) o[nf][j] *= sc;
        }
        asm volatile("s_waitcnt lgkmcnt(0)" ::: "memory");
        __builtin_amdgcn_sched_barrier(0);
        bf16x8 pah0 = *(const bf16x8*)(Plh + lr * 72 + 8 * g);
        bf16x8 pal0 = *(const bf16x8*)(Pll + lr * 72 + 8 * g);
        bf16x8 pah1 = *(const bf16x8*)(Plh + lr * 72 + 32 + 8 * g);
        bf16x8 pal1 = *(const bf16x8*)(Pll + lr * 72 + 32 + 8 * g);
        __builtin_amdgcn_s_setprio(1);
#pragma unroll
        for (int nf = 0; nf < 8; ++nf) {
            long voff = (long)(nf * 16 + lr) * T_TOK + kb + 8 * g;
            bf16x8 vh0 = *(const bf16x8*)(vbh + voff);
            bf16x8 vl0 = *(const bf16x8*)(vbl + voff);
            bf16x8 vh1 = *(const bf16x8*)(vbh + voff + 32);
            bf16x8 vl1 = *(const bf16x8*)(vbl + voff + 32);
            o[nf] = __builtin_amdgcn_mfma_f32_16x16x32_bf16(pal0, vh0, o[nf], 0, 0, 0);
            o[nf] = __builtin_amdgcn_mfma_f32_16x16x32_bf16(pah0, vl0, o[nf], 0, 0, 0);
            o[nf] = __builtin_amdgcn_mfma_f32_16x16x32_bf16(pah0, vh0, o[nf], 0, 0, 0);
            o[nf] = __builtin_amdgcn_mfma_f32_16x16x32_bf16(pal1, vh1, o[nf], 0, 0, 0);
            o[nf] = __builtin_amdgcn_mfma_f32_16x16x32_bf16(pah1, vl1, o[nf], 0, 0, 0);
            o[nf] = __builtin_amdgcn_mfma_f32_16x16x32_bf16(pah1, vh1, o[nf], 0, 0, 0);
        }
        __builtin_amdgcn_s_setprio(0);
    }
    float invl[4];
#pragma unroll
    for (int j = 0; j < 4; ++j) invl[j] = 1.f / ls[j];
#pragma unroll
    for (int nf = 0; nf < 8; ++nf)
#pragma unroll
        for (int j = 0; j < 4; ++j) {
            long idx = (long)(b * SEQ + qbase + 4 * g + j) * DIM + h * HDIM + nf * 16 + lr;
            short hh, ll;
            splitf(o[nf][j] * invl[j], hh, ll);
            ohi[idx] = hh;
            olo[idx] = ll;
        }
}

// ---------------- router: sigmoid gate + top-4 + renorm ----------------
__global__ __launch_bounds__(256)
void router_k(const float* __restrict__ x, const float* __restrict__ gw,
              float* __restrict__ topw, int* __restrict__ topi,
              int* __restrict__ posb, int* __restrict__ counts)
{
    int t = blockIdx.x, tid = threadIdx.x;
    int e = tid & 31, ch = tid >> 5;
    const float* xp = x + (long)t * DIM + ch * 256;
    float p = 0.f;
    for (int d = 0; d < 256; ++d) p += xp[d] * gw[(ch * 256 + d) * NE + e];
    __shared__ float red[8][32];
    __shared__ float gv[32];
    red[ch][e] = p;
    __syncthreads();
    if (tid < 32) {
        float s = 0.f;
        for (int c = 0; c < 8; ++c) s += red[c][tid];
        gv[tid] = 1.f / (1.f + expf(-s));
    }
    __syncthreads();
    if (tid == 0) {
        float lg[32];
        for (int i = 0; i < 32; ++i) lg[i] = gv[i];
        float tv[TOPK]; int ti[TOPK]; float wsum = 0.f;
        for (int j = 0; j < TOPK; ++j) {
            float bv = -1e30f; int bi = 0;
            for (int i = 0; i < 32; ++i) if (lg[i] > bv) { bv = lg[i]; bi = i; }
            tv[j] = bv; ti[j] = bi; lg[bi] = -1e30f; wsum += bv;
        }
        float r = 1.f / wsum;
        for (int j = 0; j < TOPK; ++j) {
            topw[t * TOPK + j] = tv[j] * r;
            topi[t * TOPK + j] = ti[j];
            posb[t * TOPK + j] = atomicAdd(&counts[ti[j]], 1);
        }
    }
}

__global__ void initmoe_k(int* __restrict__ rowmap, float* __restrict__ wslot,
                          int* __restrict__ counts, int* __restrict__ zb)
{
    int i = blockIdx.x * 256 + threadIdx.x;
    if (i < MAXROWS) { rowmap[i] = -1; wslot[i] = 0.f; }
    if (i < NE) counts[i] = 0;
    if (i < 4096) zb[i] = 0;
}

__global__ void prep_k(const int* __restrict__ counts, int* __restrict__ padoff,
                       int* __restrict__ tile_e, int* __restrict__ tile_base, int* __restrict__ ntl)
{
    if (threadIdx.x == 0 && blockIdx.x == 0) {
        int nt = 0, rb = 0;
        for (int e = 0; e < NE; ++e) {
            padoff[e] = rb;
            int c = counts[e];
            int te = (c + 127) >> 7;
            for (int i = 0; i < te; ++i) { tile_e[nt] = e; tile_base[nt] = rb + i * 128; ++nt; }
            rb += te * 128;
        }
        *ntl = nt;
    }
}

__global__ void scatter_k(const int* __restrict__ topi, const float* __restrict__ topw,
                          const int* __restrict__ posb, const int* __restrict__ padoff,
                          int* __restrict__ rowmap, float* __restrict__ wslot)
{
    int i = blockIdx.x * 256 + threadIdx.x;
    if (i < T_TOK * TOPK) {
        int e = topi[i];
        int s = padoff[e] + posb[i];
        rowmap[s] = i >> 2;
        wslot[s] = topw[i];
    }
}

// ---------------- launch ----------------
extern "C" void kernel_launch(void* const* d_in, const int* in_sizes, int n_in,
                              void* d_out, int out_size, void* d_ws, size_t ws_size,
                              hipStream_t stream)
{
    (void)in_sizes; (void)n_in; (void)out_size;
    const int*   positions = (const int*)  d_in[0];
    const float* hidden    = (const float*)d_in[1];
    const float* in_ln     = (const float*)d_in[2];
    const float* post_ln   = (const float*)d_in[3];
    const float* q_norm    = (const float*)d_in[4];
    const float* k_norm    = (const float*)d_in[5];
    const float* wq        = (const float*)d_in[6];
    const float* wk        = (const float*)d_in[7];
    const float* wv        = (const float*)d_in[8];
    const float* wo        = (const float*)d_in[9];
    const float* gate_w    = (const float*)d_in[10];
    const float* sh_wg     = (const float*)d_in[11];
    const float* sh_wu     = (const float*)d_in[12];
    const float* sh_wd     = (const float*)d_in[13];
    const float* e_wg      = (const float*)d_in[14];
    const float* e_wu      = (const float*)d_in[15];
    const float* e_wd      = (const float*)d_in[16];
    float* out = (float*)d_out;
    char* ws = (char*)d_ws;

#define MB (1048576L)
    // proven-safe region is [0, ~126MB); ET (big path) needs ws_size >= 256MB
    short* hfhi    = (short*)(ws + 0*MB);      // dead after QKV
    short* hflo    = (short*)(ws + 8*MB);
    short* gatesh  = (short*)(ws + 0*MB);      // shared phase
    short* shint   = (short*)(ws + 8*MB);
    short* interbf = (short*)(ws + 0*MB);      // expert phase, 27MB (rows<=13k)
    short* wqThi   = (short*)(ws + 16*MB);     // dead after Q gemm
    short* wqTlo   = (short*)(ws + 24*MB);
    float* h2lnf   = (float*)(ws + 16*MB);     // born step 6
    short* wkThi   = (short*)(ws + 32*MB);
    short* wkTlo   = (short*)(ws + 34*MB);
    short* wvThi   = (short*)(ws + 36*MB);
    short* wvTlo   = (short*)(ws + 38*MB);
    short* h2lnbf  = (short*)(ws + 32*MB);     // born step 6
    short* woThi   = (short*)(ws + 40*MB);     // dead after Wo gemm
    short* woTlo   = (short*)(ws + 48*MB);
    short* shTwd   = (short*)(ws + 40*MB);     // born shared phase (8MB)
    short* qhi     = (short*)(ws + 56*MB);     // dead after attn
    short* qlo     = (short*)(ws + 64*MB);
    float* kf      = (float*)(ws + 72*MB);     // dead after rope
    short* khi     = (short*)(ws + 76*MB);
    short* klo     = (short*)(ws + 78*MB);
    short* vhi     = (short*)(ws + 80*MB);     // V TRANSPOSED planes [512][2048]
    short* vlo     = (short*)(ws + 82*MB);
    float* h2      = (float*)(ws + 72*MB);     // born step 5 (16MB)
    float* qf      = (float*)(ws + 88*MB);     // dead after rope
    short* attnhi  = (short*)(ws + 88*MB);     // born attn
    short* attnlo  = (short*)(ws + 96*MB);
    short* gate_e  = (short*)(ws + 88*MB);     // expert phase, 27MB [88,115)
    short* shTwg   = (short*)(ws + 104*MB);    // shared phase (dead before gate_e write)
    short* shTwu   = (short*)(ws + 112*MB);
    char*  S       = ws + 120*MB;              // bookkeeping (proven region)
    float* topw    = (float*)(S);
    int*   topi    = (int*)  (S + 32768);
    int*   posb    = (int*)  (S + 65536);
    int*   counts  = (int*)  (S + 98304);
    int*   padoff  = (int*)  (S + 98560);
    int*   ntl     = (int*)  (S + 98816);
    int*   tile_e  = (int*)  (S + 99072);
    int*   tile_b  = (int*)  (S + 99584);
    int*   rowmap  = (int*)  (S + 100352);
    float* wslot   = (float*)(S + 165888);
    short* zbuf    = (short*)(S + 231424);     // 16KB zeros
    short* ET      = (short*)(ws + 128*MB);    // big path only: 128MB bf16T experts
    bool big = (ws_size >= (size_t)268435456);
#undef MB

    dim3 blk(256);

    // 1) input RMSNorm -> hi/lo planes; split+transpose attention weights
    rmsnorm_k<0><<<T_TOK, blk, 0, stream>>>(hidden, in_ln, hfhi, hflo, nullptr);
    splitw_k<<<dim3(32,32), blk, 0, stream>>>(wq, wqThi, wqTlo, 2048, 2048);
    splitw_k<<<dim3(32,8),  blk, 0, stream>>>(wk, wkThi, wkTlo, 2048, 512);
    splitw_k<<<dim3(32,8),  blk, 0, stream>>>(wv, wvThi, wvTlo, 2048, 512);
    splitw_k<<<dim3(32,32), blk, 0, stream>>>(wo, woThi, woTlo, 2048, 2048);
    // 2) QKV projections (split, m97 staging); V written pre-transposed
    gemmsp3_k<0><<<dim3(16,16), blk, 0, stream>>>(hfhi, hflo, wqThi, wqTlo, qf, nullptr, nullptr, nullptr, 2048, 2048);
    gemmsp3_k<0><<<dim3(16,4),  blk, 0, stream>>>(hfhi, hflo, wkThi, wkTlo, kf, nullptr, nullptr, nullptr,  512, 2048);
    gemmsp3_k<6><<<dim3(16,4),  blk, 0, stream>>>(hfhi, hflo, wvThi, wvTlo, nullptr, nullptr, vhi, vlo,     512, 2048);
    // 3) qk-norm + rope -> split planes
    rope2_k<<<dim3(T_TOK,5), blk, 0, stream>>>(qf, kf, q_norm, k_norm, positions, qhi, qlo, khi, klo);
    // 4) causal flash attention (1-wave units, 64-key steps) -> split output
    attn_k<<<2048, 64, 0, stream>>>(qhi, qlo, khi, klo, vhi, vlo, attnhi, attnlo);
    // 5) output projection + residual
    gemmsp3_k<1><<<dim3(16,16), blk, 0, stream>>>(attnhi, attnlo, woThi, woTlo, h2, hidden, nullptr, nullptr, 2048, 2048);
    // 6) post-attn RMSNorm
    rmsnorm_k<1><<<T_TOK, blk, 0, stream>>>(h2, post_ln, h2lnbf, nullptr, h2lnf);
    // 7) router + MoE bookkeeping
    initmoe_k<<<64, blk, 0, stream>>>(rowmap, wslot, counts, (int*)zbuf);
    router_k<<<T_TOK, blk, 0, stream>>>(h2lnf, gate_w, topw, topi, posb, counts);
    prep_k<<<1, 64, 0, stream>>>(counts, padoff, tile_e, tile_b, ntl);
    scatter_k<<<32, blk, 0, stream>>>(topi, topw, posb, padoff, rowmap, wslot);
    // 8) shared expert: convert to bf16T (fits), then gate / up(silu) / down(+resid)
    cvtT_k<<<dim3(32,32,1), blk, 0, stream>>>(sh_wg, shTwg, 2048, 2048);
    cvtT_k<<<dim3(32,32,1), blk, 0, stream>>>(sh_wu, shTwu, 2048, 2048);
    cvtT_k<<<dim3(32,32,1), blk, 0, stream>>>(sh_wd, shTwd, 2048, 2048);
    gemm3_k<3,false,false><<<dim3(16,16), blk, 0, stream>>>(h2lnbf, shTwg, nullptr, gatesh, nullptr, nullptr, 2048, 2048, nullptr, nullptr, nullptr, nullptr, 0, nullptr, zbuf);
    gemm3_k<5,false,false><<<dim3(16,16), blk, 0, stream>>>(h2lnbf, shTwu, nullptr, shint, nullptr, gatesh, 2048, 2048, nullptr, nullptr, nullptr, nullptr, 0, nullptr, zbuf);
    gemm3_k<1,false,false><<<dim3(16,16), blk, 0, stream>>>(shint, shTwd, out, nullptr, h2, nullptr, 2048, 2048, nullptr, nullptr, nullptr, nullptr, 0, nullptr, zbuf);
    // 9) routed experts
    if (big) {
        cvtT_k<<<dim3(32,16,NE), blk, 0, stream>>>(e_wg, ET, 2048, 1024);
        gemm3_k<3,true,true><<<dim3(MAXTILES,8), blk, 0, stream>>>(h2lnbf, ET, nullptr, gate_e, nullptr, nullptr, 1024, 2048, rowmap, tile_e, tile_b, ntl, (long)1024*2048, nullptr, zbuf);
        cvtT_k<<<dim3(32,16,NE), blk, 0, stream>>>(e_wu, ET, 2048, 1024);
        gemm3_k<5,true,true><<<dim3(MAXTILES,8), blk, 0, stream>>>(h2lnbf, ET, nullptr, interbf, nullptr, gate_e, 1024, 2048, rowmap, tile_e, tile_b, ntl, (long)1024*2048, nullptr, zbuf);
        cvtT_k<<<dim3(16,32,NE), blk, 0, stream>>>(e_wd, ET, 1024, 2048);
        gemm3_k<4,false,true><<<dim3(MAXTILES,16), blk, 0, stream>>>(interbf, ET, out, nullptr, nullptr, nullptr, 2048, 1024, rowmap, tile_e, tile_b, ntl, (long)2048*1024, wslot, zbuf);
    } else {
        gemm_k<3,true,true><<<dim3(MAXTILES,8), blk, 0, stream>>>(h2lnbf, e_wg, nullptr, gate_e, nullptr, nullptr, 1024, 2048, rowmap, tile_e, tile_b, ntl, (long)2048*1024, nullptr);
        gemm_k<5,true,true><<<dim3(MAXTILES,8), blk, 0, stream>>>(h2lnbf, e_wu, nullptr, interbf, nullptr, gate_e, 1024, 2048, rowmap, tile_e, tile_b, ntl, (long)2048*1024, nullptr);
        gemm_k<4,false,true><<<dim3(MAXTILES,16), blk, 0, stream>>>(interbf, e_wd, out, nullptr, nullptr, nullptr, 2048, 1024, rowmap, tile_e, tile_b, ntl, (long)1024*2048, wslot);
    }
}